// Round 2
// baseline (772.157 us; speedup 1.0000x reference)
//
#include <hip/hip_runtime.h>
#include <math.h>

// ---------------------------------------------------------------------------
// TransformerBlock: B=2, T=2048, K=1024, H=4 (each head gets FULL dim K).
//   q = (x@Wq)*s, k = (x@Wk)*s, v = x@Wv      s = K^-0.25
//   S[b,h] = q_h @ k_h^T  (causal), P = softmax(S)
//   ao = P @ v_h ;  x1 = x + ao@Wu + bu
//   out = x1 + relu(x1@W1+b1)@W2 + b2
//
// R1: workspace compacted 300MB -> 176MB (suspected d_ws overrun caused the
// R0 abort). V stored transposed directly from its GEMM epilogue (c_vt flag);
// single reused weight-transpose buffer; ao aliases qb, FFN temps alias kb.
// Workspace map (MB):  [0,8) xb | [8,16) Wbuf | [16,48) qb/ao | [48,80)
// kb/(x1f,x1b,h1) | [80,112) vT | [112,176) S.
// ---------------------------------------------------------------------------

#define TM 128
#define TN 128
#define BK 32

typedef __attribute__((ext_vector_type(8))) short short8;   // 8 bf16 (4 VGPRs)
typedef __attribute__((ext_vector_type(4))) float f32x4;

__device__ __forceinline__ unsigned short f2bf(float f) {
  union { float f; unsigned int u; } v; v.f = f;
  unsigned int r = (v.u + 0x7fffu + ((v.u >> 16) & 1u)) >> 16;
  return (unsigned short)r;
}
__device__ __forceinline__ float bf2f(unsigned short b) {
  union { unsigned int u; float f; } v; v.u = ((unsigned int)b) << 16;
  return v.f;
}

#define GL2LDS(g, l)                                                          \
  __builtin_amdgcn_global_load_lds(                                           \
      (__attribute__((address_space(1))) void*)(g),                           \
      (__attribute__((address_space(3))) void*)(l), 16, 0, 0)

// Generic bf16 GEMM: C = act(scale*(A @ BT^T) + bias + resid)
// A: [M,Kd] row-major (lda), BT: [N,Kd] row-major (ldb).
// Batched via grid.z: off = (z>>bh_shift)*ob + (z&mask)*oh.
// causal_mode: 0=none, 1=skip tiles fully above diagonal (scores),
//              2=truncate K-loop at m0+TM (P@V with causal-zero P).
// c_vt: store Cb in [b,h,d,t] layout (V projection; T=2048, KH=4096 fixed).
__global__ __launch_bounds__(256) void gemm_bt(
    const unsigned short* __restrict__ A, const unsigned short* __restrict__ BT,
    int M, int N, int Kd, int lda, int ldb, int ldc, int bh_shift,
    long long aob, long long aoh, long long bob, long long boh,
    long long cob, long long coh, float scale,
    const float* __restrict__ bias, const float* __restrict__ resid,
    int do_relu, float* __restrict__ Cf, unsigned short* __restrict__ Cb,
    int causal_mode, int c_vt) {
  const int n0 = blockIdx.x * TN;
  const int m0 = blockIdx.y * TM;
  if (causal_mode == 1 && n0 >= m0 + TM) return;  // fully-masked tile

  const int z = blockIdx.z;
  const int zb = z >> bh_shift;
  const int zh = z & ((1 << bh_shift) - 1);
  const long long aoff = (long long)zb * aob + (long long)zh * aoh;
  const long long boff = (long long)zb * bob + (long long)zh * boh;
  const long long coff = (long long)zb * cob + (long long)zh * coh;

  __shared__ unsigned short As[TM * BK];  // [128][32], row-major, no pad
  __shared__ unsigned short Bs[TN * BK];  // (global_load_lds needs exact order)

  const int tid = threadIdx.x;
  const int lane = tid & 63;
  const int wv = tid >> 6;
  const int wm = wv & 1;   // 2x2 wave grid over 128x128 tile
  const int wn = wv >> 1;

  const int srow = tid >> 2;
  const int scol = (tid & 3) * 8;
  const unsigned short* ap0 = A + aoff + (long long)(m0 + srow) * lda + scol;
  const unsigned short* ap1 = A + aoff + (long long)(m0 + srow + 64) * lda + scol;
  const unsigned short* bp0 = BT + boff + (long long)(n0 + srow) * ldb + scol;
  const unsigned short* bp1 = BT + boff + (long long)(n0 + srow + 64) * ldb + scol;
  unsigned short* lA0 = As + wv * 512;          // wave-uniform LDS bases
  unsigned short* lA1 = As + 2048 + wv * 512;
  unsigned short* lB0 = Bs + wv * 512;
  unsigned short* lB1 = Bs + 2048 + wv * 512;

  f32x4 acc[4][4];
#pragma unroll
  for (int i = 0; i < 4; ++i)
#pragma unroll
    for (int j = 0; j < 4; ++j) acc[i][j] = {0.f, 0.f, 0.f, 0.f};

  int kmax = Kd;
  if (causal_mode == 2) { int t = m0 + TM; if (t < kmax) kmax = t; }

  const int frow = lane & 15;          // m (or n) within 16x16
  const int fq = (lane >> 4) * 8;      // k chunk

  for (int k0 = 0; k0 < kmax; k0 += BK) {
    __syncthreads();                   // prev iter's ds_reads done
    GL2LDS(ap0, lA0);
    GL2LDS(ap1, lA1);
    GL2LDS(bp0, lB0);
    GL2LDS(bp1, lB1);
    ap0 += BK; ap1 += BK; bp0 += BK; bp1 += BK;
    __syncthreads();                   // vmcnt(0) drain -> LDS visible

    short8 af[4], bf[4];
#pragma unroll
    for (int mi = 0; mi < 4; ++mi)
      af[mi] = *(const short8*)(As + (wm * 64 + mi * 16 + frow) * BK + fq);
#pragma unroll
    for (int ni = 0; ni < 4; ++ni)
      bf[ni] = *(const short8*)(Bs + (wn * 64 + ni * 16 + frow) * BK + fq);
#pragma unroll
    for (int mi = 0; mi < 4; ++mi)
#pragma unroll
      for (int ni = 0; ni < 4; ++ni)
        acc[mi][ni] = __builtin_amdgcn_mfma_f32_16x16x32_bf16(
            af[mi], bf[ni], acc[mi][ni], 0, 0, 0);
  }

  // epilogue: C/D layout col=lane&15, row=(lane>>4)*4+r (m89-verified)
  const int ccol = lane & 15;
  const int crow = (lane >> 4) * 4;
#pragma unroll
  for (int mi = 0; mi < 4; ++mi) {
#pragma unroll
    for (int ni = 0; ni < 4; ++ni) {
      const int gc = n0 + wn * 64 + ni * 16 + ccol;
#pragma unroll
      for (int r = 0; r < 4; ++r) {
        const int gr = m0 + wm * 64 + mi * 16 + crow + r;
        float v = acc[mi][ni][r] * scale;
        if (bias) v += bias[gc];
        if (resid) v += resid[(long long)gr * ldc + gc];
        if (do_relu) v = fmaxf(v, 0.f);
        if (c_vt) {
          // v[b,t,h,d] -> vT[b,h,d,t]: b=gr>>11, t=gr&2047, (h,d)=gc
          const long long ti =
              ((long long)((gr >> 11) * 4096 + gc)) * 2048 + (gr & 2047);
          Cb[ti] = f2bf(v);
        } else {
          const long long ci = coff + (long long)gr * ldc + gc;
          if (Cf) Cf[ci] = v;
          if (Cb) Cb[ci] = f2bf(v);
        }
      }
    }
  }
}

// Row-wise causal softmax, in-place on bf16 scores. grid=(T, B*H), block=256.
// Row q has q+1 valid entries; writes 0 beyond so P@V can read full tiles.
__global__ __launch_bounds__(256) void softmax_causal(unsigned short* S, int T) {
  const int q = blockIdx.x;
  unsigned short* row = S + ((long long)blockIdx.y * T + q) * T;
  const int tid = threadIdx.x;
  const int lane = tid & 63;
  const int wv = tid >> 6;
  const int n = q + 1;
  float vals[8];
  float m = -__builtin_inff();
#pragma unroll
  for (int i = 0; i < 8; ++i) {
    int idx = i * 256 + tid;
    vals[i] = (idx < n) ? bf2f(row[idx]) : -__builtin_inff();
    m = fmaxf(m, vals[i]);
  }
#pragma unroll
  for (int o = 32; o; o >>= 1) m = fmaxf(m, __shfl_xor(m, o, 64));
  __shared__ float red[4];
  if (lane == 0) red[wv] = m;
  __syncthreads();
  m = fmaxf(fmaxf(red[0], red[1]), fmaxf(red[2], red[3]));
  __syncthreads();
  float s = 0.f, e[8];
#pragma unroll
  for (int i = 0; i < 8; ++i) {
    int idx = i * 256 + tid;
    e[i] = (idx < n) ? __expf(vals[i] - m) : 0.f;
    s += e[i];
  }
#pragma unroll
  for (int o = 32; o; o >>= 1) s += __shfl_xor(s, o, 64);
  if (lane == 0) red[wv] = s;
  __syncthreads();
  s = red[0] + red[1] + red[2] + red[3];
  const float inv = 1.f / s;
#pragma unroll
  for (int i = 0; i < 8; ++i) {
    int idx = i * 256 + tid;
    row[idx] = f2bf(e[i] * inv);  // idx in [0,2048) always; zeros past n
  }
}

// fp32 -> bf16 elementwise (n divisible by 4)
__global__ __launch_bounds__(256) void cast_bf16(const float* __restrict__ in,
                                                 unsigned short* __restrict__ out,
                                                 int n4) {
  int i = blockIdx.x * 256 + threadIdx.x;
  if (i < n4) {
    const float4 v = *(const float4*)(in + (long long)i * 4);
    ushort4 o;
    o.x = f2bf(v.x); o.y = f2bf(v.y); o.z = f2bf(v.z); o.w = f2bf(v.w);
    *(ushort4*)(out + (long long)i * 4) = o;
  }
}

// W[R,C] fp32 -> WT[C,R] bf16.  grid=(C/32, R/32), block=256.
__global__ __launch_bounds__(256) void transpose_cast_w(
    const float* __restrict__ W, unsigned short* __restrict__ WT, int R, int C) {
  __shared__ float tile[32][33];
  const int c0 = blockIdx.x * 32;
  const int r0 = blockIdx.y * 32;
  const int tx = threadIdx.x & 31;
  const int ty = threadIdx.x >> 5;  // 0..7
#pragma unroll
  for (int j = 0; j < 32; j += 8)
    tile[ty + j][tx] = W[(long long)(r0 + ty + j) * C + c0 + tx];
  __syncthreads();
#pragma unroll
  for (int j = 0; j < 32; j += 8)
    WT[(long long)(c0 + ty + j) * R + r0 + tx] = f2bf(tile[tx][ty + j]);
}

extern "C" void kernel_launch(void* const* d_in, const int* in_sizes, int n_in,
                              void* d_out, int out_size, void* d_ws,
                              size_t ws_size, hipStream_t stream) {
  (void)in_sizes; (void)n_in; (void)out_size; (void)ws_size;
  const float* x  = (const float*)d_in[0];
  const float* Wq = (const float*)d_in[1];
  const float* Wk = (const float*)d_in[2];
  const float* Wv = (const float*)d_in[3];
  const float* Wu = (const float*)d_in[4];
  const float* bu = (const float*)d_in[5];
  const float* W1 = (const float*)d_in[6];
  const float* b1 = (const float*)d_in[7];
  const float* W2 = (const float*)d_in[8];
  const float* b2 = (const float*)d_in[9];
  float* out = (float*)d_out;

  const int B = 2, T = 2048, K = 1024, H = 4;
  const int BT = B * T;   // 4096
  const int KH = K * H;   // 4096
  const size_t MB = 1024 * 1024;

  char* w = (char*)d_ws;
  // 176 MB total; aliased regions documented in header.
  unsigned short* xb   = (unsigned short*)(w + 0 * MB);    //  8 MB, bf16 x
  unsigned short* Wbuf = (unsigned short*)(w + 8 * MB);    //  8 MB, reused W^T
  unsigned short* qb   = (unsigned short*)(w + 16 * MB);   // 32 MB
  unsigned short* kb   = (unsigned short*)(w + 48 * MB);   // 32 MB
  unsigned short* vT   = (unsigned short*)(w + 80 * MB);   // 32 MB [b,h,d,t]
  unsigned short* S    = (unsigned short*)(w + 112 * MB);  // 64 MB
  unsigned short* ao   = qb;                               // alias (qb dead)
  float*          x1f  = (float*)(w + 48 * MB);            // alias kb [48,64)
  unsigned short* x1b  = (unsigned short*)(w + 64 * MB);   // alias kb [64,72)
  unsigned short* h1   = (unsigned short*)(w + 72 * MB);   // alias kb [72,80)

  const float scale = 0.17677669529663689f;  // 1024^-0.25

  cast_bf16<<<dim3(BT * K / 4 / 256), 256, 0, stream>>>(x, xb, BT * K / 4);

  // --- QKV projections: [BT,K] @ [K,KH] -> [BT,KH] (weights via Wbuf) ---
  transpose_cast_w<<<dim3(KH / 32, K / 32), 256, 0, stream>>>(Wq, Wbuf, K, KH);
  gemm_bt<<<dim3(KH / TN, BT / TM, 1), 256, 0, stream>>>(
      xb, Wbuf, BT, KH, K, K, K, KH, 0, 0, 0, 0, 0, 0, 0, scale,
      nullptr, nullptr, 0, nullptr, qb, 0, 0);
  transpose_cast_w<<<dim3(KH / 32, K / 32), 256, 0, stream>>>(Wk, Wbuf, K, KH);
  gemm_bt<<<dim3(KH / TN, BT / TM, 1), 256, 0, stream>>>(
      xb, Wbuf, BT, KH, K, K, K, KH, 0, 0, 0, 0, 0, 0, 0, scale,
      nullptr, nullptr, 0, nullptr, kb, 0, 0);
  transpose_cast_w<<<dim3(KH / 32, K / 32), 256, 0, stream>>>(Wv, Wbuf, K, KH);
  gemm_bt<<<dim3(KH / TN, BT / TM, 1), 256, 0, stream>>>(
      xb, Wbuf, BT, KH, K, K, K, KH, 0, 0, 0, 0, 0, 0, 0, 1.0f,
      nullptr, nullptr, 0, nullptr, vT, 0, 1);   // c_vt: store [b,h,d,t]

  // --- scores: per (b,h): q[T,K] @ k[T,K]^T -> S[T,T] (skip upper tiles) ---
  gemm_bt<<<dim3(T / TN, T / TM, B * H), 256, 0, stream>>>(
      qb, kb, T, T, K, KH, KH, T, 2,
      (long long)T * KH, K, (long long)T * KH, K,
      (long long)H * T * T, (long long)T * T, 1.0f,
      nullptr, nullptr, 0, nullptr, S, 1, 0);

  softmax_causal<<<dim3(T, B * H), 256, 0, stream>>>(S, T);

  // --- P @ V: per (b,h): P[T,T] @ v[T,K] -> ao[:, h*K:...] (K-truncated) ---
  gemm_bt<<<dim3(K / TN, T / TM, B * H), 256, 0, stream>>>(
      S, vT, T, K, T, T, T, KH, 2,
      (long long)H * T * T, (long long)T * T,
      (long long)H * K * T, (long long)K * T,
      (long long)T * KH, K, 1.0f,
      nullptr, nullptr, 0, nullptr, ao, 2, 0);

  // --- unify + residual: x1 = x + ao@Wu + bu (fp32 + bf16 copies) ---
  transpose_cast_w<<<dim3(K / 32, KH / 32), 256, 0, stream>>>(Wu, Wbuf, KH, K);
  gemm_bt<<<dim3(K / TN, BT / TM, 1), 256, 0, stream>>>(
      ao, Wbuf, BT, K, KH, KH, KH, K, 0, 0, 0, 0, 0, 0, 0, 1.0f,
      bu, x, 0, x1f, x1b, 0, 0);

  // --- FFN ---
  transpose_cast_w<<<dim3(K / 32, K / 32), 256, 0, stream>>>(W1, Wbuf, K, K);
  gemm_bt<<<dim3(K / TN, BT / TM, 1), 256, 0, stream>>>(
      x1b, Wbuf, BT, K, K, K, K, K, 0, 0, 0, 0, 0, 0, 0, 1.0f,
      b1, nullptr, 1, nullptr, h1, 0, 0);
  transpose_cast_w<<<dim3(K / 32, K / 32), 256, 0, stream>>>(W2, Wbuf, K, K);
  gemm_bt<<<dim3(K / TN, BT / TM, 1), 256, 0, stream>>>(
      h1, Wbuf, BT, K, K, K, K, K, 0, 0, 0, 0, 0, 0, 0, 1.0f,
      b2, x1f, 0, out, nullptr, 0, 0);
}

// Round 3
// 703.756 us; speedup vs baseline: 1.0972x; 1.0972x over previous
//
#include <hip/hip_runtime.h>
#include <math.h>

// ---------------------------------------------------------------------------
// TransformerBlock: B=2, T=2048, K=1024, H=4 (each head gets FULL dim K).
// R2: occupancy/latency attack. (1) QKV fused into one N=12288 GEMM, 1-D
// grid with XCD n-stripe swizzle (12 blocks/CU, W stripe L2-resident), V
// stored transposed from the epilogue. (2) unify/FFN1/FFN2 split-K=4 via the
// z-batch machinery (1024 blocks instead of 256) -> fp32 partials + fused
// reduce/epilogue kernel. (3) scores/PV grids reordered (z on blockIdx.x) so
// bid%8 = XCD = head -> per-XCD L2 locality on q/k/v slices.
// Workspace map (MB): [0,8) xb | [8,32) WqkvT (first 8 reused for Wu/W1/W2^T)
// | [32,96) qkb -> later (ao [32,64), x1f [64,80), x1b [80,88), h1 [88,96))
// | [96,128) vT | [128,192) S -> later split-K partials P. Total 192 MB.
// ---------------------------------------------------------------------------

#define TM 128
#define TN 128
#define BK 32

typedef __attribute__((ext_vector_type(8))) short short8;   // 8 bf16 (4 VGPRs)
typedef __attribute__((ext_vector_type(4))) float f32x4;

__device__ __forceinline__ unsigned short f2bf(float f) {
  union { float f; unsigned int u; } v; v.f = f;
  unsigned int r = (v.u + 0x7fffu + ((v.u >> 16) & 1u)) >> 16;
  return (unsigned short)r;
}
__device__ __forceinline__ float bf2f(unsigned short b) {
  union { unsigned int u; float f; } v; v.u = ((unsigned int)b) << 16;
  return v.f;
}

#define GL2LDS(g, l)                                                          \
  __builtin_amdgcn_global_load_lds(                                           \
      (__attribute__((address_space(1))) void*)(g),                           \
      (__attribute__((address_space(3))) void*)(l), 16, 0, 0)

// Generic bf16 GEMM: C = act(scale*(A @ BT^T) + bias + resid)
// A: [M,Kd] row-major (lda), BT: [N,Kd] row-major (ldb).
// grid_mode: 0 = (x=n, y=m, z=z) ; 2 = (x=z, y=n, z=m)  [XCD = z%8 locality]
//            1 = fused-QKV 1-D swizzle (grid.x=3072; 96 n-tiles x 32 m-tiles,
//                n-stripe of 12 tiles per XCD)
// Batched/split-K via z: off = (z>>bh_shift)*ob + (z&mask)*oh.  Split-K uses
// aob=bob=Kslice (column offset), cob=M*N (partial-slice offset), Kd=Kslice.
// causal_mode: 0=none, 1=skip tiles fully above diagonal, 2=truncate K at
// m0+TM. c_qkv: fused epilogue (cols<8192 -> qkb scaled; cols>=8192 -> vT
// [b,h*K+d,t] store, unscaled).
__global__ __launch_bounds__(256) void gemm_bt(
    const unsigned short* __restrict__ A, const unsigned short* __restrict__ BT,
    int Kd, int lda, int ldb, int ldc, int bh_shift,
    long long aob, long long aoh, long long bob, long long boh,
    long long cob, long long coh, float scale,
    const float* __restrict__ bias, const float* __restrict__ resid,
    int do_relu, float* __restrict__ Cf, unsigned short* __restrict__ Cb,
    unsigned short* __restrict__ Cb2, int causal_mode, int c_qkv,
    int grid_mode) {
  int n0, m0, z;
  if (grid_mode == 1) {            // fused QKV: 3072 blocks, XCD n-stripes
    const int bid = blockIdx.x;
    const int xcd = bid & 7;
    const int j = bid >> 3;        // [0,384)
    n0 = (xcd * 12 + (j % 12)) * TN;
    m0 = (j / 12) * TM;
    z = 0;
  } else if (grid_mode == 2) {     // z on x: bid%8 = XCD = z
    z = blockIdx.x; n0 = blockIdx.y * TN; m0 = blockIdx.z * TM;
  } else {
    n0 = blockIdx.x * TN; m0 = blockIdx.y * TM; z = blockIdx.z;
  }
  if (causal_mode == 1 && n0 >= m0 + TM) return;  // fully-masked tile

  const int zb = z >> bh_shift;
  const int zh = z & ((1 << bh_shift) - 1);
  const long long aoff = (long long)zb * aob + (long long)zh * aoh;
  const long long boff = (long long)zb * bob + (long long)zh * boh;
  const long long coff = (long long)zb * cob + (long long)zh * coh;

  __shared__ unsigned short As[TM * BK];  // [128][32], row-major, no pad
  __shared__ unsigned short Bs[TN * BK];  // (global_load_lds needs exact order)

  const int tid = threadIdx.x;
  const int lane = tid & 63;
  const int wv = tid >> 6;
  const int wm = wv & 1;   // 2x2 wave grid over 128x128 tile
  const int wn = wv >> 1;

  const int srow = tid >> 2;
  const int scol = (tid & 3) * 8;
  const unsigned short* ap0 = A + aoff + (long long)(m0 + srow) * lda + scol;
  const unsigned short* ap1 = A + aoff + (long long)(m0 + srow + 64) * lda + scol;
  const unsigned short* bp0 = BT + boff + (long long)(n0 + srow) * ldb + scol;
  const unsigned short* bp1 = BT + boff + (long long)(n0 + srow + 64) * ldb + scol;
  unsigned short* lA0 = As + wv * 512;          // wave-uniform LDS bases
  unsigned short* lA1 = As + 2048 + wv * 512;
  unsigned short* lB0 = Bs + wv * 512;
  unsigned short* lB1 = Bs + 2048 + wv * 512;

  f32x4 acc[4][4];
#pragma unroll
  for (int i = 0; i < 4; ++i)
#pragma unroll
    for (int j2 = 0; j2 < 4; ++j2) acc[i][j2] = {0.f, 0.f, 0.f, 0.f};

  int kmax = Kd;
  if (causal_mode == 2) { int t = m0 + TM; if (t < kmax) kmax = t; }

  const int frow = lane & 15;          // m (or n) within 16x16
  const int fq = (lane >> 4) * 8;      // k chunk

  for (int k0 = 0; k0 < kmax; k0 += BK) {
    __syncthreads();                   // prev iter's ds_reads done
    GL2LDS(ap0, lA0);
    GL2LDS(ap1, lA1);
    GL2LDS(bp0, lB0);
    GL2LDS(bp1, lB1);
    ap0 += BK; ap1 += BK; bp0 += BK; bp1 += BK;
    __syncthreads();                   // vmcnt(0) drain -> LDS visible

    short8 af[4], bf[4];
#pragma unroll
    for (int mi = 0; mi < 4; ++mi)
      af[mi] = *(const short8*)(As + (wm * 64 + mi * 16 + frow) * BK + fq);
#pragma unroll
    for (int ni = 0; ni < 4; ++ni)
      bf[ni] = *(const short8*)(Bs + (wn * 64 + ni * 16 + frow) * BK + fq);
#pragma unroll
    for (int mi = 0; mi < 4; ++mi)
#pragma unroll
      for (int ni = 0; ni < 4; ++ni)
        acc[mi][ni] = __builtin_amdgcn_mfma_f32_16x16x32_bf16(
            af[mi], bf[ni], acc[mi][ni], 0, 0, 0);
  }

  // epilogue: C/D layout col=lane&15, row=(lane>>4)*4+r (m89-verified)
  const int ccol = lane & 15;
  const int crow = (lane >> 4) * 4;
#pragma unroll
  for (int mi = 0; mi < 4; ++mi) {
#pragma unroll
    for (int ni = 0; ni < 4; ++ni) {
      const int gc = n0 + wn * 64 + ni * 16 + ccol;
#pragma unroll
      for (int r = 0; r < 4; ++r) {
        const int gr = m0 + wm * 64 + mi * 16 + crow + r;
        float v = acc[mi][ni][r];
        if (c_qkv) {
          if (gc < 8192) {             // q|k: scaled, [4096, 8192] row-major
            Cb[(long long)gr * 8192 + gc] = f2bf(v * scale);
          } else {                     // v -> vT[b, h*K+d, t]
            const int dd = gc - 8192;
            Cb2[((long long)((gr >> 11) * 4096 + dd)) * 2048 + (gr & 2047)] =
                f2bf(v);
          }
        } else {
          v *= scale;
          if (bias) v += bias[gc];
          if (resid) v += resid[(long long)gr * ldc + gc];
          if (do_relu) v = fmaxf(v, 0.f);
          const long long ci = coff + (long long)gr * ldc + gc;
          if (Cf) Cf[ci] = v;
          if (Cb) Cb[ci] = f2bf(v);
        }
      }
    }
  }
}

// Split-K reduce + epilogue: out = act(sum_s P[s] + bias + resid), float4.
// N must be 1024 here (bias index = (i*4)&1023).
__global__ __launch_bounds__(256) void reduce_epi(
    const float* __restrict__ P, int S, long long MN,
    const float* __restrict__ bias, const float* __restrict__ resid,
    int do_relu, float* __restrict__ Cf, unsigned short* __restrict__ Cb) {
  const long long i4 = ((long long)blockIdx.x * 256 + threadIdx.x) * 4;
  if (i4 >= MN) return;
  float4 s = {0.f, 0.f, 0.f, 0.f};
  for (int t = 0; t < S; ++t) {
    const float4 p = *(const float4*)(P + (long long)t * MN + i4);
    s.x += p.x; s.y += p.y; s.z += p.z; s.w += p.w;
  }
  if (bias) {
    const int c0 = (int)(i4 & 1023);
    s.x += bias[c0]; s.y += bias[c0 + 1]; s.z += bias[c0 + 2]; s.w += bias[c0 + 3];
  }
  if (resid) {
    const float4 rr = *(const float4*)(resid + i4);
    s.x += rr.x; s.y += rr.y; s.z += rr.z; s.w += rr.w;
  }
  if (do_relu) {
    s.x = fmaxf(s.x, 0.f); s.y = fmaxf(s.y, 0.f);
    s.z = fmaxf(s.z, 0.f); s.w = fmaxf(s.w, 0.f);
  }
  if (Cf) *(float4*)(Cf + i4) = s;
  if (Cb) {
    ushort4 o;
    o.x = f2bf(s.x); o.y = f2bf(s.y); o.z = f2bf(s.z); o.w = f2bf(s.w);
    *(ushort4*)(Cb + i4) = o;
  }
}

// Row-wise causal softmax, in-place on bf16 scores. grid=(T, B*H), block=256.
__global__ __launch_bounds__(256) void softmax_causal(unsigned short* S, int T) {
  const int q = blockIdx.x;
  unsigned short* row = S + ((long long)blockIdx.y * T + q) * T;
  const int tid = threadIdx.x;
  const int lane = tid & 63;
  const int wv = tid >> 6;
  const int n = q + 1;
  float vals[8];
  float m = -__builtin_inff();
#pragma unroll
  for (int i = 0; i < 8; ++i) {
    int idx = i * 256 + tid;
    vals[i] = (idx < n) ? bf2f(row[idx]) : -__builtin_inff();
    m = fmaxf(m, vals[i]);
  }
#pragma unroll
  for (int o = 32; o; o >>= 1) m = fmaxf(m, __shfl_xor(m, o, 64));
  __shared__ float red[4];
  if (lane == 0) red[wv] = m;
  __syncthreads();
  m = fmaxf(fmaxf(red[0], red[1]), fmaxf(red[2], red[3]));
  __syncthreads();
  float s = 0.f, e[8];
#pragma unroll
  for (int i = 0; i < 8; ++i) {
    int idx = i * 256 + tid;
    e[i] = (idx < n) ? __expf(vals[i] - m) : 0.f;
    s += e[i];
  }
#pragma unroll
  for (int o = 32; o; o >>= 1) s += __shfl_xor(s, o, 64);
  if (lane == 0) red[wv] = s;
  __syncthreads();
  s = red[0] + red[1] + red[2] + red[3];
  const float inv = 1.f / s;
#pragma unroll
  for (int i = 0; i < 8; ++i) {
    int idx = i * 256 + tid;
    row[idx] = f2bf(e[i] * inv);  // idx in [0,2048) always; zeros past n
  }
}

// fp32 -> bf16 elementwise (n divisible by 4)
__global__ __launch_bounds__(256) void cast_bf16(const float* __restrict__ in,
                                                 unsigned short* __restrict__ out,
                                                 int n4) {
  int i = blockIdx.x * 256 + threadIdx.x;
  if (i < n4) {
    const float4 v = *(const float4*)(in + (long long)i * 4);
    ushort4 o;
    o.x = f2bf(v.x); o.y = f2bf(v.y); o.z = f2bf(v.z); o.w = f2bf(v.w);
    *(ushort4*)(out + (long long)i * 4) = o;
  }
}

// W[R,C] fp32 -> WT[C,R] bf16.  grid=(C/32, R/32), block=256.
__global__ __launch_bounds__(256) void transpose_cast_w(
    const float* __restrict__ W, unsigned short* __restrict__ WT, int R, int C) {
  __shared__ float tile[32][33];
  const int c0 = blockIdx.x * 32;
  const int r0 = blockIdx.y * 32;
  const int tx = threadIdx.x & 31;
  const int ty = threadIdx.x >> 5;  // 0..7
#pragma unroll
  for (int j = 0; j < 32; j += 8)
    tile[ty + j][tx] = W[(long long)(r0 + ty + j) * C + c0 + tx];
  __syncthreads();
#pragma unroll
  for (int j = 0; j < 32; j += 8)
    WT[(long long)(c0 + ty + j) * R + r0 + tx] = f2bf(tile[tx][ty + j]);
}

extern "C" void kernel_launch(void* const* d_in, const int* in_sizes, int n_in,
                              void* d_out, int out_size, void* d_ws,
                              size_t ws_size, hipStream_t stream) {
  (void)in_sizes; (void)n_in; (void)out_size; (void)ws_size;
  const float* x  = (const float*)d_in[0];
  const float* Wq = (const float*)d_in[1];
  const float* Wk = (const float*)d_in[2];
  const float* Wv = (const float*)d_in[3];
  const float* Wu = (const float*)d_in[4];
  const float* bu = (const float*)d_in[5];
  const float* W1 = (const float*)d_in[6];
  const float* b1 = (const float*)d_in[7];
  const float* W2 = (const float*)d_in[8];
  const float* b2 = (const float*)d_in[9];
  float* out = (float*)d_out;

  const int B = 2, T = 2048, K = 1024, H = 4;
  const int BT = B * T;   // 4096
  const int KH = K * H;   // 4096
  const size_t MB = 1024 * 1024;

  char* w = (char*)d_ws;
  unsigned short* xb    = (unsigned short*)(w + 0 * MB);    //  8 MB
  unsigned short* WqkvT = (unsigned short*)(w + 8 * MB);    // 24 MB [12288,1024]
  unsigned short* Wbuf  = WqkvT;                            //  8 MB reuse
  unsigned short* qkb   = (unsigned short*)(w + 32 * MB);   // 64 MB [4096,8192]
  unsigned short* vT    = (unsigned short*)(w + 96 * MB);   // 32 MB [b,h*K+d,t]
  unsigned short* S     = (unsigned short*)(w + 128 * MB);  // 64 MB
  unsigned short* ao    = (unsigned short*)(w + 32 * MB);   // alias qkb
  float*          x1f   = (float*)(w + 64 * MB);            // alias qkb
  unsigned short* x1b   = (unsigned short*)(w + 80 * MB);   // alias qkb
  unsigned short* h1    = (unsigned short*)(w + 88 * MB);   // alias qkb
  float*          P     = (float*)(w + 128 * MB);           // alias S, 64 MB

  const float scale = 0.17677669529663689f;  // 1024^-0.25
  const long long MN = (long long)BT * K;    // 4 Mi elements

  cast_bf16<<<dim3(BT * K / 4 / 256), 256, 0, stream>>>(x, xb, BT * K / 4);

  // --- fused QKV: W^T rows [0,4096)=Wq, [4096,8192)=Wk, [8192,12288)=Wv ---
  transpose_cast_w<<<dim3(KH / 32, K / 32), 256, 0, stream>>>(Wq, WqkvT, K, KH);
  transpose_cast_w<<<dim3(KH / 32, K / 32), 256, 0, stream>>>(
      Wk, WqkvT + (size_t)4096 * 1024, K, KH);
  transpose_cast_w<<<dim3(KH / 32, K / 32), 256, 0, stream>>>(
      Wv, WqkvT + (size_t)8192 * 1024, K, KH);
  gemm_bt<<<dim3(3072), 256, 0, stream>>>(
      xb, WqkvT, K, K, K, 8192, 0, 0, 0, 0, 0, 0, 0, scale,
      nullptr, nullptr, 0, nullptr, qkb, vT, 0, 1, 1);

  // --- scores: z(=b*4+h) on x so bid%8=XCD=head; q|k from qkb ---
  gemm_bt<<<dim3(8, T / TN, T / TM), 256, 0, stream>>>(
      qkb, qkb + 4096, K, 8192, 8192, T, 2,
      (long long)T * 8192, 1024, (long long)T * 8192, 1024,
      (long long)H * T * T, (long long)T * T, 1.0f,
      nullptr, nullptr, 0, nullptr, S, nullptr, 1, 0, 2);

  softmax_causal<<<dim3(T, B * H), 256, 0, stream>>>(S, T);

  // --- P @ V: z on x again; K-truncated at diagonal ---
  gemm_bt<<<dim3(8, K / TN, T / TM), 256, 0, stream>>>(
      S, vT, T, T, T, KH, 2,
      (long long)H * T * T, (long long)T * T,
      (long long)H * K * T, (long long)K * T,
      (long long)T * KH, K, 1.0f,
      nullptr, nullptr, 0, nullptr, ao, nullptr, 2, 0, 2);

  // --- unify: split-K=4 (slices of 1024) -> fp32 partials P ---
  transpose_cast_w<<<dim3(K / 32, KH / 32), 256, 0, stream>>>(Wu, Wbuf, KH, K);
  gemm_bt<<<dim3(K / TN, BT / TM, 4), 256, 0, stream>>>(
      ao, Wbuf, 1024, KH, KH, K, 0,
      1024, 0, 1024, 0, MN, 0, 1.0f,
      nullptr, nullptr, 0, P, nullptr, nullptr, 0, 0, 0);
  reduce_epi<<<dim3(4096), 256, 0, stream>>>(P, 4, MN, bu, x, 0, x1f, x1b);

  // --- FFN1: split-K=4 (slices of 256), relu in reduce ---
  transpose_cast_w<<<dim3(K / 32, K / 32), 256, 0, stream>>>(W1, Wbuf, K, K);
  gemm_bt<<<dim3(K / TN, BT / TM, 4), 256, 0, stream>>>(
      x1b, Wbuf, 256, K, K, K, 0,
      256, 0, 256, 0, MN, 0, 1.0f,
      nullptr, nullptr, 0, P, nullptr, nullptr, 0, 0, 0);
  reduce_epi<<<dim3(4096), 256, 0, stream>>>(P, 4, MN, b1, nullptr, 1, nullptr, h1);

  // --- FFN2: split-K=4, + b2 + x1 residual -> out ---
  transpose_cast_w<<<dim3(K / 32, K / 32), 256, 0, stream>>>(W2, Wbuf, K, K);
  gemm_bt<<<dim3(K / TN, BT / TM, 4), 256, 0, stream>>>(
      h1, Wbuf, 256, K, K, K, 0,
      256, 0, 256, 0, MN, 0, 1.0f,
      nullptr, nullptr, 0, P, nullptr, nullptr, 0, 0, 0);
  reduce_epi<<<dim3(4096), 256, 0, stream>>>(P, 4, MN, b2, x1f, 0, out, nullptr);
}

// Round 4
// 588.095 us; speedup vs baseline: 1.3130x; 1.1967x over previous
//
#include <hip/hip_runtime.h>
#include <math.h>

// ---------------------------------------------------------------------------
// TransformerBlock: B=2, T=2048, K=1024, H=4 (each head gets FULL dim K).
// R3: (1) QKV epilogue stores V row-major; separate coalesced transpose_v
// builds vT (removes 4KB-stride 2B scatter). (2) BK=64 K-tiles via dual
// 32-col LDS halves (8 global_load_lds + 2 barriers per 64-K vs per 32-K).
// (3) prep launches batched (prep_qkv, prep_w). (4) softmax writes zeros only
// to next 128 boundary. Split-K=4 + reduce_epi kept for unify/FFN.
// Workspace (MB): [0,8) xb | [8,32) WqkvT -> (WuT [8,16), W1T [16,18),
// W2T [18,20)) | [32,96) qkb -> (ao [32,64), x1f [64,80), x1b [80,88),
// h1 [88,96)) | [96,128) vT | [128,192) vb -> S -> split-K partials P.
// ---------------------------------------------------------------------------

#define TM 128
#define TN 128
#define BK 64

typedef __attribute__((ext_vector_type(8))) short short8;   // 8 bf16 (4 VGPRs)
typedef __attribute__((ext_vector_type(4))) float f32x4;

__device__ __forceinline__ unsigned short f2bf(float f) {
  union { float f; unsigned int u; } v; v.f = f;
  unsigned int r = (v.u + 0x7fffu + ((v.u >> 16) & 1u)) >> 16;
  return (unsigned short)r;
}
__device__ __forceinline__ float bf2f(unsigned short b) {
  union { unsigned int u; float f; } v; v.u = ((unsigned int)b) << 16;
  return v.f;
}

#define GL2LDS(g, l)                                                          \
  __builtin_amdgcn_global_load_lds(                                           \
      (__attribute__((address_space(1))) void*)(g),                           \
      (__attribute__((address_space(3))) void*)(l), 16, 0, 0)

// Generic bf16 GEMM: C = act(scale*(A @ BT^T) + bias + resid)
// A: [M,Kd] row-major (lda), BT: [N,Kd] row-major (ldb).
// grid_mode: 0 = (x=n, y=m, z=z); 2 = (x=z, y=n, z=m) [XCD = z%8 locality];
//            1 = fused-QKV 1-D swizzle (grid.x=3072; 96 n x 32 m tiles,
//                12-tile n-stripe per XCD)
// Split-K via z: off = (z>>bh_shift)*ob + (z&mask)*oh; aob=bob=Kslice,
// cob=M*N, Kd=Kslice. causal_mode: 1=skip tiles above diagonal, 2=truncate
// K at m0+TM. c_qkv: cols<8192 -> Cb=qkb (scaled); cols>=8192 -> Cb2=vb
// row-major [4096] (unscaled).
__global__ __launch_bounds__(256) void gemm_bt(
    const unsigned short* __restrict__ A, const unsigned short* __restrict__ BT,
    int Kd, int lda, int ldb, int ldc, int bh_shift,
    long long aob, long long aoh, long long bob, long long boh,
    long long cob, long long coh, float scale,
    const float* __restrict__ bias, const float* __restrict__ resid,
    int do_relu, float* __restrict__ Cf, unsigned short* __restrict__ Cb,
    unsigned short* __restrict__ Cb2, int causal_mode, int c_qkv,
    int grid_mode) {
  int n0, m0, z;
  if (grid_mode == 1) {            // fused QKV: 3072 blocks, XCD n-stripes
    const int bid = blockIdx.x;
    const int xcd = bid & 7;
    const int j = bid >> 3;        // [0,384)
    n0 = (xcd * 12 + (j % 12)) * TN;
    m0 = (j / 12) * TM;
    z = 0;
  } else if (grid_mode == 2) {     // z on x: bid%8 = XCD = z
    z = blockIdx.x; n0 = blockIdx.y * TN; m0 = blockIdx.z * TM;
  } else {
    n0 = blockIdx.x * TN; m0 = blockIdx.y * TM; z = blockIdx.z;
  }
  if (causal_mode == 1 && n0 >= m0 + TM) return;  // fully-masked tile

  const int zb = z >> bh_shift;
  const int zh = z & ((1 << bh_shift) - 1);
  const long long aoff = (long long)zb * aob + (long long)zh * aoh;
  const long long boff = (long long)zb * bob + (long long)zh * boh;
  const long long coff = (long long)zb * cob + (long long)zh * coh;

  // dual 32-col halves: [2][128][32] ushort each => 16KB + 16KB
  __shared__ unsigned short As[8192];
  __shared__ unsigned short Bs[8192];

  const int tid = threadIdx.x;
  const int lane = tid & 63;
  const int wv = tid >> 6;
  const int wm = wv & 1;   // 2x2 wave grid over 128x128 tile
  const int wn = wv >> 1;

  const int srow = tid >> 2;            // 0..63
  const int scol = (tid & 3) * 8;       // 0,8,16,24 within a 32-col half
  const unsigned short* ap0 = A + aoff + (long long)(m0 + srow) * lda + scol;
  const unsigned short* ap1 = ap0 + (long long)64 * lda;
  const unsigned short* bp0 = BT + boff + (long long)(n0 + srow) * ldb + scol;
  const unsigned short* bp1 = bp0 + (long long)64 * ldb;
  // wave-uniform LDS bases (shorts): half h at h*4096, rows[64,128) at +2048
  unsigned short* lA00 = As + wv * 512;
  unsigned short* lA10 = As + 2048 + wv * 512;
  unsigned short* lA01 = As + 4096 + wv * 512;
  unsigned short* lA11 = As + 6144 + wv * 512;
  unsigned short* lB00 = Bs + wv * 512;
  unsigned short* lB10 = Bs + 2048 + wv * 512;
  unsigned short* lB01 = Bs + 4096 + wv * 512;
  unsigned short* lB11 = Bs + 6144 + wv * 512;

  f32x4 acc[4][4];
#pragma unroll
  for (int i = 0; i < 4; ++i)
#pragma unroll
    for (int j2 = 0; j2 < 4; ++j2) acc[i][j2] = {0.f, 0.f, 0.f, 0.f};

  int kmax = Kd;
  if (causal_mode == 2) { int t = m0 + TM; if (t < kmax) kmax = t; }

  const int frow = lane & 15;          // m (or n) within 16x16
  const int fq = (lane >> 4) * 8;      // k chunk within 32-col half

  for (int k0 = 0; k0 < kmax; k0 += BK) {
    __syncthreads();                   // prev iter's ds_reads done
    GL2LDS(ap0, lA00); GL2LDS(ap0 + 32, lA01);
    GL2LDS(ap1, lA10); GL2LDS(ap1 + 32, lA11);
    GL2LDS(bp0, lB00); GL2LDS(bp0 + 32, lB01);
    GL2LDS(bp1, lB10); GL2LDS(bp1 + 32, lB11);
    ap0 += BK; ap1 += BK; bp0 += BK; bp1 += BK;
    __syncthreads();                   // vmcnt(0) drain -> LDS visible

#pragma unroll
    for (int s = 0; s < 2; ++s) {      // k-step of 32 per half
      short8 afr[4], bfr[4];
#pragma unroll
      for (int mi = 0; mi < 4; ++mi)
        afr[mi] = *(const short8*)(As + s * 4096 +
                                   (wm * 64 + mi * 16 + frow) * 32 + fq);
#pragma unroll
      for (int ni = 0; ni < 4; ++ni)
        bfr[ni] = *(const short8*)(Bs + s * 4096 +
                                   (wn * 64 + ni * 16 + frow) * 32 + fq);
#pragma unroll
      for (int mi = 0; mi < 4; ++mi)
#pragma unroll
        for (int ni = 0; ni < 4; ++ni)
          acc[mi][ni] = __builtin_amdgcn_mfma_f32_16x16x32_bf16(
              afr[mi], bfr[ni], acc[mi][ni], 0, 0, 0);
    }
  }

  // epilogue: C/D layout col=lane&15, row=(lane>>4)*4+r (m89-verified)
  const int ccol = lane & 15;
  const int crow = (lane >> 4) * 4;
#pragma unroll
  for (int mi = 0; mi < 4; ++mi) {
#pragma unroll
    for (int ni = 0; ni < 4; ++ni) {
      const int gc = n0 + wn * 64 + ni * 16 + ccol;
#pragma unroll
      for (int r = 0; r < 4; ++r) {
        const int gr = m0 + wm * 64 + mi * 16 + crow + r;
        float v = acc[mi][ni][r];
        if (c_qkv) {
          if (gc < 8192) {             // q|k: scaled, row-major [4096,8192]
            Cb[(long long)gr * 8192 + gc] = f2bf(v * scale);
          } else {                     // v: row-major vb [4096,4096]
            Cb2[(long long)gr * 4096 + (gc - 8192)] = f2bf(v);
          }
        } else {
          v *= scale;
          if (bias) v += bias[gc];
          if (resid) v += resid[(long long)gr * ldc + gc];
          if (do_relu) v = fmaxf(v, 0.f);
          const long long ci = coff + (long long)gr * ldc + gc;
          if (Cf) Cf[ci] = v;
          if (Cb) Cb[ci] = f2bf(v);
        }
      }
    }
  }
}

// Split-K reduce + epilogue: out = act(sum_s P[s] + bias + resid), float4.
// N must be 1024 (bias index = (i*4)&1023).
__global__ __launch_bounds__(256) void reduce_epi(
    const float* __restrict__ P, int S, long long MN,
    const float* __restrict__ bias, const float* __restrict__ resid,
    int do_relu, float* __restrict__ Cf, unsigned short* __restrict__ Cb) {
  const long long i4 = ((long long)blockIdx.x * 256 + threadIdx.x) * 4;
  if (i4 >= MN) return;
  float4 s = {0.f, 0.f, 0.f, 0.f};
  for (int t = 0; t < S; ++t) {
    const float4 p = *(const float4*)(P + (long long)t * MN + i4);
    s.x += p.x; s.y += p.y; s.z += p.z; s.w += p.w;
  }
  if (bias) {
    const int c0 = (int)(i4 & 1023);
    s.x += bias[c0]; s.y += bias[c0 + 1]; s.z += bias[c0 + 2]; s.w += bias[c0 + 3];
  }
  if (resid) {
    const float4 rr = *(const float4*)(resid + i4);
    s.x += rr.x; s.y += rr.y; s.z += rr.z; s.w += rr.w;
  }
  if (do_relu) {
    s.x = fmaxf(s.x, 0.f); s.y = fmaxf(s.y, 0.f);
    s.z = fmaxf(s.z, 0.f); s.w = fmaxf(s.w, 0.f);
  }
  if (Cf) *(float4*)(Cf + i4) = s;
  if (Cb) {
    ushort4 o;
    o.x = f2bf(s.x); o.y = f2bf(s.y); o.z = f2bf(s.z); o.w = f2bf(s.w);
    *(ushort4*)(Cb + i4) = o;
  }
}

// Row-wise causal softmax, in-place on bf16 scores. grid=(T, B*H), block=256.
// Row q: q+1 valid entries; zeros written only to next 128 boundary (PV
// truncates K there).
__global__ __launch_bounds__(256) void softmax_causal(unsigned short* S, int T) {
  const int q = blockIdx.x;
  unsigned short* row = S + ((long long)blockIdx.y * T + q) * T;
  const int tid = threadIdx.x;
  const int lane = tid & 63;
  const int wv = tid >> 6;
  const int n = q + 1;
  const int nz = (n + 127) & ~127;     // write limit
  float vals[8];
  float m = -__builtin_inff();
#pragma unroll
  for (int i = 0; i < 8; ++i) {
    int idx = i * 256 + tid;
    vals[i] = (idx < n) ? bf2f(row[idx]) : -__builtin_inff();
    m = fmaxf(m, vals[i]);
  }
#pragma unroll
  for (int o = 32; o; o >>= 1) m = fmaxf(m, __shfl_xor(m, o, 64));
  __shared__ float red[4];
  if (lane == 0) red[wv] = m;
  __syncthreads();
  m = fmaxf(fmaxf(red[0], red[1]), fmaxf(red[2], red[3]));
  __syncthreads();
  float s = 0.f, e[8];
#pragma unroll
  for (int i = 0; i < 8; ++i) {
    int idx = i * 256 + tid;
    e[i] = (idx < n) ? __expf(vals[i] - m) : 0.f;
    s += e[i];
  }
#pragma unroll
  for (int o = 32; o; o >>= 1) s += __shfl_xor(s, o, 64);
  if (lane == 0) red[wv] = s;
  __syncthreads();
  s = red[0] + red[1] + red[2] + red[3];
  const float inv = 1.f / s;
#pragma unroll
  for (int i = 0; i < 8; ++i) {
    int idx = i * 256 + tid;
    if (idx < nz) row[idx] = f2bf(e[i] * inv);
  }
}

// fp32 -> bf16 elementwise (n divisible by 4)
__global__ __launch_bounds__(256) void cast_bf16(const float* __restrict__ in,
                                                 unsigned short* __restrict__ out,
                                                 int n4) {
  int i = blockIdx.x * 256 + threadIdx.x;
  if (i < n4) {
    const float4 v = *(const float4*)(in + (long long)i * 4);
    ushort4 o;
    o.x = f2bf(v.x); o.y = f2bf(v.y); o.z = f2bf(v.z); o.w = f2bf(v.w);
    *(ushort4*)(out + (long long)i * 4) = o;
  }
}

// Batched Wq/Wk/Wv [1024,4096] fp32 -> WT [z][4096,1024] bf16.
// grid=(128, 32, 3), block=256.
__global__ __launch_bounds__(256) void prep_qkv(
    const float* __restrict__ Wq, const float* __restrict__ Wk,
    const float* __restrict__ Wv, unsigned short* __restrict__ dst) {
  const int z = blockIdx.z;
  const float* W = (z == 0) ? Wq : (z == 1) ? Wk : Wv;
  unsigned short* WT = dst + (size_t)z * 4096 * 1024;
  __shared__ float tile[32][33];
  const int c0 = blockIdx.x * 32;      // over C=4096
  const int r0 = blockIdx.y * 32;      // over R=1024
  const int tx = threadIdx.x & 31;
  const int ty = threadIdx.x >> 5;
#pragma unroll
  for (int j = 0; j < 32; j += 8)
    tile[ty + j][tx] = W[(long long)(r0 + ty + j) * 4096 + c0 + tx];
  __syncthreads();
#pragma unroll
  for (int j = 0; j < 32; j += 8)
    WT[(long long)(c0 + ty + j) * 1024 + r0 + tx] = f2bf(tile[tx][ty + j]);
}

// Batched Wu[4096,1024]/W1[1024,1024]/W2[1024,1024] -> WT bf16 at
// dst + {0, 4Mi, 5Mi} shorts. grid=(32, 128, 3), block=256.
__global__ __launch_bounds__(256) void prep_w(
    const float* __restrict__ Wu, const float* __restrict__ W1,
    const float* __restrict__ W2, unsigned short* __restrict__ dst) {
  const int z = blockIdx.z;
  const int R = (z == 0) ? 4096 : 1024;
  if (blockIdx.y * 32 >= R) return;
  const float* W = (z == 0) ? Wu : (z == 1) ? W1 : W2;
  unsigned short* WT =
      dst + ((z == 0) ? 0 : (z == 1) ? (size_t)4096 * 1024
                                     : (size_t)4096 * 1024 + 1024 * 1024);
  __shared__ float tile[32][33];
  const int c0 = blockIdx.x * 32;      // over C=1024
  const int r0 = blockIdx.y * 32;      // over R
  const int tx = threadIdx.x & 31;
  const int ty = threadIdx.x >> 5;
#pragma unroll
  for (int j = 0; j < 32; j += 8)
    tile[ty + j][tx] = W[(long long)(r0 + ty + j) * 1024 + c0 + tx];
  __syncthreads();
#pragma unroll
  for (int j = 0; j < 32; j += 8)
    WT[(long long)(c0 + ty + j) * R + r0 + tx] = f2bf(tile[tx][ty + j]);
}

// vb [b*2048+t][4096] -> vT [b*4096+hd][2048]. grid=(64, 128, 2), block=256.
__global__ __launch_bounds__(256) void transpose_v(
    const unsigned short* __restrict__ vb, unsigned short* __restrict__ vT) {
  __shared__ unsigned short tile[32][33];
  const int t0 = blockIdx.x * 32;
  const int d0 = blockIdx.y * 32;
  const int b = blockIdx.z;
  const int tx = threadIdx.x & 31;
  const int ty = threadIdx.x >> 5;
#pragma unroll
  for (int j = 0; j < 32; j += 8)
    tile[ty + j][tx] =
        vb[(long long)(b * 2048 + t0 + ty + j) * 4096 + d0 + tx];
  __syncthreads();
#pragma unroll
  for (int j = 0; j < 32; j += 8)
    vT[(long long)(b * 4096 + d0 + ty + j) * 2048 + t0 + tx] =
        tile[tx][ty + j];
}

extern "C" void kernel_launch(void* const* d_in, const int* in_sizes, int n_in,
                              void* d_out, int out_size, void* d_ws,
                              size_t ws_size, hipStream_t stream) {
  (void)in_sizes; (void)n_in; (void)out_size; (void)ws_size;
  const float* x  = (const float*)d_in[0];
  const float* Wq = (const float*)d_in[1];
  const float* Wk = (const float*)d_in[2];
  const float* Wv = (const float*)d_in[3];
  const float* Wu = (const float*)d_in[4];
  const float* bu = (const float*)d_in[5];
  const float* W1 = (const float*)d_in[6];
  const float* b1 = (const float*)d_in[7];
  const float* W2 = (const float*)d_in[8];
  const float* b2 = (const float*)d_in[9];
  float* out = (float*)d_out;

  const int B = 2, T = 2048, K = 1024, H = 4;
  const int BT = B * T;   // 4096
  const int KH = K * H;   // 4096
  const size_t MB = 1024 * 1024;

  char* w = (char*)d_ws;
  unsigned short* xb    = (unsigned short*)(w + 0 * MB);    //  8 MB
  unsigned short* WqkvT = (unsigned short*)(w + 8 * MB);    // 24 MB
  unsigned short* Wpk   = WqkvT;             // WuT/W1T/W2T after QKV
  unsigned short* WuT   = WqkvT;                            //  8 MB
  unsigned short* W1T   = (unsigned short*)(w + 16 * MB);   //  2 MB
  unsigned short* W2T   = (unsigned short*)(w + 18 * MB);   //  2 MB
  unsigned short* qkb   = (unsigned short*)(w + 32 * MB);   // 64 MB [4096,8192]
  unsigned short* vT    = (unsigned short*)(w + 96 * MB);   // 32 MB [b*4096+hd,t]
  unsigned short* vb    = (unsigned short*)(w + 128 * MB);  // 32 MB (dies -> S)
  unsigned short* S     = (unsigned short*)(w + 128 * MB);  // 64 MB
  unsigned short* ao    = (unsigned short*)(w + 32 * MB);   // alias qkb
  float*          x1f   = (float*)(w + 64 * MB);            // alias qkb
  unsigned short* x1b   = (unsigned short*)(w + 80 * MB);   // alias qkb
  unsigned short* h1    = (unsigned short*)(w + 88 * MB);   // alias qkb
  float*          P     = (float*)(w + 128 * MB);           // alias S, 64 MB

  const float scale = 0.17677669529663689f;  // 1024^-0.25
  const long long MN = (long long)BT * K;    // 4 Mi elements

  cast_bf16<<<dim3(BT * K / 4 / 256), 256, 0, stream>>>(x, xb, BT * K / 4);
  prep_qkv<<<dim3(128, 32, 3), 256, 0, stream>>>(Wq, Wk, Wv, WqkvT);

  // --- fused QKV: q|k -> qkb row-major, v -> vb row-major ---
  gemm_bt<<<dim3(3072), 256, 0, stream>>>(
      xb, WqkvT, K, K, K, 8192, 0, 0, 0, 0, 0, 0, 0, scale,
      nullptr, nullptr, 0, nullptr, qkb, vb, 0, 1, 1);

  transpose_v<<<dim3(64, 128, 2), 256, 0, stream>>>(vb, vT);
  prep_w<<<dim3(32, 128, 3), 256, 0, stream>>>(Wu, W1, W2, Wpk);

  // --- scores: z(=b*4+h) on x so bid%8=XCD; q|k from qkb ---
  gemm_bt<<<dim3(8, T / TN, T / TM), 256, 0, stream>>>(
      qkb, qkb + 4096, K, 8192, 8192, T, 2,
      (long long)T * 8192, 1024, (long long)T * 8192, 1024,
      (long long)H * T * T, (long long)T * T, 1.0f,
      nullptr, nullptr, 0, nullptr, S, nullptr, 1, 0, 2);

  softmax_causal<<<dim3(T, B * H), 256, 0, stream>>>(S, T);

  // --- P @ V: K-truncated at diagonal ---
  gemm_bt<<<dim3(8, K / TN, T / TM), 256, 0, stream>>>(
      S, vT, T, T, T, KH, 2,
      (long long)H * T * T, (long long)T * T,
      (long long)H * K * T, (long long)K * T,
      (long long)T * KH, K, 1.0f,
      nullptr, nullptr, 0, nullptr, ao, nullptr, 2, 0, 2);

  // --- unify: split-K=4 -> fp32 partials, then fused reduce/epilogue ---
  gemm_bt<<<dim3(K / TN, BT / TM, 4), 256, 0, stream>>>(
      ao, WuT, 1024, KH, KH, K, 0,
      1024, 0, 1024, 0, MN, 0, 1.0f,
      nullptr, nullptr, 0, P, nullptr, nullptr, 0, 0, 0);
  reduce_epi<<<dim3(4096), 256, 0, stream>>>(P, 4, MN, bu, x, 0, x1f, x1b);

  // --- FFN1: split-K=4, relu in reduce ---
  gemm_bt<<<dim3(K / TN, BT / TM, 4), 256, 0, stream>>>(
      x1b, W1T, 256, K, K, K, 0,
      256, 0, 256, 0, MN, 0, 1.0f,
      nullptr, nullptr, 0, P, nullptr, nullptr, 0, 0, 0);
  reduce_epi<<<dim3(4096), 256, 0, stream>>>(P, 4, MN, b1, nullptr, 1, nullptr, h1);

  // --- FFN2: split-K=4, + b2 + x1 residual -> out ---
  gemm_bt<<<dim3(K / TN, BT / TM, 4), 256, 0, stream>>>(
      h1, W2T, 256, K, K, K, 0,
      256, 0, 256, 0, MN, 0, 1.0f,
      nullptr, nullptr, 0, P, nullptr, nullptr, 0, 0, 0);
  reduce_epi<<<dim3(4096), 256, 0, stream>>>(P, 4, MN, b2, x1f, 0, out, nullptr);
}

// Round 5
// 579.279 us; speedup vs baseline: 1.3330x; 1.0152x over previous
//
#include <hip/hip_runtime.h>
#include <math.h>

// ---------------------------------------------------------------------------
// TransformerBlock: B=2, T=2048, K=1024, H=4 (each head gets FULL dim K).
// R5: algebraic folding. Since heads use the full K dim:
//   S  = s^2 x (Wq_h Wk_h^T) x^T   -> precompute MT_h = s^2 Wk_h Wq_h^T,
//        t = x MT^T, S = t x^T     (k-projection + kb eliminated)
//   ao = sum_h P_h x (Wv_h Wu_h)   -> precompute VT_h = Wu_h^T Wv_h^T,
//        vv = x V, PV writes fp32 per-head partials, reduce sums + bu + x
//        (unify GEMM + its split-K pass eliminated)
// Pipeline: cast x | cast Wq/Wk/Wv + transpose Wu/W1/W2 | combine GEMMs
// (MT,VT) | t|vv GEMM | transpose vv | scores (causal skip) | softmax |
// PV (K-trunc) -> head partials | reduce(+bu+x) | FFN1 split4 | FFN2 split4.
// Workspace (MB, 188 total, aliased by liveness):
//   [0,8) xb | [8,16) Wqc [16,24) Wkc [24,32) Wvc [32,40) WuTb  (die after
//   combine; region reused: S [8,72) after scores; x1f [8,24) x1b [24,32)
//   h1 [32,40) after PV) | [72,136) tv -> P partials | [136,168) vT |
//   [168,184) Wcomb | [184,186) W1T [186,188) W2T.
// ---------------------------------------------------------------------------

#define TM 128
#define TN 128
#define BK 64

typedef __attribute__((ext_vector_type(8))) short short8;   // 8 bf16 (4 VGPRs)
typedef __attribute__((ext_vector_type(4))) float f32x4;

__device__ __forceinline__ unsigned short f2bf(float f) {
  union { float f; unsigned int u; } v; v.f = f;
  unsigned int r = (v.u + 0x7fffu + ((v.u >> 16) & 1u)) >> 16;
  return (unsigned short)r;
}
__device__ __forceinline__ float bf2f(unsigned short b) {
  union { unsigned int u; float f; } v; v.u = ((unsigned int)b) << 16;
  return v.f;
}

#define GL2LDS(g, l)                                                          \
  __builtin_amdgcn_global_load_lds(                                           \
      (__attribute__((address_space(1))) void*)(g),                           \
      (__attribute__((address_space(3))) void*)(l), 16, 0, 0)

// Generic bf16 GEMM: C = act(scale*(A @ BT^T) + bias + resid)
// A: [M,Kd] row-major (lda), BT: [N,Kd] row-major (ldb).
// grid_mode: 0 = (x=n, y=m, z=z); 2 = (x=z, y=n, z=m) [XCD = z%8 locality].
// z decode: zb=z>>bh_shift, zh=z&mask; offsets aoff=zb*aob+zh*aoh etc.
// Split-K via z: aob=bob=Kslice, cob=M*N, Kd=Kslice.
// causal_mode: 1=skip tiles fully above diagonal, 2=truncate K at m0+TM.
__global__ __launch_bounds__(256) void gemm_bt(
    const unsigned short* __restrict__ A, const unsigned short* __restrict__ BT,
    int Kd, int lda, int ldb, int ldc, int bh_shift,
    long long aob, long long aoh, long long bob, long long boh,
    long long cob, long long coh, float scale,
    const float* __restrict__ bias, const float* __restrict__ resid,
    int do_relu, float* __restrict__ Cf, unsigned short* __restrict__ Cb,
    int causal_mode, int grid_mode) {
  int n0, m0, z;
  if (grid_mode == 2) {            // z on x: bid%8 = XCD = z
    z = blockIdx.x; n0 = blockIdx.y * TN; m0 = blockIdx.z * TM;
  } else {
    n0 = blockIdx.x * TN; m0 = blockIdx.y * TM; z = blockIdx.z;
  }
  if (causal_mode == 1 && n0 >= m0 + TM) return;  // fully-masked tile

  const int zb = z >> bh_shift;
  const int zh = z & ((1 << bh_shift) - 1);
  const long long aoff = (long long)zb * aob + (long long)zh * aoh;
  const long long boff = (long long)zb * bob + (long long)zh * boh;
  const long long coff = (long long)zb * cob + (long long)zh * coh;

  // dual 32-col halves: [2][128][32] ushort each => 16KB + 16KB
  __shared__ unsigned short As[8192];
  __shared__ unsigned short Bs[8192];

  const int tid = threadIdx.x;
  const int lane = tid & 63;
  const int wv = tid >> 6;
  const int wm = wv & 1;   // 2x2 wave grid over 128x128 tile
  const int wn = wv >> 1;

  const int srow = tid >> 2;            // 0..63
  const int scol = (tid & 3) * 8;       // 0,8,16,24 within a 32-col half
  const unsigned short* ap0 = A + aoff + (long long)(m0 + srow) * lda + scol;
  const unsigned short* ap1 = ap0 + (long long)64 * lda;
  const unsigned short* bp0 = BT + boff + (long long)(n0 + srow) * ldb + scol;
  const unsigned short* bp1 = bp0 + (long long)64 * ldb;
  unsigned short* lA00 = As + wv * 512;
  unsigned short* lA10 = As + 2048 + wv * 512;
  unsigned short* lA01 = As + 4096 + wv * 512;
  unsigned short* lA11 = As + 6144 + wv * 512;
  unsigned short* lB00 = Bs + wv * 512;
  unsigned short* lB10 = Bs + 2048 + wv * 512;
  unsigned short* lB01 = Bs + 4096 + wv * 512;
  unsigned short* lB11 = Bs + 6144 + wv * 512;

  f32x4 acc[4][4];
#pragma unroll
  for (int i = 0; i < 4; ++i)
#pragma unroll
    for (int j2 = 0; j2 < 4; ++j2) acc[i][j2] = {0.f, 0.f, 0.f, 0.f};

  int kmax = Kd;
  if (causal_mode == 2) { int t = m0 + TM; if (t < kmax) kmax = t; }

  const int frow = lane & 15;          // m (or n) within 16x16
  const int fq = (lane >> 4) * 8;      // k chunk within 32-col half

  for (int k0 = 0; k0 < kmax; k0 += BK) {
    __syncthreads();                   // prev iter's ds_reads done
    GL2LDS(ap0, lA00); GL2LDS(ap0 + 32, lA01);
    GL2LDS(ap1, lA10); GL2LDS(ap1 + 32, lA11);
    GL2LDS(bp0, lB00); GL2LDS(bp0 + 32, lB01);
    GL2LDS(bp1, lB10); GL2LDS(bp1 + 32, lB11);
    ap0 += BK; ap1 += BK; bp0 += BK; bp1 += BK;
    __syncthreads();                   // vmcnt(0) drain -> LDS visible

#pragma unroll
    for (int s = 0; s < 2; ++s) {      // k-step of 32 per half
      short8 afr[4], bfr[4];
#pragma unroll
      for (int mi = 0; mi < 4; ++mi)
        afr[mi] = *(const short8*)(As + s * 4096 +
                                   (wm * 64 + mi * 16 + frow) * 32 + fq);
#pragma unroll
      for (int ni = 0; ni < 4; ++ni)
        bfr[ni] = *(const short8*)(Bs + s * 4096 +
                                   (wn * 64 + ni * 16 + frow) * 32 + fq);
#pragma unroll
      for (int mi = 0; mi < 4; ++mi)
#pragma unroll
        for (int ni = 0; ni < 4; ++ni)
          acc[mi][ni] = __builtin_amdgcn_mfma_f32_16x16x32_bf16(
              afr[mi], bfr[ni], acc[mi][ni], 0, 0, 0);
    }
  }

  // epilogue: C/D layout col=lane&15, row=(lane>>4)*4+r (m89-verified)
  const int ccol = lane & 15;
  const int crow = (lane >> 4) * 4;
#pragma unroll
  for (int mi = 0; mi < 4; ++mi) {
#pragma unroll
    for (int ni = 0; ni < 4; ++ni) {
      const int gc = n0 + wn * 64 + ni * 16 + ccol;
#pragma unroll
      for (int r = 0; r < 4; ++r) {
        const int gr = m0 + wm * 64 + mi * 16 + crow + r;
        float v = acc[mi][ni][r] * scale;
        if (bias) v += bias[gc];
        if (resid) v += resid[(long long)gr * ldc + gc];
        if (do_relu) v = fmaxf(v, 0.f);
        const long long ci = coff + (long long)gr * ldc + gc;
        if (Cf) Cf[ci] = v;
        if (Cb) Cb[ci] = f2bf(v);
      }
    }
  }
}

// Split-K / head-sum reduce + epilogue: out = act(sum_s P[s] + bias + resid).
// N must be 1024 (bias index = (i*4)&1023).
__global__ __launch_bounds__(256) void reduce_epi(
    const float* __restrict__ P, int S, long long MN,
    const float* __restrict__ bias, const float* __restrict__ resid,
    int do_relu, float* __restrict__ Cf, unsigned short* __restrict__ Cb) {
  const long long i4 = ((long long)blockIdx.x * 256 + threadIdx.x) * 4;
  if (i4 >= MN) return;
  float4 s = {0.f, 0.f, 0.f, 0.f};
  for (int t = 0; t < S; ++t) {
    const float4 p = *(const float4*)(P + (long long)t * MN + i4);
    s.x += p.x; s.y += p.y; s.z += p.z; s.w += p.w;
  }
  if (bias) {
    const int c0 = (int)(i4 & 1023);
    s.x += bias[c0]; s.y += bias[c0 + 1]; s.z += bias[c0 + 2]; s.w += bias[c0 + 3];
  }
  if (resid) {
    const float4 rr = *(const float4*)(resid + i4);
    s.x += rr.x; s.y += rr.y; s.z += rr.z; s.w += rr.w;
  }
  if (do_relu) {
    s.x = fmaxf(s.x, 0.f); s.y = fmaxf(s.y, 0.f);
    s.z = fmaxf(s.z, 0.f); s.w = fmaxf(s.w, 0.f);
  }
  if (Cf) *(float4*)(Cf + i4) = s;
  if (Cb) {
    ushort4 o;
    o.x = f2bf(s.x); o.y = f2bf(s.y); o.z = f2bf(s.z); o.w = f2bf(s.w);
    *(ushort4*)(Cb + i4) = o;
  }
}

// Row-wise causal softmax, in-place on bf16 scores. grid=(T, B*H), block=256.
// Row q: q+1 valid entries; zeros written only to next 128 boundary.
__global__ __launch_bounds__(256) void softmax_causal(unsigned short* S, int T) {
  const int q = blockIdx.x;
  unsigned short* row = S + ((long long)blockIdx.y * T + q) * T;
  const int tid = threadIdx.x;
  const int lane = tid & 63;
  const int wv = tid >> 6;
  const int n = q + 1;
  const int nz = (n + 127) & ~127;     // write limit
  float vals[8];
  float m = -__builtin_inff();
#pragma unroll
  for (int i = 0; i < 8; ++i) {
    int idx = i * 256 + tid;
    vals[i] = (idx < n) ? bf2f(row[idx]) : -__builtin_inff();
    m = fmaxf(m, vals[i]);
  }
#pragma unroll
  for (int o = 32; o; o >>= 1) m = fmaxf(m, __shfl_xor(m, o, 64));
  __shared__ float red[4];
  if (lane == 0) red[wv] = m;
  __syncthreads();
  m = fmaxf(fmaxf(red[0], red[1]), fmaxf(red[2], red[3]));
  __syncthreads();
  float s = 0.f, e[8];
#pragma unroll
  for (int i = 0; i < 8; ++i) {
    int idx = i * 256 + tid;
    e[i] = (idx < n) ? __expf(vals[i] - m) : 0.f;
    s += e[i];
  }
#pragma unroll
  for (int o = 32; o; o >>= 1) s += __shfl_xor(s, o, 64);
  if (lane == 0) red[wv] = s;
  __syncthreads();
  s = red[0] + red[1] + red[2] + red[3];
  const float inv = 1.f / s;
#pragma unroll
  for (int i = 0; i < 8; ++i) {
    int idx = i * 256 + tid;
    if (idx < nz) row[idx] = f2bf(e[i] * inv);
  }
}

// fp32 -> bf16 cast of x. grid=(4096), block=256.
__global__ __launch_bounds__(256) void cast_bf16(const float* __restrict__ in,
                                                 unsigned short* __restrict__ out,
                                                 int n4) {
  int i = blockIdx.x * 256 + threadIdx.x;
  if (i < n4) {
    const float4 v = *(const float4*)(in + (long long)i * 4);
    ushort4 o;
    o.x = f2bf(v.x); o.y = f2bf(v.y); o.z = f2bf(v.z); o.w = f2bf(v.w);
    *(ushort4*)(out + (long long)i * 4) = o;
  }
}

// Batched plain cast Wq/Wk/Wv [1024,4096] fp32 -> bf16 (same layout).
// grid=(4096, 3), block=256.
__global__ __launch_bounds__(256) void prep_cast(
    const float* __restrict__ Wq, const float* __restrict__ Wk,
    const float* __restrict__ Wv, unsigned short* __restrict__ dst) {
  const int z = blockIdx.y;
  const float* W = (z == 0) ? Wq : (z == 1) ? Wk : Wv;
  unsigned short* o = dst + (size_t)z * 4096 * 1024;
  const long long i4 = ((long long)blockIdx.x * 256 + threadIdx.x) * 4;
  const float4 v = *(const float4*)(W + i4);
  ushort4 u;
  u.x = f2bf(v.x); u.y = f2bf(v.y); u.z = f2bf(v.z); u.w = f2bf(v.w);
  *(ushort4*)(o + i4) = u;
}

// Batched transpose-cast: z=0 Wu[4096,1024]->WuTb[1024,4096]; z=1 W1, z=2 W2
// [1024,1024]->WT[1024,1024]. grid=(32, 128, 3), block=256.
__global__ __launch_bounds__(256) void prep_w(
    const float* __restrict__ Wu, const float* __restrict__ W1,
    const float* __restrict__ W2, unsigned short* __restrict__ WuTb,
    unsigned short* __restrict__ W1T, unsigned short* __restrict__ W2T) {
  const int z = blockIdx.z;
  const int R = (z == 0) ? 4096 : 1024;
  if (blockIdx.y * 32 >= R) return;
  const float* W = (z == 0) ? Wu : (z == 1) ? W1 : W2;
  unsigned short* WT = (z == 0) ? WuTb : (z == 1) ? W1T : W2T;
  __shared__ float tile[32][33];
  const int c0 = blockIdx.x * 32;      // over C=1024
  const int r0 = blockIdx.y * 32;      // over R
  const int tx = threadIdx.x & 31;
  const int ty = threadIdx.x >> 5;
#pragma unroll
  for (int j = 0; j < 32; j += 8)
    tile[ty + j][tx] = W[(long long)(r0 + ty + j) * 1024 + c0 + tx];
  __syncthreads();
#pragma unroll
  for (int j = 0; j < 32; j += 8)
    WT[(long long)(c0 + ty + j) * R + r0 + tx] = f2bf(tile[tx][ty + j]);
}

// tv[b][2048,8192] cols [4096,8192) -> vT[b][4096,2048]. grid=(64,128,2).
__global__ __launch_bounds__(256) void transpose_v(
    const unsigned short* __restrict__ tv, unsigned short* __restrict__ vT) {
  __shared__ unsigned short tile[32][33];
  const int t0 = blockIdx.x * 32;
  const int d0 = blockIdx.y * 32;
  const int b = blockIdx.z;
  const int tx = threadIdx.x & 31;
  const int ty = threadIdx.x >> 5;
#pragma unroll
  for (int j = 0; j < 32; j += 8)
    tile[ty + j][tx] =
        tv[(long long)(b * 2048 + t0 + ty + j) * 8192 + 4096 + d0 + tx];
  __syncthreads();
#pragma unroll
  for (int j = 0; j < 32; j += 8)
    vT[(long long)(b * 4096 + d0 + ty + j) * 2048 + t0 + tx] =
        tile[tx][ty + j];
}

extern "C" void kernel_launch(void* const* d_in, const int* in_sizes, int n_in,
                              void* d_out, int out_size, void* d_ws,
                              size_t ws_size, hipStream_t stream) {
  (void)in_sizes; (void)n_in; (void)out_size; (void)ws_size;
  const float* x  = (const float*)d_in[0];
  const float* Wq = (const float*)d_in[1];
  const float* Wk = (const float*)d_in[2];
  const float* Wv = (const float*)d_in[3];
  const float* Wu = (const float*)d_in[4];
  const float* bu = (const float*)d_in[5];
  const float* W1 = (const float*)d_in[6];
  const float* b1 = (const float*)d_in[7];
  const float* W2 = (const float*)d_in[8];
  const float* b2 = (const float*)d_in[9];
  float* out = (float*)d_out;

  const int B = 2, T = 2048, K = 1024, H = 4;
  const int BT = B * T;   // 4096
  const size_t MB = 1024 * 1024;
  const long long MN = (long long)BT * K;    // 4 Mi elements
  const long long TT = (long long)T * T;     // 4 Mi

  char* w = (char*)d_ws;
  unsigned short* xb    = (unsigned short*)(w + 0 * MB);    //  8 MB
  unsigned short* Wqc   = (unsigned short*)(w + 8 * MB);    //  8 MB (dies)
  unsigned short* Wkc   = (unsigned short*)(w + 16 * MB);   //  8 MB (dies)
  unsigned short* Wvc   = (unsigned short*)(w + 24 * MB);   //  8 MB (dies)
  unsigned short* WuTb  = (unsigned short*)(w + 32 * MB);   //  8 MB (dies)
  unsigned short* S     = (unsigned short*)(w + 8 * MB);    // 64 MB [8,72)
  float*          x1f   = (float*)(w + 8 * MB);             // 16 MB after PV
  unsigned short* x1b   = (unsigned short*)(w + 24 * MB);   //  8 MB after PV
  unsigned short* h1    = (unsigned short*)(w + 32 * MB);   //  8 MB after PV
  unsigned short* tv    = (unsigned short*)(w + 72 * MB);   // 64 MB [72,136)
  float*          P     = (float*)(w + 72 * MB);            // 64 MB after scores
  unsigned short* vT    = (unsigned short*)(w + 136 * MB);  // 32 MB [136,168)
  unsigned short* Wcomb = (unsigned short*)(w + 168 * MB);  // 16 MB [168,184)
  unsigned short* W1T   = (unsigned short*)(w + 184 * MB);  //  2 MB
  unsigned short* W2T   = (unsigned short*)(w + 186 * MB);  //  2 MB

  const float s2 = 0.03125f;  // (1024^-0.25)^2 = 2^-5

  // --- prep: casts + transposes ---
  cast_bf16<<<dim3(4096), 256, 0, stream>>>(x, xb, BT * K / 4);
  prep_cast<<<dim3(4096, 3), 256, 0, stream>>>(Wq, Wk, Wv, Wqc);
  prep_w<<<dim3(32, 128, 3), 256, 0, stream>>>(Wu, W1, W2, WuTb, W1T, W2T);

  // --- combine1: MT_h = s^2 * Wk_h @ Wq_h^T -> Wcomb rows [h*1024, ...) ---
  gemm_bt<<<dim3(8, 8, 4), 256, 0, stream>>>(
      Wkc, Wqc, K, 4096, 4096, 1024, 0,
      1024, 0, 1024, 0, (long long)1024 * 1024, 0, s2,
      nullptr, nullptr, 0, nullptr, Wcomb, 0, 0);
  // --- combine2: VT_h = WuT_h @ Wv_h^T -> Wcomb rows [4096 + h*1024, ...) ---
  gemm_bt<<<dim3(8, 8, 4), 256, 0, stream>>>(
      WuTb, Wvc, K, 4096, 4096, 1024, 0,
      1024, 0, 1024, 0, (long long)1024 * 1024, 0, 1.0f,
      nullptr, nullptr, 0, nullptr, Wcomb + (size_t)4096 * 1024, 0, 0);

  // --- t|vv: per b: xb_b [2048,1024] @ Wcomb^T -> tv [2048,8192] ---
  gemm_bt<<<dim3(64, 16, 2), 256, 0, stream>>>(
      xb, Wcomb, K, K, K, 8192, 0,
      (long long)T * K, 0, 0, 0, (long long)T * 8192, 0, 1.0f,
      nullptr, nullptr, 0, nullptr, tv, 0, 0);

  transpose_v<<<dim3(64, 128, 2), 256, 0, stream>>>(tv, vT);

  // --- scores: per (b,h): t_h [2048,1024] @ xb_b^T -> S (causal skip) ---
  gemm_bt<<<dim3(8, T / TN, T / TM), 256, 0, stream>>>(
      tv, xb, K, 8192, K, T, 2,
      (long long)T * 8192, 1024, (long long)T * K, 0,
      (long long)H * TT, TT, 1.0f,
      nullptr, nullptr, 0, nullptr, S, 1, 2);

  softmax_causal<<<dim3(T, B * H), 256, 0, stream>>>(S, T);

  // --- PV: per (b,h): P_h [2048,2048] @ vv_h^T -> fp32 head partials ---
  gemm_bt<<<dim3(8, K / TN, T / TM), 256, 0, stream>>>(
      S, vT, T, T, 2048, K, 2,
      (long long)H * TT, TT, (long long)4096 * 2048, (long long)1024 * 2048,
      (long long)T * K, MN, 1.0f,
      nullptr, nullptr, 0, P, nullptr, 2, 2);

  // --- head-sum + bu + x residual -> x1 (replaces unify GEMM) ---
  reduce_epi<<<dim3(4096), 256, 0, stream>>>(P, 4, MN, bu, x, 0, x1f, x1b);

  // --- FFN1: split-K=4 (slices of 256), relu in reduce ---
  gemm_bt<<<dim3(K / TN, BT / TM, 4), 256, 0, stream>>>(
      x1b, W1T, 256, K, K, K, 0,
      256, 0, 256, 0, MN, 0, 1.0f,
      nullptr, nullptr, 0, P, nullptr, 0, 0);
  reduce_epi<<<dim3(4096), 256, 0, stream>>>(P, 4, MN, b1, nullptr, 1, nullptr, h1);

  // --- FFN2: split-K=4, + b2 + x1 residual -> out ---
  gemm_bt<<<dim3(K / TN, BT / TM, 4), 256, 0, stream>>>(
      h1, W2T, 256, K, K, K, 0,
      256, 0, 256, 0, MN, 0, 1.0f,
      nullptr, nullptr, 0, P, nullptr, 0, 0);
  reduce_epi<<<dim3(4096), 256, 0, stream>>>(P, 4, MN, b2, x1f, 0, out, nullptr);
}

// Round 6
// 528.595 us; speedup vs baseline: 1.4608x; 1.0959x over previous
//
#include <hip/hip_runtime.h>
#include <math.h>

// ---------------------------------------------------------------------------
// TransformerBlock: B=2, T=2048, K=1024, H=4 (each head gets FULL dim K).
// R6 (on top of R5's algebraic folding):
//  - combine1+2 merged into one z=8 GEMM (Wk pre-scaled by s^2 at cast).
//  - t-GEMM and vvT-GEMM split; vvT emits [d,t] directly (transpose_v gone).
//  - PV head-partials and FFN split-K partials in bf16 (half the traffic).
//  - softmax vectorized (ushort8 = 16B per thread).
// Algebra: MT_h = s^2 Wk_h Wq_h^T ; VT_h = Wu_h^T Wv_h^T ; t = x MT^T ;
// S = t x^T (causal) ; P = softmax ; out_h = P_h vv_h with vvT = VT x^T ;
// x1 = x + sum_h out_h + bu ; out = x1 + relu(x1 W1 + b1) W2 + b2.
// Workspace (MB, 188): [0,8) xb | [8,16) Wqc | [16,24) Wvc | [24,32) Wkc'
// | [32,40) WuTb | [40,56) Wcomb | [56,88) tb | [88,120) vT | [120,184) S
// | [184,186) W1T | [186,188) W2T.  Aliases by liveness: Pb(PV partials,
// 32MB)=[40,72) after vvT; x1f=[8,24), x1b=[24,32), h1=[32,40) after combine;
// Pb2(FFN partials, 32MB)=[88,120) after PV.
// ---------------------------------------------------------------------------

#define TM 128
#define TN 128
#define BK 64

typedef __attribute__((ext_vector_type(8))) short short8;   // 8 bf16 (4 VGPRs)
typedef __attribute__((ext_vector_type(4))) float f32x4;

__device__ __forceinline__ unsigned short f2bf(float f) {
  union { float f; unsigned int u; } v; v.f = f;
  unsigned int r = (v.u + 0x7fffu + ((v.u >> 16) & 1u)) >> 16;
  return (unsigned short)r;
}
__device__ __forceinline__ float bf2f(unsigned short b) {
  union { unsigned int u; float f; } v; v.u = ((unsigned int)b) << 16;
  return v.f;
}

#define GL2LDS(g, l)                                                          \
  __builtin_amdgcn_global_load_lds(                                           \
      (__attribute__((address_space(1))) void*)(g),                           \
      (__attribute__((address_space(3))) void*)(l), 16, 0, 0)

// Generic bf16 GEMM: C = scale*(A @ BT^T) [+bias/resid/relu].
// A: [M,Kd] row-major (lda), BT: [N,Kd] row-major (ldb).
// grid_mode: 0 = (x=n, y=m, z=z); 2 = (x=z, y=n, z=m) [XCD = z%8 locality].
// z decode: zb=z>>bh_shift, zh=z&mask; aoff=zb*aob+zh*aoh, etc.
// Split-K via z: aob=bob=Kslice, cob=M*N, Kd=Kslice.
// causal_mode: 1=skip tiles fully above diagonal, 2=truncate K at m0+TM.
__global__ __launch_bounds__(256) void gemm_bt(
    const unsigned short* __restrict__ A, const unsigned short* __restrict__ BT,
    int Kd, int lda, int ldb, int ldc, int bh_shift,
    long long aob, long long aoh, long long bob, long long boh,
    long long cob, long long coh, float scale,
    const float* __restrict__ bias, const float* __restrict__ resid,
    int do_relu, float* __restrict__ Cf, unsigned short* __restrict__ Cb,
    int causal_mode, int grid_mode) {
  int n0, m0, z;
  if (grid_mode == 2) {            // z on x: bid%8 = XCD = z
    z = blockIdx.x; n0 = blockIdx.y * TN; m0 = blockIdx.z * TM;
  } else {
    n0 = blockIdx.x * TN; m0 = blockIdx.y * TM; z = blockIdx.z;
  }
  if (causal_mode == 1 && n0 >= m0 + TM) return;  // fully-masked tile

  const int zb = z >> bh_shift;
  const int zh = z & ((1 << bh_shift) - 1);
  const long long aoff = (long long)zb * aob + (long long)zh * aoh;
  const long long boff = (long long)zb * bob + (long long)zh * boh;
  const long long coff = (long long)zb * cob + (long long)zh * coh;

  // dual 32-col halves: [2][128][32] ushort each => 16KB + 16KB
  __shared__ unsigned short As[8192];
  __shared__ unsigned short Bs[8192];

  const int tid = threadIdx.x;
  const int lane = tid & 63;
  const int wv = tid >> 6;
  const int wm = wv & 1;   // 2x2 wave grid over 128x128 tile
  const int wn = wv >> 1;

  const int srow = tid >> 2;            // 0..63
  const int scol = (tid & 3) * 8;       // 0,8,16,24 within a 32-col half
  const unsigned short* ap0 = A + aoff + (long long)(m0 + srow) * lda + scol;
  const unsigned short* ap1 = ap0 + (long long)64 * lda;
  const unsigned short* bp0 = BT + boff + (long long)(n0 + srow) * ldb + scol;
  const unsigned short* bp1 = bp0 + (long long)64 * ldb;
  unsigned short* lA00 = As + wv * 512;
  unsigned short* lA10 = As + 2048 + wv * 512;
  unsigned short* lA01 = As + 4096 + wv * 512;
  unsigned short* lA11 = As + 6144 + wv * 512;
  unsigned short* lB00 = Bs + wv * 512;
  unsigned short* lB10 = Bs + 2048 + wv * 512;
  unsigned short* lB01 = Bs + 4096 + wv * 512;
  unsigned short* lB11 = Bs + 6144 + wv * 512;

  f32x4 acc[4][4];
#pragma unroll
  for (int i = 0; i < 4; ++i)
#pragma unroll
    for (int j2 = 0; j2 < 4; ++j2) acc[i][j2] = {0.f, 0.f, 0.f, 0.f};

  int kmax = Kd;
  if (causal_mode == 2) { int t = m0 + TM; if (t < kmax) kmax = t; }

  const int frow = lane & 15;          // m (or n) within 16x16
  const int fq = (lane >> 4) * 8;      // k chunk within 32-col half

  for (int k0 = 0; k0 < kmax; k0 += BK) {
    __syncthreads();                   // prev iter's ds_reads done
    GL2LDS(ap0, lA00); GL2LDS(ap0 + 32, lA01);
    GL2LDS(ap1, lA10); GL2LDS(ap1 + 32, lA11);
    GL2LDS(bp0, lB00); GL2LDS(bp0 + 32, lB01);
    GL2LDS(bp1, lB10); GL2LDS(bp1 + 32, lB11);
    ap0 += BK; ap1 += BK; bp0 += BK; bp1 += BK;
    __syncthreads();                   // vmcnt(0) drain -> LDS visible

#pragma unroll
    for (int s = 0; s < 2; ++s) {      // k-step of 32 per half
      short8 afr[4], bfr[4];
#pragma unroll
      for (int mi = 0; mi < 4; ++mi)
        afr[mi] = *(const short8*)(As + s * 4096 +
                                   (wm * 64 + mi * 16 + frow) * 32 + fq);
#pragma unroll
      for (int ni = 0; ni < 4; ++ni)
        bfr[ni] = *(const short8*)(Bs + s * 4096 +
                                   (wn * 64 + ni * 16 + frow) * 32 + fq);
#pragma unroll
      for (int mi = 0; mi < 4; ++mi)
#pragma unroll
        for (int ni = 0; ni < 4; ++ni)
          acc[mi][ni] = __builtin_amdgcn_mfma_f32_16x16x32_bf16(
              afr[mi], bfr[ni], acc[mi][ni], 0, 0, 0);
    }
  }

  // epilogue: C/D layout col=lane&15, row=(lane>>4)*4+r (m89-verified)
  const int ccol = lane & 15;
  const int crow = (lane >> 4) * 4;
#pragma unroll
  for (int mi = 0; mi < 4; ++mi) {
#pragma unroll
    for (int ni = 0; ni < 4; ++ni) {
      const int gc = n0 + wn * 64 + ni * 16 + ccol;
#pragma unroll
      for (int r = 0; r < 4; ++r) {
        const int gr = m0 + wm * 64 + mi * 16 + crow + r;
        float v = acc[mi][ni][r] * scale;
        if (bias) v += bias[gc];
        if (resid) v += resid[(long long)gr * ldc + gc];
        if (do_relu) v = fmaxf(v, 0.f);
        const long long ci = coff + (long long)gr * ldc + gc;
        if (Cf) Cf[ci] = v;
        if (Cb) Cb[ci] = f2bf(v);
      }
    }
  }
}

// Partial-sum reduce + epilogue over bf16 partials:
// out = act(sum_s Pb[s*MN + i] + bias + resid).  N must be 1024.
__global__ __launch_bounds__(256) void reduce_epi(
    const unsigned short* __restrict__ Pb, int S, long long MN,
    const float* __restrict__ bias, const float* __restrict__ resid,
    int do_relu, float* __restrict__ Cf, unsigned short* __restrict__ Cb) {
  const long long i4 = ((long long)blockIdx.x * 256 + threadIdx.x) * 4;
  if (i4 >= MN) return;
  float4 s = {0.f, 0.f, 0.f, 0.f};
  for (int t = 0; t < S; ++t) {
    const ushort4 p = *(const ushort4*)(Pb + (long long)t * MN + i4);
    s.x += bf2f(p.x); s.y += bf2f(p.y); s.z += bf2f(p.z); s.w += bf2f(p.w);
  }
  if (bias) {
    const int c0 = (int)(i4 & 1023);
    s.x += bias[c0]; s.y += bias[c0 + 1]; s.z += bias[c0 + 2]; s.w += bias[c0 + 3];
  }
  if (resid) {
    const float4 rr = *(const float4*)(resid + i4);
    s.x += rr.x; s.y += rr.y; s.z += rr.z; s.w += rr.w;
  }
  if (do_relu) {
    s.x = fmaxf(s.x, 0.f); s.y = fmaxf(s.y, 0.f);
    s.z = fmaxf(s.z, 0.f); s.w = fmaxf(s.w, 0.f);
  }
  if (Cf) *(float4*)(Cf + i4) = s;
  if (Cb) {
    ushort4 o;
    o.x = f2bf(s.x); o.y = f2bf(s.y); o.z = f2bf(s.z); o.w = f2bf(s.w);
    *(ushort4*)(Cb + i4) = o;
  }
}

// Row-wise causal softmax, in-place on bf16 scores. grid=(T, B*H), block=256.
// Vectorized: thread t owns elements [t*8, t*8+8) (one 16B load/store).
// Row q: q+1 valid; zeros written to next 128 boundary (PV truncates there).
__global__ __launch_bounds__(256) void softmax_causal(unsigned short* S, int T) {
  const int q = blockIdx.x;
  unsigned short* row = S + ((long long)blockIdx.y * T + q) * T;
  const int tid = threadIdx.x;
  const int lane = tid & 63;
  const int wv = tid >> 6;
  const int n = q + 1;
  const int nz = (n + 127) & ~127;     // write limit
  const int base = tid * 8;
  const short8 raw = *(const short8*)(row + base);
  float vals[8];
  float m = -__builtin_inff();
#pragma unroll
  for (int i = 0; i < 8; ++i) {
    vals[i] = (base + i < n) ? bf2f((unsigned short)raw[i]) : -__builtin_inff();
    m = fmaxf(m, vals[i]);
  }
#pragma unroll
  for (int o = 32; o; o >>= 1) m = fmaxf(m, __shfl_xor(m, o, 64));
  __shared__ float red[4];
  if (lane == 0) red[wv] = m;
  __syncthreads();
  m = fmaxf(fmaxf(red[0], red[1]), fmaxf(red[2], red[3]));
  __syncthreads();
  float s = 0.f, e[8];
#pragma unroll
  for (int i = 0; i < 8; ++i) {
    e[i] = (base + i < n) ? __expf(vals[i] - m) : 0.f;
    s += e[i];
  }
#pragma unroll
  for (int o = 32; o; o >>= 1) s += __shfl_xor(s, o, 64);
  if (lane == 0) red[wv] = s;
  __syncthreads();
  s = red[0] + red[1] + red[2] + red[3];
  const float inv = 1.f / s;
  if (base < nz) {
    short8 o8;
#pragma unroll
    for (int i = 0; i < 8; ++i) o8[i] = (short)f2bf(e[i] * inv);
    *(short8*)(row + base) = o8;
  }
}

// fp32 -> bf16 cast of x. grid=(4096), block=256.
__global__ __launch_bounds__(256) void cast_bf16(const float* __restrict__ in,
                                                 unsigned short* __restrict__ out,
                                                 int n4) {
  int i = blockIdx.x * 256 + threadIdx.x;
  if (i < n4) {
    const float4 v = *(const float4*)(in + (long long)i * 4);
    ushort4 o;
    o.x = f2bf(v.x); o.y = f2bf(v.y); o.z = f2bf(v.z); o.w = f2bf(v.w);
    *(ushort4*)(out + (long long)i * 4) = o;
  }
}

// Batched plain casts: Wq->dq, Wk*s2->dk, Wv->dv. grid=(4096, 3), block=256.
__global__ __launch_bounds__(256) void prep_cast(
    const float* __restrict__ Wq, const float* __restrict__ Wk,
    const float* __restrict__ Wv, unsigned short* __restrict__ dq,
    unsigned short* __restrict__ dk, unsigned short* __restrict__ dv,
    float s2) {
  const int z = blockIdx.y;
  const float* W = (z == 0) ? Wq : (z == 1) ? Wk : Wv;
  unsigned short* o = (z == 0) ? dq : (z == 1) ? dk : dv;
  const float sc = (z == 1) ? s2 : 1.0f;
  const long long i4 = ((long long)blockIdx.x * 256 + threadIdx.x) * 4;
  const float4 v = *(const float4*)(W + i4);
  ushort4 u;
  u.x = f2bf(v.x * sc); u.y = f2bf(v.y * sc);
  u.z = f2bf(v.z * sc); u.w = f2bf(v.w * sc);
  *(ushort4*)(o + i4) = u;
}

// Batched transpose-cast: z=0 Wu[4096,1024]->WuTb[1024,4096]; z=1 W1, z=2 W2
// [1024,1024]->WT. grid=(32, 128, 3), block=256.
__global__ __launch_bounds__(256) void prep_w(
    const float* __restrict__ Wu, const float* __restrict__ W1,
    const float* __restrict__ W2, unsigned short* __restrict__ WuTb,
    unsigned short* __restrict__ W1T, unsigned short* __restrict__ W2T) {
  const int z = blockIdx.z;
  const int R = (z == 0) ? 4096 : 1024;
  if (blockIdx.y * 32 >= R) return;
  const float* W = (z == 0) ? Wu : (z == 1) ? W1 : W2;
  unsigned short* WT = (z == 0) ? WuTb : (z == 1) ? W1T : W2T;
  __shared__ float tile[32][33];
  const int c0 = blockIdx.x * 32;      // over C=1024
  const int r0 = blockIdx.y * 32;      // over R
  const int tx = threadIdx.x & 31;
  const int ty = threadIdx.x >> 5;
#pragma unroll
  for (int j = 0; j < 32; j += 8)
    tile[ty + j][tx] = W[(long long)(r0 + ty + j) * 1024 + c0 + tx];
  __syncthreads();
#pragma unroll
  for (int j = 0; j < 32; j += 8)
    WT[(long long)(c0 + ty + j) * R + r0 + tx] = f2bf(tile[tx][ty + j]);
}

extern "C" void kernel_launch(void* const* d_in, const int* in_sizes, int n_in,
                              void* d_out, int out_size, void* d_ws,
                              size_t ws_size, hipStream_t stream) {
  (void)in_sizes; (void)n_in; (void)out_size; (void)ws_size;
  const float* x  = (const float*)d_in[0];
  const float* Wq = (const float*)d_in[1];
  const float* Wk = (const float*)d_in[2];
  const float* Wv = (const float*)d_in[3];
  const float* Wu = (const float*)d_in[4];
  const float* bu = (const float*)d_in[5];
  const float* W1 = (const float*)d_in[6];
  const float* b1 = (const float*)d_in[7];
  const float* W2 = (const float*)d_in[8];
  const float* b2 = (const float*)d_in[9];
  float* out = (float*)d_out;

  const int B = 2, T = 2048, K = 1024, H = 4;
  const int BT = B * T;   // 4096
  const size_t MB = 1024 * 1024;
  const long long MN = (long long)BT * K;    // 4 Mi elements
  const long long TT = (long long)T * T;     // 4 Mi
  const long long Mi = 1024 * 1024;

  char* w = (char*)d_ws;
  unsigned short* xb    = (unsigned short*)(w + 0 * MB);    //  8 MB
  unsigned short* Wqc   = (unsigned short*)(w + 8 * MB);    //  8 MB (dies)
  unsigned short* Wvc   = (unsigned short*)(w + 16 * MB);   //  8 MB (dies)
  unsigned short* Wkc   = (unsigned short*)(w + 24 * MB);   //  8 MB pre-scaled
  unsigned short* WuTb  = (unsigned short*)(w + 32 * MB);   //  8 MB (dies)
  unsigned short* Wcomb = (unsigned short*)(w + 40 * MB);   // 16 MB (dies)
  unsigned short* tb    = (unsigned short*)(w + 56 * MB);   // 32 MB (dies)
  unsigned short* vT    = (unsigned short*)(w + 88 * MB);   // 32 MB (dies)
  unsigned short* S     = (unsigned short*)(w + 120 * MB);  // 64 MB
  unsigned short* W1T   = (unsigned short*)(w + 184 * MB);  //  2 MB
  unsigned short* W2T   = (unsigned short*)(w + 186 * MB);  //  2 MB
  // liveness aliases:
  unsigned short* Pb    = (unsigned short*)(w + 40 * MB);   // 32 MB PV partials
  float*          x1f   = (float*)(w + 8 * MB);             // 16 MB
  unsigned short* x1b   = (unsigned short*)(w + 24 * MB);   //  8 MB
  unsigned short* h1    = (unsigned short*)(w + 32 * MB);   //  8 MB
  unsigned short* Pb2   = (unsigned short*)(w + 88 * MB);   // 32 MB FFN part.

  const float s2 = 0.03125f;  // (1024^-0.25)^2 = 2^-5

  // --- prep ---
  cast_bf16<<<dim3(4096), 256, 0, stream>>>(x, xb, BT * K / 4);
  prep_cast<<<dim3(4096, 3), 256, 0, stream>>>(Wq, Wk, Wv, Wqc, Wkc, Wvc, s2);
  prep_w<<<dim3(32, 128, 3), 256, 0, stream>>>(Wu, W1, W2, WuTb, W1T, W2T);

  // --- merged combine (z=8): zb=0: MT_h = (s^2 Wk)_h Wq_h^T -> Wcomb[0:4096)
  //     zb=1: VT_h = WuT_h Wv_h^T -> Wcomb[4096:8192). A base Wkc (WuTb at
  //     +4Mi), B base Wqc (Wvc at +4Mi). ---
  gemm_bt<<<dim3(8, 8, 8), 256, 0, stream>>>(
      Wkc, Wqc, K, 4096, 4096, 1024, 2,
      4 * Mi, 1024, 4 * Mi, 1024, 4 * Mi, Mi, 1.0f,
      nullptr, nullptr, 0, nullptr, Wcomb, 0, 0);

  // --- t = x @ MT^T : [4096,1024] x [4096,1024]^T -> tb [4096,4096] ---
  gemm_bt<<<dim3(32, 32, 1), 256, 0, stream>>>(
      xb, Wcomb, K, K, K, 4096, 0,
      0, 0, 0, 0, 0, 0, 1.0f,
      nullptr, nullptr, 0, nullptr, tb, 0, 0);

  // --- scores: per (b,h): t_h [2048,1024] @ xb_b^T -> S (causal skip) ---
  gemm_bt<<<dim3(8, T / TN, T / TM), 256, 0, stream>>>(
      tb, xb, K, 4096, K, T, 2,
      (long long)T * 4096, 1024, (long long)T * K, 0,
      (long long)H * TT, TT, 1.0f,
      nullptr, nullptr, 0, nullptr, S, 1, 2);

  softmax_causal<<<dim3(T, B * H), 256, 0, stream>>>(S, T);

  // --- vvT: VT [4096,1024] @ xb_b^T -> vT[b][4096,2048] (direct [d,t]) ---
  gemm_bt<<<dim3(16, 32, 2), 256, 0, stream>>>(
      Wcomb + (size_t)4 * Mi, xb, K, K, K, 2048, 0,
      0, 0, (long long)T * K, 0, (long long)4096 * 2048, 0, 1.0f,
      nullptr, nullptr, 0, nullptr, vT, 0, 0);

  // --- PV: per (b,h): P_h [2048,2048] @ vvT_h^T -> bf16 head partials ---
  gemm_bt<<<dim3(8, K / TN, T / TM), 256, 0, stream>>>(
      S, vT, T, T, 2048, K, 2,
      (long long)H * TT, TT, (long long)4096 * 2048, (long long)1024 * 2048,
      (long long)2048 * 1024, MN, 1.0f,
      nullptr, nullptr, 0, nullptr, Pb, 2, 2);

  // --- head-sum + bu + x residual -> x1 ---
  reduce_epi<<<dim3(4096), 256, 0, stream>>>(Pb, 4, MN, bu, x, 0, x1f, x1b);

  // --- FFN1: split-K=4 (slices of 256) -> bf16 partials, relu in reduce ---
  gemm_bt<<<dim3(K / TN, BT / TM, 4), 256, 0, stream>>>(
      x1b, W1T, 256, K, K, K, 0,
      256, 0, 256, 0, MN, 0, 1.0f,
      nullptr, nullptr, 0, nullptr, Pb2, 0, 0);
  reduce_epi<<<dim3(4096), 256, 0, stream>>>(Pb2, 4, MN, b1, nullptr, 1,
                                             nullptr, h1);

  // --- FFN2: split-K=4, + b2 + x1 residual -> out ---
  gemm_bt<<<dim3(K / TN, BT / TM, 4), 256, 0, stream>>>(
      h1, W2T, 256, K, K, K, 0,
      256, 0, 256, 0, MN, 0, 1.0f,
      nullptr, nullptr, 0, nullptr, Pb2, 0, 0);
  reduce_epi<<<dim3(4096), 256, 0, stream>>>(Pb2, 4, MN, b2, x1f, 0, out,
                                             nullptr);
}

// Round 7
// 503.157 us; speedup vs baseline: 1.5346x; 1.0506x over previous
//
#include <hip/hip_runtime.h>
#include <math.h>

// ---------------------------------------------------------------------------
// TransformerBlock: B=2, T=2048, K=1024, H=4 (each head gets FULL dim K).
// R7: scheduling round on top of R6's algebraic folding.
//  - scores: compact triangular grid (1088 blocks, no dead blocks).
//  - PV: m-interleaved grid (x=z, y=m, z=n) to kill the heavy-tile tail.
//  - t-GEMM + vvT-GEMM merged into one 2048-block launch (gemm_tvv).
//  - all prep (casts + transposes) in one launch.
// Algebra: MT_h = s^2 Wk_h Wq_h^T ; VT_h = Wu_h^T Wv_h^T ; t = x MT^T ;
// S = t x^T (causal) ; P = softmax ; out_h = P_h vv_h with vvT = VT x^T ;
// x1 = x + sum_h out_h + bu ; out = x1 + relu(x1 W1 + b1) W2 + b2.
// Workspace (MB, 188): [0,8) xb | [8,16) Wqc | [16,24) Wvc | [24,32) Wkc'
// | [32,40) WuTb | [40,56) Wcomb | [56,88) tb | [88,120) vT | [120,184) S
// | [184,186) W1T | [186,188) W2T.  Aliases by liveness: Pb=[40,72) after
// vvT; x1f=[8,24), x1b=[24,32), h1=[32,40) after combine; Pb2=[88,120)
// after PV.
// ---------------------------------------------------------------------------

#define TM 128
#define TN 128
#define BK 64

typedef __attribute__((ext_vector_type(8))) short short8;   // 8 bf16 (4 VGPRs)
typedef __attribute__((ext_vector_type(4))) float f32x4;

__device__ __forceinline__ unsigned short f2bf(float f) {
  union { float f; unsigned int u; } v; v.f = f;
  unsigned int r = (v.u + 0x7fffu + ((v.u >> 16) & 1u)) >> 16;
  return (unsigned short)r;
}
__device__ __forceinline__ float bf2f(unsigned short b) {
  union { unsigned int u; float f; } v; v.u = ((unsigned int)b) << 16;
  return v.f;
}

#define GL2LDS(g, l)                                                          \
  __builtin_amdgcn_global_load_lds(                                           \
      (__attribute__((address_space(1))) void*)(g),                           \
      (__attribute__((address_space(3))) void*)(l), 16, 0, 0)

// Shared GEMM core: C_tile(m0,n0) = scale*(A @ BT^T) [+bias/resid/relu].
// A, BT already offset by caller. As/Bs are the kernel's LDS buffers.
__device__ __forceinline__ void gemm_core(
    const unsigned short* __restrict__ A, const unsigned short* __restrict__ BT,
    int m0, int n0, int kmax, int lda, int ldb, int ldc, long long coff,
    float scale, const float* __restrict__ bias,
    const float* __restrict__ resid, int do_relu, float* __restrict__ Cf,
    unsigned short* __restrict__ Cb, unsigned short* As, unsigned short* Bs) {
  const int tid = threadIdx.x;
  const int lane = tid & 63;
  const int wv = tid >> 6;
  const int wm = wv & 1;   // 2x2 wave grid over 128x128 tile
  const int wn = wv >> 1;

  const int srow = tid >> 2;            // 0..63
  const int scol = (tid & 3) * 8;       // 0,8,16,24 within a 32-col half
  const unsigned short* ap0 = A + (long long)(m0 + srow) * lda + scol;
  const unsigned short* ap1 = ap0 + (long long)64 * lda;
  const unsigned short* bp0 = BT + (long long)(n0 + srow) * ldb + scol;
  const unsigned short* bp1 = bp0 + (long long)64 * ldb;
  unsigned short* lA00 = As + wv * 512;
  unsigned short* lA10 = As + 2048 + wv * 512;
  unsigned short* lA01 = As + 4096 + wv * 512;
  unsigned short* lA11 = As + 6144 + wv * 512;
  unsigned short* lB00 = Bs + wv * 512;
  unsigned short* lB10 = Bs + 2048 + wv * 512;
  unsigned short* lB01 = Bs + 4096 + wv * 512;
  unsigned short* lB11 = Bs + 6144 + wv * 512;

  f32x4 acc[4][4];
#pragma unroll
  for (int i = 0; i < 4; ++i)
#pragma unroll
    for (int j2 = 0; j2 < 4; ++j2) acc[i][j2] = {0.f, 0.f, 0.f, 0.f};

  const int frow = lane & 15;          // m (or n) within 16x16
  const int fq = (lane >> 4) * 8;      // k chunk within 32-col half

  for (int k0 = 0; k0 < kmax; k0 += BK) {
    __syncthreads();                   // prev iter's ds_reads done
    GL2LDS(ap0, lA00); GL2LDS(ap0 + 32, lA01);
    GL2LDS(ap1, lA10); GL2LDS(ap1 + 32, lA11);
    GL2LDS(bp0, lB00); GL2LDS(bp0 + 32, lB01);
    GL2LDS(bp1, lB10); GL2LDS(bp1 + 32, lB11);
    ap0 += BK; ap1 += BK; bp0 += BK; bp1 += BK;
    __syncthreads();                   // vmcnt(0) drain -> LDS visible

#pragma unroll
    for (int s = 0; s < 2; ++s) {      // k-step of 32 per half
      short8 afr[4], bfr[4];
#pragma unroll
      for (int mi = 0; mi < 4; ++mi)
        afr[mi] = *(const short8*)(As + s * 4096 +
                                   (wm * 64 + mi * 16 + frow) * 32 + fq);
#pragma unroll
      for (int ni = 0; ni < 4; ++ni)
        bfr[ni] = *(const short8*)(Bs + s * 4096 +
                                   (wn * 64 + ni * 16 + frow) * 32 + fq);
#pragma unroll
      for (int mi = 0; mi < 4; ++mi)
#pragma unroll
        for (int ni = 0; ni < 4; ++ni)
          acc[mi][ni] = __builtin_amdgcn_mfma_f32_16x16x32_bf16(
              afr[mi], bfr[ni], acc[mi][ni], 0, 0, 0);
    }
  }

  // epilogue: C/D layout col=lane&15, row=(lane>>4)*4+r (m89-verified)
  const int ccol = lane & 15;
  const int crow = (lane >> 4) * 4;
#pragma unroll
  for (int mi = 0; mi < 4; ++mi) {
#pragma unroll
    for (int ni = 0; ni < 4; ++ni) {
      const int gc = n0 + wn * 64 + ni * 16 + ccol;
#pragma unroll
      for (int r = 0; r < 4; ++r) {
        const int gr = m0 + wm * 64 + mi * 16 + crow + r;
        float v = acc[mi][ni][r] * scale;
        if (bias) v += bias[gc];
        if (resid) v += resid[(long long)gr * ldc + gc];
        if (do_relu) v = fmaxf(v, 0.f);
        const long long ci = coff + (long long)gr * ldc + gc;
        if (Cf) Cf[ci] = v;
        if (Cb) Cb[ci] = f2bf(v);
      }
    }
  }
}

// Generic batched GEMM wrapper.
// grid_mode: 0 = (x=n, y=m, z=z); 2 = (x=z, y=n, z=m);
//            4 = (x=z, y=m, z=n)  [PV: m varies early -> balanced tail];
//            5 = compact triangular 1-D: z=bid&7, idx=bid>>3 -> (m,n), n<=m.
// z decode: zb=z>>bh_shift, zh=z&mask; aoff=zb*aob+zh*aoh, etc.
// causal_mode: 1=skip tiles fully above diagonal, 2=truncate K at m0+TM.
__global__ __launch_bounds__(256) void gemm_bt(
    const unsigned short* __restrict__ A, const unsigned short* __restrict__ BT,
    int Kd, int lda, int ldb, int ldc, int bh_shift,
    long long aob, long long aoh, long long bob, long long boh,
    long long cob, long long coh, float scale,
    const float* __restrict__ bias, const float* __restrict__ resid,
    int do_relu, float* __restrict__ Cf, unsigned short* __restrict__ Cb,
    int causal_mode, int grid_mode) {
  __shared__ unsigned short As[8192];
  __shared__ unsigned short Bs[8192];
  int n0, m0, z;
  if (grid_mode == 2) {
    z = blockIdx.x; n0 = blockIdx.y * TN; m0 = blockIdx.z * TM;
  } else if (grid_mode == 4) {
    z = blockIdx.x; m0 = blockIdx.y * TM; n0 = blockIdx.z * TN;
  } else if (grid_mode == 5) {
    const int bid = blockIdx.x;
    z = bid & 7;
    const int idx = bid >> 3;          // [0, 136)
    int m = (int)((sqrtf(8.0f * idx + 1.0f) - 1.0f) * 0.5f);
    while ((m + 1) * (m + 2) / 2 <= idx) ++m;
    while (m * (m + 1) / 2 > idx) --m;
    m0 = m * TM;
    n0 = (idx - m * (m + 1) / 2) * TN;
  } else {
    n0 = blockIdx.x * TN; m0 = blockIdx.y * TM; z = blockIdx.z;
  }
  if (causal_mode == 1 && n0 >= m0 + TM) return;

  const int zb = z >> bh_shift;
  const int zh = z & ((1 << bh_shift) - 1);
  const long long aoff = (long long)zb * aob + (long long)zh * aoh;
  const long long boff = (long long)zb * bob + (long long)zh * boh;
  const long long coff = (long long)zb * cob + (long long)zh * coh;

  int kmax = Kd;
  if (causal_mode == 2) { int t = m0 + TM; if (t < kmax) kmax = t; }

  gemm_core(A + aoff, BT + boff, m0, n0, kmax, lda, ldb, ldc, coff, scale,
            bias, resid, do_relu, Cf, Cb, As, Bs);
}

// Merged t-GEMM (bid<1024) + vvT-GEMM (bid>=1024), both K=1024.
// t: tb[4096,4096] = xb @ Wcomb[0:4096)^T.
// vvT: per b: vT[b][4096,2048] = VT @ xb_b^T, VT = Wcomb[4096:8192).
__global__ __launch_bounds__(256) void gemm_tvv(
    const unsigned short* __restrict__ xb,
    const unsigned short* __restrict__ Wcomb,
    unsigned short* __restrict__ tb, unsigned short* __restrict__ vT) {
  __shared__ unsigned short As[8192];
  __shared__ unsigned short Bs[8192];
  const int bid = blockIdx.x;
  if (bid < 1024) {
    const int m0 = (bid >> 5) * TM;
    const int n0 = (bid & 31) * TN;
    gemm_core(xb, Wcomb, m0, n0, 1024, 1024, 1024, 4096, 0, 1.0f,
              nullptr, nullptr, 0, nullptr, tb, As, Bs);
  } else {
    int r = bid - 1024;                // [0,1024): bb = r>>9, rr = r&511
    const int bb = r >> 9;
    const int rr = r & 511;
    const int m0 = (rr >> 4) * TM;     // 32 m-tiles over 4096
    const int n0 = (rr & 15) * TN;     // 16 n-tiles over 2048
    gemm_core(Wcomb + (size_t)4096 * 1024, xb + (long long)bb * 2048 * 1024,
              m0, n0, 1024, 1024, 1024, 2048, (long long)bb * 4096 * 2048,
              1.0f, nullptr, nullptr, 0, nullptr, vT, As, Bs);
  }
}

// Partial-sum reduce + epilogue over bf16 partials:
// out = act(sum_s Pb[s*MN + i] + bias + resid).  N must be 1024.
__global__ __launch_bounds__(256) void reduce_epi(
    const unsigned short* __restrict__ Pb, int S, long long MN,
    const float* __restrict__ bias, const float* __restrict__ resid,
    int do_relu, float* __restrict__ Cf, unsigned short* __restrict__ Cb) {
  const long long i4 = ((long long)blockIdx.x * 256 + threadIdx.x) * 4;
  if (i4 >= MN) return;
  float4 s = {0.f, 0.f, 0.f, 0.f};
  for (int t = 0; t < S; ++t) {
    const ushort4 p = *(const ushort4*)(Pb + (long long)t * MN + i4);
    s.x += bf2f(p.x); s.y += bf2f(p.y); s.z += bf2f(p.z); s.w += bf2f(p.w);
  }
  if (bias) {
    const int c0 = (int)(i4 & 1023);
    s.x += bias[c0]; s.y += bias[c0 + 1]; s.z += bias[c0 + 2]; s.w += bias[c0 + 3];
  }
  if (resid) {
    const float4 rr = *(const float4*)(resid + i4);
    s.x += rr.x; s.y += rr.y; s.z += rr.z; s.w += rr.w;
  }
  if (do_relu) {
    s.x = fmaxf(s.x, 0.f); s.y = fmaxf(s.y, 0.f);
    s.z = fmaxf(s.z, 0.f); s.w = fmaxf(s.w, 0.f);
  }
  if (Cf) *(float4*)(Cf + i4) = s;
  if (Cb) {
    ushort4 o;
    o.x = f2bf(s.x); o.y = f2bf(s.y); o.z = f2bf(s.z); o.w = f2bf(s.w);
    *(ushort4*)(Cb + i4) = o;
  }
}

// Row-wise causal softmax, in-place on bf16 scores. grid=(T, B*H), block=256.
// Vectorized: thread t owns elements [t*8, t*8+8). Row q: q+1 valid; zeros
// written to next 128 boundary (PV truncates K there).
__global__ __launch_bounds__(256) void softmax_causal(unsigned short* S, int T) {
  const int q = blockIdx.x;
  unsigned short* row = S + ((long long)blockIdx.y * T + q) * T;
  const int tid = threadIdx.x;
  const int lane = tid & 63;
  const int wv = tid >> 6;
  const int n = q + 1;
  const int nz = (n + 127) & ~127;     // write limit
  const int base = tid * 8;
  const short8 raw = *(const short8*)(row + base);
  float vals[8];
  float m = -__builtin_inff();
#pragma unroll
  for (int i = 0; i < 8; ++i) {
    vals[i] = (base + i < n) ? bf2f((unsigned short)raw[i]) : -__builtin_inff();
    m = fmaxf(m, vals[i]);
  }
#pragma unroll
  for (int o = 32; o; o >>= 1) m = fmaxf(m, __shfl_xor(m, o, 64));
  __shared__ float red[4];
  if (lane == 0) red[wv] = m;
  __syncthreads();
  m = fmaxf(fmaxf(red[0], red[1]), fmaxf(red[2], red[3]));
  __syncthreads();
  float s = 0.f, e[8];
#pragma unroll
  for (int i = 0; i < 8; ++i) {
    e[i] = (base + i < n) ? __expf(vals[i] - m) : 0.f;
    s += e[i];
  }
#pragma unroll
  for (int o = 32; o; o >>= 1) s += __shfl_xor(s, o, 64);
  if (lane == 0) red[wv] = s;
  __syncthreads();
  s = red[0] + red[1] + red[2] + red[3];
  const float inv = 1.f / s;
  if (base < nz) {
    short8 o8;
#pragma unroll
    for (int i = 0; i < 8; ++i) o8[i] = (short)f2bf(e[i] * inv);
    *(short8*)(row + base) = o8;
  }
}

// All prep in one launch. grid=(4096, 7), block=256.
// z=0: cast x -> xb. z=1..3: cast Wq->Wqc, Wk*s2->Wkc, Wv->Wvc.
// z=4: Wu[4096,1024] -> WuTb[1024,4096]; z=5/6: W1/W2 [1024,1024] -> WT
// (transpose-cast; z=5/6 use only 1024 blocks).
__global__ __launch_bounds__(256) void prep_all(
    const float* __restrict__ x, const float* __restrict__ Wq,
    const float* __restrict__ Wk, const float* __restrict__ Wv,
    const float* __restrict__ Wu, const float* __restrict__ W1,
    const float* __restrict__ W2, unsigned short* __restrict__ xb,
    unsigned short* __restrict__ Wqc, unsigned short* __restrict__ Wkc,
    unsigned short* __restrict__ Wvc, unsigned short* __restrict__ WuTb,
    unsigned short* __restrict__ W1T, unsigned short* __restrict__ W2T,
    float s2) {
  const int z = blockIdx.y;
  if (z <= 3) {
    const float* src = (z == 0) ? x : (z == 1) ? Wq : (z == 2) ? Wk : Wv;
    unsigned short* dst = (z == 0) ? xb : (z == 1) ? Wqc : (z == 2) ? Wkc : Wvc;
    const float sc = (z == 2) ? s2 : 1.0f;
    const long long i4 = ((long long)blockIdx.x * 256 + threadIdx.x) * 4;
    const float4 v = *(const float4*)(src + i4);
    ushort4 u;
    u.x = f2bf(v.x * sc); u.y = f2bf(v.y * sc);
    u.z = f2bf(v.z * sc); u.w = f2bf(v.w * sc);
    *(ushort4*)(dst + i4) = u;
    return;
  }
  const int R = (z == 4) ? 4096 : 1024;
  const int by = blockIdx.x >> 5;      // r-tile
  if (by * 32 >= R) return;
  const float* W = (z == 4) ? Wu : (z == 5) ? W1 : W2;
  unsigned short* WT = (z == 4) ? WuTb : (z == 5) ? W1T : W2T;
  __shared__ float tile[32][33];
  const int c0 = (blockIdx.x & 31) * 32;  // over C=1024
  const int r0 = by * 32;
  const int tx = threadIdx.x & 31;
  const int ty = threadIdx.x >> 5;
#pragma unroll
  for (int j = 0; j < 32; j += 8)
    tile[ty + j][tx] = W[(long long)(r0 + ty + j) * 1024 + c0 + tx];
  __syncthreads();
#pragma unroll
  for (int j = 0; j < 32; j += 8)
    WT[(long long)(c0 + ty + j) * R + r0 + tx] = f2bf(tile[tx][ty + j]);
}

extern "C" void kernel_launch(void* const* d_in, const int* in_sizes, int n_in,
                              void* d_out, int out_size, void* d_ws,
                              size_t ws_size, hipStream_t stream) {
  (void)in_sizes; (void)n_in; (void)out_size; (void)ws_size;
  const float* x  = (const float*)d_in[0];
  const float* Wq = (const float*)d_in[1];
  const float* Wk = (const float*)d_in[2];
  const float* Wv = (const float*)d_in[3];
  const float* Wu = (const float*)d_in[4];
  const float* bu = (const float*)d_in[5];
  const float* W1 = (const float*)d_in[6];
  const float* b1 = (const float*)d_in[7];
  const float* W2 = (const float*)d_in[8];
  const float* b2 = (const float*)d_in[9];
  float* out = (float*)d_out;

  const int T = 2048, K = 1024;
  const int BT = 4096;
  const size_t MB = 1024 * 1024;
  const long long MN = (long long)BT * K;    // 4 Mi elements
  const long long TT = (long long)T * T;     // 4 Mi
  const long long Mi = 1024 * 1024;

  char* w = (char*)d_ws;
  unsigned short* xb    = (unsigned short*)(w + 0 * MB);    //  8 MB
  unsigned short* Wqc   = (unsigned short*)(w + 8 * MB);    //  8 MB (dies)
  unsigned short* Wvc   = (unsigned short*)(w + 16 * MB);   //  8 MB (dies)
  unsigned short* Wkc   = (unsigned short*)(w + 24 * MB);   //  8 MB pre-scaled
  unsigned short* WuTb  = (unsigned short*)(w + 32 * MB);   //  8 MB (dies)
  unsigned short* Wcomb = (unsigned short*)(w + 40 * MB);   // 16 MB (dies)
  unsigned short* tb    = (unsigned short*)(w + 56 * MB);   // 32 MB (dies)
  unsigned short* vT    = (unsigned short*)(w + 88 * MB);   // 32 MB (dies)
  unsigned short* S     = (unsigned short*)(w + 120 * MB);  // 64 MB
  unsigned short* W1T   = (unsigned short*)(w + 184 * MB);  //  2 MB
  unsigned short* W2T   = (unsigned short*)(w + 186 * MB);  //  2 MB
  // liveness aliases:
  unsigned short* Pb    = (unsigned short*)(w + 40 * MB);   // 32 MB PV partials
  float*          x1f   = (float*)(w + 8 * MB);             // 16 MB
  unsigned short* x1b   = (unsigned short*)(w + 24 * MB);   //  8 MB
  unsigned short* h1    = (unsigned short*)(w + 32 * MB);   //  8 MB
  unsigned short* Pb2   = (unsigned short*)(w + 88 * MB);   // 32 MB FFN part.

  const float s2 = 0.03125f;  // (1024^-0.25)^2 = 2^-5

  // --- prep (all casts + transposes, one launch) ---
  prep_all<<<dim3(4096, 7), 256, 0, stream>>>(
      x, Wq, Wk, Wv, Wu, W1, W2, xb, Wqc, Wkc, Wvc, WuTb, W1T, W2T, s2);

  // --- merged combine (z=8): zb=0: MT_h = (s^2 Wk)_h Wq_h^T -> Wcomb[0:4096)
  //     zb=1: VT_h = WuT_h Wv_h^T -> Wcomb[4096:8192). ---
  gemm_bt<<<dim3(8, 8, 8), 256, 0, stream>>>(
      Wkc, Wqc, K, 4096, 4096, 1024, 2,
      4 * Mi, 1024, 4 * Mi, 1024, 4 * Mi, Mi, 1.0f,
      nullptr, nullptr, 0, nullptr, Wcomb, 0, 2);

  // --- t = x @ MT^T  and  vvT = VT @ x_b^T, one 2048-block launch ---
  gemm_tvv<<<dim3(2048), 256, 0, stream>>>(xb, Wcomb, tb, vT);

  // --- scores: compact triangular (8 z * 136 tiles), full K=1024 ---
  gemm_bt<<<dim3(1088), 256, 0, stream>>>(
      tb, xb, K, 4096, K, T, 2,
      (long long)T * 4096, 1024, (long long)T * K, 0,
      (long long)4 * TT, TT, 1.0f,
      nullptr, nullptr, 0, nullptr, S, 0, 5);

  softmax_causal<<<dim3(T, 8), 256, 0, stream>>>(S, T);

  // --- PV: per (b,h): P_h @ vvT_h^T -> bf16 head partials; m-interleaved ---
  gemm_bt<<<dim3(8, T / TM, K / TN), 256, 0, stream>>>(
      S, vT, T, T, 2048, K, 2,
      (long long)4 * TT, TT, (long long)4096 * 2048, (long long)1024 * 2048,
      (long long)2048 * 1024, MN, 1.0f,
      nullptr, nullptr, 0, nullptr, Pb, 2, 4);

  // --- head-sum + bu + x residual -> x1 ---
  reduce_epi<<<dim3(4096), 256, 0, stream>>>(Pb, 4, MN, bu, x, 0, x1f, x1b);

  // --- FFN1: split-K=4 (slices of 256) -> bf16 partials, relu in reduce ---
  gemm_bt<<<dim3(K / TN, BT / TM, 4), 256, 0, stream>>>(
      x1b, W1T, 256, K, K, K, 0,
      256, 0, 256, 0, MN, 0, 1.0f,
      nullptr, nullptr, 0, nullptr, Pb2, 0, 0);
  reduce_epi<<<dim3(4096), 256, 0, stream>>>(Pb2, 4, MN, b1, nullptr, 1,
                                             nullptr, h1);

  // --- FFN2: split-K=4, + b2 + x1 residual -> out ---
  gemm_bt<<<dim3(K / TN, BT / TM, 4), 256, 0, stream>>>(
      h1, W2T, 256, K, K, K, 0,
      256, 0, 256, 0, MN, 0, 1.0f,
      nullptr, nullptr, 0, nullptr, Pb2, 0, 0);
  reduce_epi<<<dim3(4096), 256, 0, stream>>>(Pb2, 4, MN, b2, x1f, 0, out,
                                             nullptr);
}

// Round 8
// 493.855 us; speedup vs baseline: 1.5635x; 1.0188x over previous
//
#include <hip/hip_runtime.h>
#include <math.h>

// ---------------------------------------------------------------------------
// TransformerBlock: B=2, T=2048, K=1024, H=4 (each head gets FULL dim K).
// R8: cache-locality round.
//  - gemm_tvv: XCD m-stripe swizzle (each XCD's A-stripe 1MB L2-resident,
//    m_local fastest so B n-tiles are read once per XCD).
//  - grid_mode 6 for FFN split-K GEMMs: same XCD-stripe idea.
//  - softmax: row load guarded at causal limit (-29MB traffic).
// Algebra (R5/R6): MT_h = s^2 Wk_h Wq_h^T ; VT_h = Wu_h^T Wv_h^T ;
// t = x MT^T ; S = t x^T (causal) ; P = softmax ; vvT = VT x^T ;
// x1 = x + sum_h P_h vv_h + bu ; out = x1 + relu(x1 W1 + b1) W2 + b2.
// Workspace (MB, 188): [0,8) xb | [8,16) Wqc | [16,24) Wvc | [24,32) Wkc'
// | [32,40) WuTb | [40,56) Wcomb | [56,88) tb | [88,120) vT | [120,184) S
// | [184,186) W1T | [186,188) W2T.  Aliases by liveness: Pb=[40,72) after
// vvT; x1f=[8,24), x1b=[24,32), h1=[32,40) after combine; Pb2=[88,120)
// after PV.
// ---------------------------------------------------------------------------

#define TM 128
#define TN 128
#define BK 64

typedef __attribute__((ext_vector_type(8))) short short8;   // 8 bf16 (4 VGPRs)
typedef __attribute__((ext_vector_type(4))) float f32x4;

__device__ __forceinline__ unsigned short f2bf(float f) {
  union { float f; unsigned int u; } v; v.f = f;
  unsigned int r = (v.u + 0x7fffu + ((v.u >> 16) & 1u)) >> 16;
  return (unsigned short)r;
}
__device__ __forceinline__ float bf2f(unsigned short b) {
  union { unsigned int u; float f; } v; v.u = ((unsigned int)b) << 16;
  return v.f;
}

#define GL2LDS(g, l)                                                          \
  __builtin_amdgcn_global_load_lds(                                           \
      (__attribute__((address_space(1))) void*)(g),                           \
      (__attribute__((address_space(3))) void*)(l), 16, 0, 0)

// Shared GEMM core: C_tile(m0,n0) = scale*(A @ BT^T) [+bias/resid/relu].
// A, BT already offset by caller. As/Bs are the kernel's LDS buffers.
__device__ __forceinline__ void gemm_core(
    const unsigned short* __restrict__ A, const unsigned short* __restrict__ BT,
    int m0, int n0, int kmax, int lda, int ldb, int ldc, long long coff,
    float scale, const float* __restrict__ bias,
    const float* __restrict__ resid, int do_relu, float* __restrict__ Cf,
    unsigned short* __restrict__ Cb, unsigned short* As, unsigned short* Bs) {
  const int tid = threadIdx.x;
  const int lane = tid & 63;
  const int wv = tid >> 6;
  const int wm = wv & 1;   // 2x2 wave grid over 128x128 tile
  const int wn = wv >> 1;

  const int srow = tid >> 2;            // 0..63
  const int scol = (tid & 3) * 8;       // 0,8,16,24 within a 32-col half
  const unsigned short* ap0 = A + (long long)(m0 + srow) * lda + scol;
  const unsigned short* ap1 = ap0 + (long long)64 * lda;
  const unsigned short* bp0 = BT + (long long)(n0 + srow) * ldb + scol;
  const unsigned short* bp1 = bp0 + (long long)64 * ldb;
  unsigned short* lA00 = As + wv * 512;
  unsigned short* lA10 = As + 2048 + wv * 512;
  unsigned short* lA01 = As + 4096 + wv * 512;
  unsigned short* lA11 = As + 6144 + wv * 512;
  unsigned short* lB00 = Bs + wv * 512;
  unsigned short* lB10 = Bs + 2048 + wv * 512;
  unsigned short* lB01 = Bs + 4096 + wv * 512;
  unsigned short* lB11 = Bs + 6144 + wv * 512;

  f32x4 acc[4][4];
#pragma unroll
  for (int i = 0; i < 4; ++i)
#pragma unroll
    for (int j2 = 0; j2 < 4; ++j2) acc[i][j2] = {0.f, 0.f, 0.f, 0.f};

  const int frow = lane & 15;          // m (or n) within 16x16
  const int fq = (lane >> 4) * 8;      // k chunk within 32-col half

  for (int k0 = 0; k0 < kmax; k0 += BK) {
    __syncthreads();                   // prev iter's ds_reads done
    GL2LDS(ap0, lA00); GL2LDS(ap0 + 32, lA01);
    GL2LDS(ap1, lA10); GL2LDS(ap1 + 32, lA11);
    GL2LDS(bp0, lB00); GL2LDS(bp0 + 32, lB01);
    GL2LDS(bp1, lB10); GL2LDS(bp1 + 32, lB11);
    ap0 += BK; ap1 += BK; bp0 += BK; bp1 += BK;
    __syncthreads();                   // vmcnt(0) drain -> LDS visible

#pragma unroll
    for (int s = 0; s < 2; ++s) {      // k-step of 32 per half
      short8 afr[4], bfr[4];
#pragma unroll
      for (int mi = 0; mi < 4; ++mi)
        afr[mi] = *(const short8*)(As + s * 4096 +
                                   (wm * 64 + mi * 16 + frow) * 32 + fq);
#pragma unroll
      for (int ni = 0; ni < 4; ++ni)
        bfr[ni] = *(const short8*)(Bs + s * 4096 +
                                   (wn * 64 + ni * 16 + frow) * 32 + fq);
#pragma unroll
      for (int mi = 0; mi < 4; ++mi)
#pragma unroll
        for (int ni = 0; ni < 4; ++ni)
          acc[mi][ni] = __builtin_amdgcn_mfma_f32_16x16x32_bf16(
              afr[mi], bfr[ni], acc[mi][ni], 0, 0, 0);
    }
  }

  // epilogue: C/D layout col=lane&15, row=(lane>>4)*4+r (m89-verified)
  const int ccol = lane & 15;
  const int crow = (lane >> 4) * 4;
#pragma unroll
  for (int mi = 0; mi < 4; ++mi) {
#pragma unroll
    for (int ni = 0; ni < 4; ++ni) {
      const int gc = n0 + wn * 64 + ni * 16 + ccol;
#pragma unroll
      for (int r = 0; r < 4; ++r) {
        const int gr = m0 + wm * 64 + mi * 16 + crow + r;
        float v = acc[mi][ni][r] * scale;
        if (bias) v += bias[gc];
        if (resid) v += resid[(long long)gr * ldc + gc];
        if (do_relu) v = fmaxf(v, 0.f);
        const long long ci = coff + (long long)gr * ldc + gc;
        if (Cf) Cf[ci] = v;
        if (Cb) Cb[ci] = f2bf(v);
      }
    }
  }
}

// Generic batched GEMM wrapper.
// grid_mode: 0 = (x=n, y=m, z=z); 2 = (x=z, y=n, z=m);
//            4 = (x=z, y=m, z=n)  [PV: m varies early -> balanced tail];
//            5 = compact triangular 1-D: z=bid&7, idx=bid>>3 -> (m,n), n<=m;
//            6 = FFN split-K 1-D (1024 blocks): xcd=bid&7 owns 4 m-tiles
//                (A-stripe L2-resident), j>>2 -> (n, slice), j&3 = m_local.
// z decode: zb=z>>bh_shift, zh=z&mask; aoff=zb*aob+zh*aoh, etc.
// causal_mode: 1=skip tiles fully above diagonal, 2=truncate K at m0+TM.
__global__ __launch_bounds__(256) void gemm_bt(
    const unsigned short* __restrict__ A, const unsigned short* __restrict__ BT,
    int Kd, int lda, int ldb, int ldc, int bh_shift,
    long long aob, long long aoh, long long bob, long long boh,
    long long cob, long long coh, float scale,
    const float* __restrict__ bias, const float* __restrict__ resid,
    int do_relu, float* __restrict__ Cf, unsigned short* __restrict__ Cb,
    int causal_mode, int grid_mode) {
  __shared__ unsigned short As[8192];
  __shared__ unsigned short Bs[8192];
  int n0, m0, z;
  if (grid_mode == 2) {
    z = blockIdx.x; n0 = blockIdx.y * TN; m0 = blockIdx.z * TM;
  } else if (grid_mode == 4) {
    z = blockIdx.x; m0 = blockIdx.y * TM; n0 = blockIdx.z * TN;
  } else if (grid_mode == 5) {
    const int bid = blockIdx.x;
    z = bid & 7;
    const int idx = bid >> 3;          // [0, 136)
    int m = (int)((sqrtf(8.0f * idx + 1.0f) - 1.0f) * 0.5f);
    while ((m + 1) * (m + 2) / 2 <= idx) ++m;
    while (m * (m + 1) / 2 > idx) --m;
    m0 = m * TM;
    n0 = (idx - m * (m + 1) / 2) * TN;
  } else if (grid_mode == 6) {         // FFN: 32 m-tiles, 8 n-tiles, 4 slices
    const int bid = blockIdx.x;
    const int xcd = bid & 7;
    const int j = bid >> 3;            // [0,128)
    const int ns = j >> 2;             // [0,32)
    m0 = (xcd * 4 + (j & 3)) * TM;
    n0 = (ns >> 2) * TN;
    z = ns & 3;
  } else {
    n0 = blockIdx.x * TN; m0 = blockIdx.y * TM; z = blockIdx.z;
  }
  if (causal_mode == 1 && n0 >= m0 + TM) return;

  const int zb = z >> bh_shift;
  const int zh = z & ((1 << bh_shift) - 1);
  const long long aoff = (long long)zb * aob + (long long)zh * aoh;
  const long long boff = (long long)zb * bob + (long long)zh * boh;
  const long long coff = (long long)zb * cob + (long long)zh * coh;

  int kmax = Kd;
  if (causal_mode == 2) { int t = m0 + TM; if (t < kmax) kmax = t; }

  gemm_core(A + aoff, BT + boff, m0, n0, kmax, lda, ldb, ldc, coff, scale,
            bias, resid, do_relu, Cf, Cb, As, Bs);
}

// Merged t-GEMM (bid<1024) + vvT-GEMM (bid>=1024), both K=1024.
// XCD-stripe: xcd=bid&7 owns 4 m-tiles; m_local fastest so each B n-tile is
// read once per XCD (A-stripe 1MB stays L2-resident, B streams via L3).
// t: tb[4096,4096] = xb @ Wcomb[0:4096)^T.
// vvT: per b: vT[b][4096,2048] = VT @ xb_b^T, VT = Wcomb[4096:8192).
__global__ __launch_bounds__(256) void gemm_tvv(
    const unsigned short* __restrict__ xb,
    const unsigned short* __restrict__ Wcomb,
    unsigned short* __restrict__ tb, unsigned short* __restrict__ vT) {
  __shared__ unsigned short As[8192];
  __shared__ unsigned short Bs[8192];
  const int bid = blockIdx.x;
  if (bid < 1024) {
    const int xcd = bid & 7;
    const int j = bid >> 3;            // [0,128)
    const int m0 = (xcd * 4 + (j & 3)) * TM;   // 32 m-tiles
    const int n0 = (j >> 2) * TN;              // 32 n-tiles
    gemm_core(xb, Wcomb, m0, n0, 1024, 1024, 1024, 4096, 0, 1.0f,
              nullptr, nullptr, 0, nullptr, tb, As, Bs);
  } else {
    const int r = bid - 1024;
    const int xcd = r & 7;
    const int j = r >> 3;              // [0,128)
    const int bb = j >> 6;             // batch
    const int rr = j & 63;
    const int m0 = (xcd * 4 + (rr & 3)) * TM;  // 32 m-tiles
    const int n0 = (rr >> 2) * TN;             // 16 n-tiles
    gemm_core(Wcomb + (size_t)4096 * 1024, xb + (long long)bb * 2048 * 1024,
              m0, n0, 1024, 1024, 1024, 2048, (long long)bb * 4096 * 2048,
              1.0f, nullptr, nullptr, 0, nullptr, vT, As, Bs);
  }
}

// Partial-sum reduce + epilogue over bf16 partials:
// out = act(sum_s Pb[s*MN + i] + bias + resid).  N must be 1024.
__global__ __launch_bounds__(256) void reduce_epi(
    const unsigned short* __restrict__ Pb, int S, long long MN,
    const float* __restrict__ bias, const float* __restrict__ resid,
    int do_relu, float* __restrict__ Cf, unsigned short* __restrict__ Cb) {
  const long long i4 = ((long long)blockIdx.x * 256 + threadIdx.x) * 4;
  if (i4 >= MN) return;
  float4 s = {0.f, 0.f, 0.f, 0.f};
  for (int t = 0; t < S; ++t) {
    const ushort4 p = *(const ushort4*)(Pb + (long long)t * MN + i4);
    s.x += bf2f(p.x); s.y += bf2f(p.y); s.z += bf2f(p.z); s.w += bf2f(p.w);
  }
  if (bias) {
    const int c0 = (int)(i4 & 1023);
    s.x += bias[c0]; s.y += bias[c0 + 1]; s.z += bias[c0 + 2]; s.w += bias[c0 + 3];
  }
  if (resid) {
    const float4 rr = *(const float4*)(resid + i4);
    s.x += rr.x; s.y += rr.y; s.z += rr.z; s.w += rr.w;
  }
  if (do_relu) {
    s.x = fmaxf(s.x, 0.f); s.y = fmaxf(s.y, 0.f);
    s.z = fmaxf(s.z, 0.f); s.w = fmaxf(s.w, 0.f);
  }
  if (Cf) *(float4*)(Cf + i4) = s;
  if (Cb) {
    ushort4 o;
    o.x = f2bf(s.x); o.y = f2bf(s.y); o.z = f2bf(s.z); o.w = f2bf(s.w);
    *(ushort4*)(Cb + i4) = o;
  }
}

// Row-wise causal softmax, in-place on bf16 scores. grid=(T, B*H), block=256.
// Vectorized: thread t owns elements [t*8, t*8+8). Row q: q+1 valid; loads
// and stores only up to the next 128 boundary (PV truncates K there).
__global__ __launch_bounds__(256) void softmax_causal(unsigned short* S, int T) {
  const int q = blockIdx.x;
  unsigned short* row = S + ((long long)blockIdx.y * T + q) * T;
  const int tid = threadIdx.x;
  const int lane = tid & 63;
  const int wv = tid >> 6;
  const int n = q + 1;
  const int nz = (n + 127) & ~127;     // load/store limit
  const int base = tid * 8;
  short8 raw = {};
  if (base < nz) raw = *(const short8*)(row + base);
  float vals[8];
  float m = -__builtin_inff();
#pragma unroll
  for (int i = 0; i < 8; ++i) {
    vals[i] = (base + i < n) ? bf2f((unsigned short)raw[i]) : -__builtin_inff();
    m = fmaxf(m, vals[i]);
  }
#pragma unroll
  for (int o = 32; o; o >>= 1) m = fmaxf(m, __shfl_xor(m, o, 64));
  __shared__ float red[4];
  if (lane == 0) red[wv] = m;
  __syncthreads();
  m = fmaxf(fmaxf(red[0], red[1]), fmaxf(red[2], red[3]));
  __syncthreads();
  float s = 0.f, e[8];
#pragma unroll
  for (int i = 0; i < 8; ++i) {
    e[i] = (base + i < n) ? __expf(vals[i] - m) : 0.f;
    s += e[i];
  }
#pragma unroll
  for (int o = 32; o; o >>= 1) s += __shfl_xor(s, o, 64);
  if (lane == 0) red[wv] = s;
  __syncthreads();
  s = red[0] + red[1] + red[2] + red[3];
  const float inv = 1.f / s;
  if (base < nz) {
    short8 o8;
#pragma unroll
    for (int i = 0; i < 8; ++i) o8[i] = (short)f2bf(e[i] * inv);
    *(short8*)(row + base) = o8;
  }
}

// All prep in one launch. grid=(4096, 7), block=256.
// z=0: cast x -> xb. z=1..3: cast Wq->Wqc, Wk*s2->Wkc, Wv->Wvc.
// z=4: Wu[4096,1024] -> WuTb[1024,4096]; z=5/6: W1/W2 [1024,1024] -> WT
// (transpose-cast; z=5/6 use only 1024 blocks).
__global__ __launch_bounds__(256) void prep_all(
    const float* __restrict__ x, const float* __restrict__ Wq,
    const float* __restrict__ Wk, const float* __restrict__ Wv,
    const float* __restrict__ Wu, const float* __restrict__ W1,
    const float* __restrict__ W2, unsigned short* __restrict__ xb,
    unsigned short* __restrict__ Wqc, unsigned short* __restrict__ Wkc,
    unsigned short* __restrict__ Wvc, unsigned short* __restrict__ WuTb,
    unsigned short* __restrict__ W1T, unsigned short* __restrict__ W2T,
    float s2) {
  const int z = blockIdx.y;
  if (z <= 3) {
    const float* src = (z == 0) ? x : (z == 1) ? Wq : (z == 2) ? Wk : Wv;
    unsigned short* dst = (z == 0) ? xb : (z == 1) ? Wqc : (z == 2) ? Wkc : Wvc;
    const float sc = (z == 2) ? s2 : 1.0f;
    const long long i4 = ((long long)blockIdx.x * 256 + threadIdx.x) * 4;
    const float4 v = *(const float4*)(src + i4);
    ushort4 u;
    u.x = f2bf(v.x * sc); u.y = f2bf(v.y * sc);
    u.z = f2bf(v.z * sc); u.w = f2bf(v.w * sc);
    *(ushort4*)(dst + i4) = u;
    return;
  }
  const int R = (z == 4) ? 4096 : 1024;
  const int by = blockIdx.x >> 5;      // r-tile
  if (by * 32 >= R) return;
  const float* W = (z == 4) ? Wu : (z == 5) ? W1 : W2;
  unsigned short* WT = (z == 4) ? WuTb : (z == 5) ? W1T : W2T;
  __shared__ float tile[32][33];
  const int c0 = (blockIdx.x & 31) * 32;  // over C=1024
  const int r0 = by * 32;
  const int tx = threadIdx.x & 31;
  const int ty = threadIdx.x >> 5;
#pragma unroll
  for (int j = 0; j < 32; j += 8)
    tile[ty + j][tx] = W[(long long)(r0 + ty + j) * 1024 + c0 + tx];
  __syncthreads();
#pragma unroll
  for (int j = 0; j < 32; j += 8)
    WT[(long long)(c0 + ty + j) * R + r0 + tx] = f2bf(tile[tx][ty + j]);
}

extern "C" void kernel_launch(void* const* d_in, const int* in_sizes, int n_in,
                              void* d_out, int out_size, void* d_ws,
                              size_t ws_size, hipStream_t stream) {
  (void)in_sizes; (void)n_in; (void)out_size; (void)ws_size;
  const float* x  = (const float*)d_in[0];
  const float* Wq = (const float*)d_in[1];
  const float* Wk = (const float*)d_in[2];
  const float* Wv = (const float*)d_in[3];
  const float* Wu = (const float*)d_in[4];
  const float* bu = (const float*)d_in[5];
  const float* W1 = (const float*)d_in[6];
  const float* b1 = (const float*)d_in[7];
  const float* W2 = (const float*)d_in[8];
  const float* b2 = (const float*)d_in[9];
  float* out = (float*)d_out;

  const int T = 2048, K = 1024;
  const int BT = 4096;
  const size_t MB = 1024 * 1024;
  const long long MN = (long long)BT * K;    // 4 Mi elements
  const long long TT = (long long)T * T;     // 4 Mi
  const long long Mi = 1024 * 1024;

  char* w = (char*)d_ws;
  unsigned short* xb    = (unsigned short*)(w + 0 * MB);    //  8 MB
  unsigned short* Wqc   = (unsigned short*)(w + 8 * MB);    //  8 MB (dies)
  unsigned short* Wvc   = (unsigned short*)(w + 16 * MB);   //  8 MB (dies)
  unsigned short* Wkc   = (unsigned short*)(w + 24 * MB);   //  8 MB pre-scaled
  unsigned short* WuTb  = (unsigned short*)(w + 32 * MB);   //  8 MB (dies)
  unsigned short* Wcomb = (unsigned short*)(w + 40 * MB);   // 16 MB (dies)
  unsigned short* tb    = (unsigned short*)(w + 56 * MB);   // 32 MB (dies)
  unsigned short* vT    = (unsigned short*)(w + 88 * MB);   // 32 MB (dies)
  unsigned short* S     = (unsigned short*)(w + 120 * MB);  // 64 MB
  unsigned short* W1T   = (unsigned short*)(w + 184 * MB);  //  2 MB
  unsigned short* W2T   = (unsigned short*)(w + 186 * MB);  //  2 MB
  // liveness aliases:
  unsigned short* Pb    = (unsigned short*)(w + 40 * MB);   // 32 MB PV partials
  float*          x1f   = (float*)(w + 8 * MB);             // 16 MB
  unsigned short* x1b   = (unsigned short*)(w + 24 * MB);   //  8 MB
  unsigned short* h1    = (unsigned short*)(w + 32 * MB);   //  8 MB
  unsigned short* Pb2   = (unsigned short*)(w + 88 * MB);   // 32 MB FFN part.

  const float s2 = 0.03125f;  // (1024^-0.25)^2 = 2^-5

  // --- prep (all casts + transposes, one launch) ---
  prep_all<<<dim3(4096, 7), 256, 0, stream>>>(
      x, Wq, Wk, Wv, Wu, W1, W2, xb, Wqc, Wkc, Wvc, WuTb, W1T, W2T, s2);

  // --- merged combine (z=8): zb=0: MT_h = (s^2 Wk)_h Wq_h^T -> Wcomb[0:4096)
  //     zb=1: VT_h = WuT_h Wv_h^T -> Wcomb[4096:8192). ---
  gemm_bt<<<dim3(8, 8, 8), 256, 0, stream>>>(
      Wkc, Wqc, K, 4096, 4096, 1024, 2,
      4 * Mi, 1024, 4 * Mi, 1024, 4 * Mi, Mi, 1.0f,
      nullptr, nullptr, 0, nullptr, Wcomb, 0, 2);

  // --- t = x @ MT^T  and  vvT = VT @ x_b^T, one 2048-block launch ---
  gemm_tvv<<<dim3(2048), 256, 0, stream>>>(xb, Wcomb, tb, vT);

  // --- scores: compact triangular (8 z * 136 tiles), full K=1024 ---
  gemm_bt<<<dim3(1088), 256, 0, stream>>>(
      tb, xb, K, 4096, K, T, 2,
      (long long)T * 4096, 1024, (long long)T * K, 0,
      (long long)4 * TT, TT, 1.0f,
      nullptr, nullptr, 0, nullptr, S, 0, 5);

  softmax_causal<<<dim3(T, 8), 256, 0, stream>>>(S, T);

  // --- PV: per (b,h): P_h @ vvT_h^T -> bf16 head partials; m-interleaved ---
  gemm_bt<<<dim3(8, T / TM, K / TN), 256, 0, stream>>>(
      S, vT, T, T, 2048, K, 2,
      (long long)4 * TT, TT, (long long)4096 * 2048, (long long)1024 * 2048,
      (long long)2048 * 1024, MN, 1.0f,
      nullptr, nullptr, 0, nullptr, Pb, 2, 4);

  // --- head-sum + bu + x residual -> x1 ---
  reduce_epi<<<dim3(4096), 256, 0, stream>>>(Pb, 4, MN, bu, x, 0, x1f, x1b);

  // --- FFN1: split-K=4 (slices of 256) -> bf16 partials, relu in reduce ---
  gemm_bt<<<dim3(1024), 256, 0, stream>>>(
      x1b, W1T, 256, K, K, K, 0,
      256, 0, 256, 0, MN, 0, 1.0f,
      nullptr, nullptr, 0, nullptr, Pb2, 0, 6);
  reduce_epi<<<dim3(4096), 256, 0, stream>>>(Pb2, 4, MN, b1, nullptr, 1,
                                             nullptr, h1);

  // --- FFN2: split-K=4, + b2 + x1 residual -> out ---
  gemm_bt<<<dim3(1024), 256, 0, stream>>>(
      h1, W2T, 256, K, K, K, 0,
      256, 0, 256, 0, MN, 0, 1.0f,
      nullptr, nullptr, 0, nullptr, Pb2, 0, 6);
  reduce_epi<<<dim3(4096), 256, 0, stream>>>(Pb2, 4, MN, b2, x1f, 0, out,
                                             nullptr);
}

// Round 10
// 486.673 us; speedup vs baseline: 1.5866x; 1.0148x over previous
//
#include <hip/hip_runtime.h>
#include <math.h>

// ---------------------------------------------------------------------------
// TransformerBlock: B=2, T=2048, K=1024, H=4 (each head gets FULL dim K).
// R10: revert of the failed R9 cooperative mega-kernel back to the R8
// multi-kernel pipeline, plus one packing change: vvT is independent of
// scores (vvT needs xb+Wcomb, scores needs tb), so:
//   - t-GEMM launches alone (1024 blocks, exactly 4/CU, balanced);
//   - scores (1088 triangular tiles) + vvT (1024 tiles) share ONE 2112-block
//     launch (gemm_sv) -> scores' 25% tail is back-filled with vvT work.
// Algebra (R5/R6): MT_h = s^2 Wk_h Wq_h^T ; VT_h = Wu_h^T Wv_h^T ;
// t = x MT^T ; S = t x^T (causal) ; P = softmax ; vvT = VT x^T ;
// x1 = x + sum_h P_h vv_h + bu ; out = x1 + relu(x1 W1 + b1) W2 + b2.
// Workspace (MB, 188): [0,8) xb | [8,16) Wqc | [16,24) Wvc | [24,32) Wkc'
// | [32,40) WuTb | [40,56) Wcomb | [56,88) tb | [88,120) vT | [120,184) S
// | [184,186) W1T | [186,188) W2T.  Aliases by liveness: Pb=[40,72) after
// vvT; x1f=[8,24), x1b=[24,32), h1=[32,40) after combine; Pb2=[88,120)
// after PV.
// ---------------------------------------------------------------------------

#define TM 128
#define TN 128
#define BK 64

typedef __attribute__((ext_vector_type(8))) short short8;   // 8 bf16 (4 VGPRs)
typedef __attribute__((ext_vector_type(4))) float f32x4;

__device__ __forceinline__ unsigned short f2bf(float f) {
  union { float f; unsigned int u; } v; v.f = f;
  unsigned int r = (v.u + 0x7fffu + ((v.u >> 16) & 1u)) >> 16;
  return (unsigned short)r;
}
__device__ __forceinline__ float bf2f(unsigned short b) {
  union { unsigned int u; float f; } v; v.u = ((unsigned int)b) << 16;
  return v.f;
}

#define GL2LDS(g, l)                                                          \
  __builtin_amdgcn_global_load_lds(                                           \
      (__attribute__((address_space(1))) void*)(g),                           \
      (__attribute__((address_space(3))) void*)(l), 16, 0, 0)

// Shared GEMM core: C_tile(m0,n0) = scale*(A @ BT^T) [+bias/resid/relu].
// A, BT already offset by caller. As/Bs are the kernel's LDS buffers.
__device__ __forceinline__ void gemm_core(
    const unsigned short* __restrict__ A, const unsigned short* __restrict__ BT,
    int m0, int n0, int kmax, int lda, int ldb, int ldc, long long coff,
    float scale, const float* __restrict__ bias,
    const float* __restrict__ resid, int do_relu, float* __restrict__ Cf,
    unsigned short* __restrict__ Cb, unsigned short* As, unsigned short* Bs) {
  const int tid = threadIdx.x;
  const int lane = tid & 63;
  const int wv = tid >> 6;
  const int wm = wv & 1;   // 2x2 wave grid over 128x128 tile
  const int wn = wv >> 1;

  const int srow = tid >> 2;            // 0..63
  const int scol = (tid & 3) * 8;       // 0,8,16,24 within a 32-col half
  const unsigned short* ap0 = A + (long long)(m0 + srow) * lda + scol;
  const unsigned short* ap1 = ap0 + (long long)64 * lda;
  const unsigned short* bp0 = BT + (long long)(n0 + srow) * ldb + scol;
  const unsigned short* bp1 = bp0 + (long long)64 * ldb;
  unsigned short* lA00 = As + wv * 512;
  unsigned short* lA10 = As + 2048 + wv * 512;
  unsigned short* lA01 = As + 4096 + wv * 512;
  unsigned short* lA11 = As + 6144 + wv * 512;
  unsigned short* lB00 = Bs + wv * 512;
  unsigned short* lB10 = Bs + 2048 + wv * 512;
  unsigned short* lB01 = Bs + 4096 + wv * 512;
  unsigned short* lB11 = Bs + 6144 + wv * 512;

  f32x4 acc[4][4];
#pragma unroll
  for (int i = 0; i < 4; ++i)
#pragma unroll
    for (int j2 = 0; j2 < 4; ++j2) acc[i][j2] = {0.f, 0.f, 0.f, 0.f};

  const int frow = lane & 15;          // m (or n) within 16x16
  const int fq = (lane >> 4) * 8;      // k chunk within 32-col half

  for (int k0 = 0; k0 < kmax; k0 += BK) {
    __syncthreads();                   // prev iter's ds_reads done
    GL2LDS(ap0, lA00); GL2LDS(ap0 + 32, lA01);
    GL2LDS(ap1, lA10); GL2LDS(ap1 + 32, lA11);
    GL2LDS(bp0, lB00); GL2LDS(bp0 + 32, lB01);
    GL2LDS(bp1, lB10); GL2LDS(bp1 + 32, lB11);
    ap0 += BK; ap1 += BK; bp0 += BK; bp1 += BK;
    __syncthreads();                   // vmcnt(0) drain -> LDS visible

#pragma unroll
    for (int s = 0; s < 2; ++s) {      // k-step of 32 per half
      short8 afr[4], bfr[4];
#pragma unroll
      for (int mi = 0; mi < 4; ++mi)
        afr[mi] = *(const short8*)(As + s * 4096 +
                                   (wm * 64 + mi * 16 + frow) * 32 + fq);
#pragma unroll
      for (int ni = 0; ni < 4; ++ni)
        bfr[ni] = *(const short8*)(Bs + s * 4096 +
                                   (wn * 64 + ni * 16 + frow) * 32 + fq);
#pragma unroll
      for (int mi = 0; mi < 4; ++mi)
#pragma unroll
        for (int ni = 0; ni < 4; ++ni)
          acc[mi][ni] = __builtin_amdgcn_mfma_f32_16x16x32_bf16(
              afr[mi], bfr[ni], acc[mi][ni], 0, 0, 0);
    }
  }

  // epilogue: C/D layout col=lane&15, row=(lane>>4)*4+r (m89-verified)
  const int ccol = lane & 15;
  const int crow = (lane >> 4) * 4;
#pragma unroll
  for (int mi = 0; mi < 4; ++mi) {
#pragma unroll
    for (int ni = 0; ni < 4; ++ni) {
      const int gc = n0 + wn * 64 + ni * 16 + ccol;
#pragma unroll
      for (int r = 0; r < 4; ++r) {
        const int gr = m0 + wm * 64 + mi * 16 + crow + r;
        float v = acc[mi][ni][r] * scale;
        if (bias) v += bias[gc];
        if (resid) v += resid[(long long)gr * ldc + gc];
        if (do_relu) v = fmaxf(v, 0.f);
        const long long ci = coff + (long long)gr * ldc + gc;
        if (Cf) Cf[ci] = v;
        if (Cb) Cb[ci] = f2bf(v);
      }
    }
  }
}

// Generic batched GEMM wrapper.
// grid_mode: 0 = (x=n, y=m, z=z); 2 = (x=z, y=n, z=m);
//            4 = (x=z, y=m, z=n)  [PV: m varies early -> balanced tail];
//            6 = FFN split-K 1-D (1024 blocks): xcd=bid&7 owns 4 m-tiles
//                (A-stripe L2-resident), j>>2 -> (n, slice), j&3 = m_local.
// z decode: zb=z>>bh_shift, zh=z&mask; aoff=zb*aob+zh*aoh, etc.
// causal_mode: 2=truncate K at m0+TM.
__global__ __launch_bounds__(256) void gemm_bt(
    const unsigned short* __restrict__ A, const unsigned short* __restrict__ BT,
    int Kd, int lda, int ldb, int ldc, int bh_shift,
    long long aob, long long aoh, long long bob, long long boh,
    long long cob, long long coh, float scale,
    const float* __restrict__ bias, const float* __restrict__ resid,
    int do_relu, float* __restrict__ Cf, unsigned short* __restrict__ Cb,
    int causal_mode, int grid_mode) {
  __shared__ unsigned short As[8192];
  __shared__ unsigned short Bs[8192];
  int n0, m0, z;
  if (grid_mode == 2) {
    z = blockIdx.x; n0 = blockIdx.y * TN; m0 = blockIdx.z * TM;
  } else if (grid_mode == 4) {
    z = blockIdx.x; m0 = blockIdx.y * TM; n0 = blockIdx.z * TN;
  } else if (grid_mode == 6) {         // FFN: 32 m-tiles, 8 n-tiles, 4 slices
    const int bid = blockIdx.x;
    const int xcd = bid & 7;
    const int j = bid >> 3;            // [0,128)
    const int ns = j >> 2;             // [0,32)
    m0 = (xcd * 4 + (j & 3)) * TM;
    n0 = (ns >> 2) * TN;
    z = ns & 3;
  } else {
    n0 = blockIdx.x * TN; m0 = blockIdx.y * TM; z = blockIdx.z;
  }

  const int zb = z >> bh_shift;
  const int zh = z & ((1 << bh_shift) - 1);
  const long long aoff = (long long)zb * aob + (long long)zh * aoh;
  const long long boff = (long long)zb * bob + (long long)zh * boh;
  const long long coff = (long long)zb * cob + (long long)zh * coh;

  int kmax = Kd;
  if (causal_mode == 2) { int t = m0 + TM; if (t < kmax) kmax = t; }

  gemm_core(A + aoff, BT + boff, m0, n0, kmax, lda, ldb, ldc, coff, scale,
            bias, resid, do_relu, Cf, Cb, As, Bs);
}

// t-GEMM only: tb[4096,4096] = xb @ MT^T (MT = Wcomb rows [0,4096)).
// 1024 blocks, XCD m-stripe (A-stripe 1MB L2-resident).
__global__ __launch_bounds__(256) void gemm_t(
    const unsigned short* __restrict__ xb,
    const unsigned short* __restrict__ Wcomb,
    unsigned short* __restrict__ tb) {
  __shared__ unsigned short As[8192];
  __shared__ unsigned short Bs[8192];
  const int bid = blockIdx.x;
  const int xcd = bid & 7;
  const int j = bid >> 3;              // [0,128)
  const int m0 = (xcd * 4 + (j & 3)) * TM;   // 32 m-tiles
  const int n0 = (j >> 2) * TN;              // 32 n-tiles
  gemm_core(xb, Wcomb, m0, n0, 1024, 1024, 1024, 4096, 0, 1.0f,
            nullptr, nullptr, 0, nullptr, tb, As, Bs);
}

// Merged scores (bid<1088, compact triangular) + vvT (bid>=1088).
// scores: per (b,h): S = t_h @ xb_b^T (full K; PV truncates).
// vvT: per b: vT[b][4096,2048] = VT @ xb_b^T, VT = Wcomb[4096:8192).
__global__ __launch_bounds__(256) void gemm_sv(
    const unsigned short* __restrict__ xb,
    const unsigned short* __restrict__ Wcomb,
    const unsigned short* __restrict__ tb,
    unsigned short* __restrict__ S, unsigned short* __restrict__ vT) {
  __shared__ unsigned short As[8192];
  __shared__ unsigned short Bs[8192];
  const long long TT = (long long)2048 * 2048;
  const int bid = blockIdx.x;
  if (bid < 1088) {                    // scores, triangular
    const int z = bid & 7, zb = z >> 2, zh = z & 3;
    const int idx = bid >> 3;          // [0,136)
    int m = (int)((sqrtf(8.0f * idx + 1.0f) - 1.0f) * 0.5f);
    while ((m + 1) * (m + 2) / 2 <= idx) ++m;
    while (m * (m + 1) / 2 > idx) --m;
    const int m0 = m * TM;
    const int n0 = (idx - m * (m + 1) / 2) * TN;
    gemm_core(tb + (long long)zb * 2048 * 4096 + zh * 1024,
              xb + (long long)zb * 2048 * 1024,
              m0, n0, 1024, 4096, 1024, 2048,
              (long long)zb * 4 * TT + (long long)zh * TT,
              1.0f, nullptr, nullptr, 0, nullptr, S, As, Bs);
  } else {                             // vvT, XCD m-stripe
    const int r = bid - 1088;          // [0,1024)
    const int xcd = r & 7;
    const int j = r >> 3;              // [0,128)
    const int bb = j >> 6;             // batch
    const int rr = j & 63;
    const int m0 = (xcd * 4 + (rr & 3)) * TM;  // 32 m-tiles
    const int n0 = (rr >> 2) * TN;             // 16 n-tiles
    gemm_core(Wcomb + (size_t)4096 * 1024, xb + (long long)bb * 2048 * 1024,
              m0, n0, 1024, 1024, 1024, 2048, (long long)bb * 4096 * 2048,
              1.0f, nullptr, nullptr, 0, nullptr, vT, As, Bs);
  }
}

// Partial-sum reduce + epilogue over bf16 partials:
// out = act(sum_s Pb[s*MN + i] + bias + resid).  N must be 1024.
__global__ __launch_bounds__(256) void reduce_epi(
    const unsigned short* __restrict__ Pb, int S, long long MN,
    const float* __restrict__ bias, const float* __restrict__ resid,
    int do_relu, float* __restrict__ Cf, unsigned short* __restrict__ Cb) {
  const long long i4 = ((long long)blockIdx.x * 256 + threadIdx.x) * 4;
  if (i4 >= MN) return;
  float4 s = {0.f, 0.f, 0.f, 0.f};
  for (int t = 0; t < S; ++t) {
    const ushort4 p = *(const ushort4*)(Pb + (long long)t * MN + i4);
    s.x += bf2f(p.x); s.y += bf2f(p.y); s.z += bf2f(p.z); s.w += bf2f(p.w);
  }
  if (bias) {
    const int c0 = (int)(i4 & 1023);
    s.x += bias[c0]; s.y += bias[c0 + 1]; s.z += bias[c0 + 2]; s.w += bias[c0 + 3];
  }
  if (resid) {
    const float4 rr = *(const float4*)(resid + i4);
    s.x += rr.x; s.y += rr.y; s.z += rr.z; s.w += rr.w;
  }
  if (do_relu) {
    s.x = fmaxf(s.x, 0.f); s.y = fmaxf(s.y, 0.f);
    s.z = fmaxf(s.z, 0.f); s.w = fmaxf(s.w, 0.f);
  }
  if (Cf) *(float4*)(Cf + i4) = s;
  if (Cb) {
    ushort4 o;
    o.x = f2bf(s.x); o.y = f2bf(s.y); o.z = f2bf(s.z); o.w = f2bf(s.w);
    *(ushort4*)(Cb + i4) = o;
  }
}

// Row-wise causal softmax, in-place on bf16 scores. grid=(T, B*H), block=256.
// Vectorized: thread t owns elements [t*8, t*8+8). Row q: q+1 valid; loads
// and stores only up to the next 128 boundary (PV truncates K there).
__global__ __launch_bounds__(256) void softmax_causal(unsigned short* S, int T) {
  const int q = blockIdx.x;
  unsigned short* row = S + ((long long)blockIdx.y * T + q) * T;
  const int tid = threadIdx.x;
  const int lane = tid & 63;
  const int wv = tid >> 6;
  const int n = q + 1;
  const int nz = (n + 127) & ~127;     // load/store limit
  const int base = tid * 8;
  short8 raw = {};
  if (base < nz) raw = *(const short8*)(row + base);
  float vals[8];
  float m = -__builtin_inff();
#pragma unroll
  for (int i = 0; i < 8; ++i) {
    vals[i] = (base + i < n) ? bf2f((unsigned short)raw[i]) : -__builtin_inff();
    m = fmaxf(m, vals[i]);
  }
#pragma unroll
  for (int o = 32; o; o >>= 1) m = fmaxf(m, __shfl_xor(m, o, 64));
  __shared__ float red[4];
  if (lane == 0) red[wv] = m;
  __syncthreads();
  m = fmaxf(fmaxf(red[0], red[1]), fmaxf(red[2], red[3]));
  __syncthreads();
  float s = 0.f, e[8];
#pragma unroll
  for (int i = 0; i < 8; ++i) {
    e[i] = (base + i < n) ? __expf(vals[i] - m) : 0.f;
    s += e[i];
  }
#pragma unroll
  for (int o = 32; o; o >>= 1) s += __shfl_xor(s, o, 64);
  if (lane == 0) red[wv] = s;
  __syncthreads();
  s = red[0] + red[1] + red[2] + red[3];
  const float inv = 1.f / s;
  if (base < nz) {
    short8 o8;
#pragma unroll
    for (int i = 0; i < 8; ++i) o8[i] = (short)f2bf(e[i] * inv);
    *(short8*)(row + base) = o8;
  }
}

// All prep in one launch. grid=(4096, 7), block=256.
// z=0: cast x -> xb. z=1..3: cast Wq->Wqc, Wk*s2->Wkc, Wv->Wvc.
// z=4: Wu[4096,1024] -> WuTb[1024,4096]; z=5/6: W1/W2 [1024,1024] -> WT
// (transpose-cast; z=5/6 use only 1024 blocks).
__global__ __launch_bounds__(256) void prep_all(
    const float* __restrict__ x, const float* __restrict__ Wq,
    const float* __restrict__ Wk, const float* __restrict__ Wv,
    const float* __restrict__ Wu, const float* __restrict__ W1,
    const float* __restrict__ W2, unsigned short* __restrict__ xb,
    unsigned short* __restrict__ Wqc, unsigned short* __restrict__ Wkc,
    unsigned short* __restrict__ Wvc, unsigned short* __restrict__ WuTb,
    unsigned short* __restrict__ W1T, unsigned short* __restrict__ W2T,
    float s2) {
  const int z = blockIdx.y;
  if (z <= 3) {
    const float* src = (z == 0) ? x : (z == 1) ? Wq : (z == 2) ? Wk : Wv;
    unsigned short* dst = (z == 0) ? xb : (z == 1) ? Wqc : (z == 2) ? Wkc : Wvc;
    const float sc = (z == 2) ? s2 : 1.0f;
    const long long i4 = ((long long)blockIdx.x * 256 + threadIdx.x) * 4;
    const float4 v = *(const float4*)(src + i4);
    ushort4 u;
    u.x = f2bf(v.x * sc); u.y = f2bf(v.y * sc);
    u.z = f2bf(v.z * sc); u.w = f2bf(v.w * sc);
    *(ushort4*)(dst + i4) = u;
    return;
  }
  const int R = (z == 4) ? 4096 : 1024;
  const int by = blockIdx.x >> 5;      // r-tile
  if (by * 32 >= R) return;
  const float* W = (z == 4) ? Wu : (z == 5) ? W1 : W2;
  unsigned short* WT = (z == 4) ? WuTb : (z == 5) ? W1T : W2T;
  __shared__ float tile[32][33];
  const int c0 = (blockIdx.x & 31) * 32;  // over C=1024
  const int r0 = by * 32;
  const int tx = threadIdx.x & 31;
  const int ty = threadIdx.x >> 5;
#pragma unroll
  for (int j = 0; j < 32; j += 8)
    tile[ty + j][tx] = W[(long long)(r0 + ty + j) * 1024 + c0 + tx];
  __syncthreads();
#pragma unroll
  for (int j = 0; j < 32; j += 8)
    WT[(long long)(c0 + ty + j) * R + r0 + tx] = f2bf(tile[tx][ty + j]);
}

extern "C" void kernel_launch(void* const* d_in, const int* in_sizes, int n_in,
                              void* d_out, int out_size, void* d_ws,
                              size_t ws_size, hipStream_t stream) {
  (void)in_sizes; (void)n_in; (void)out_size; (void)ws_size;
  const float* x  = (const float*)d_in[0];
  const float* Wq = (const float*)d_in[1];
  const float* Wk = (const float*)d_in[2];
  const float* Wv = (const float*)d_in[3];
  const float* Wu = (const float*)d_in[4];
  const float* bu = (const float*)d_in[5];
  const float* W1 = (const float*)d_in[6];
  const float* b1 = (const float*)d_in[7];
  const float* W2 = (const float*)d_in[8];
  const float* b2 = (const float*)d_in[9];
  float* out = (float*)d_out;

  const int T = 2048, K = 1024;
  const int BT = 4096;
  const size_t MB = 1024 * 1024;
  const long long MN = (long long)BT * K;    // 4 Mi elements
  const long long TT = (long long)T * T;     // 4 Mi
  const long long Mi = 1024 * 1024;

  char* w = (char*)d_ws;
  unsigned short* xb    = (unsigned short*)(w + 0 * MB);    //  8 MB
  unsigned short* Wqc   = (unsigned short*)(w + 8 * MB);    //  8 MB (dies)
  unsigned short* Wvc   = (unsigned short*)(w + 16 * MB);   //  8 MB (dies)
  unsigned short* Wkc   = (unsigned short*)(w + 24 * MB);   //  8 MB pre-scaled
  unsigned short* WuTb  = (unsigned short*)(w + 32 * MB);   //  8 MB (dies)
  unsigned short* Wcomb = (unsigned short*)(w + 40 * MB);   // 16 MB (dies)
  unsigned short* tb    = (unsigned short*)(w + 56 * MB);   // 32 MB (dies)
  unsigned short* vT    = (unsigned short*)(w + 88 * MB);   // 32 MB (dies)
  unsigned short* S     = (unsigned short*)(w + 120 * MB);  // 64 MB
  unsigned short* W1T   = (unsigned short*)(w + 184 * MB);  //  2 MB
  unsigned short* W2T   = (unsigned short*)(w + 186 * MB);  //  2 MB
  // liveness aliases:
  unsigned short* Pb    = (unsigned short*)(w + 40 * MB);   // 32 MB PV partials
  float*          x1f   = (float*)(w + 8 * MB);             // 16 MB
  unsigned short* x1b   = (unsigned short*)(w + 24 * MB);   //  8 MB
  unsigned short* h1    = (unsigned short*)(w + 32 * MB);   //  8 MB
  unsigned short* Pb2   = (unsigned short*)(w + 88 * MB);   // 32 MB FFN part.

  const float s2 = 0.03125f;  // (1024^-0.25)^2 = 2^-5

  // --- prep (all casts + transposes, one launch) ---
  prep_all<<<dim3(4096, 7), 256, 0, stream>>>(
      x, Wq, Wk, Wv, Wu, W1, W2, xb, Wqc, Wkc, Wvc, WuTb, W1T, W2T, s2);

  // --- merged combine (z=8): zb=0: MT_h = (s^2 Wk)_h Wq_h^T -> Wcomb[0:4096)
  //     zb=1: VT_h = WuT_h Wv_h^T -> Wcomb[4096:8192). ---
  gemm_bt<<<dim3(8, 8, 8), 256, 0, stream>>>(
      Wkc, Wqc, K, 4096, 4096, 1024, 2,
      4 * Mi, 1024, 4 * Mi, 1024, 4 * Mi, Mi, 1.0f,
      nullptr, nullptr, 0, nullptr, Wcomb, 0, 2);

  // --- t = x @ MT^T (1024 blocks, 4/CU balanced) ---
  gemm_t<<<dim3(1024), 256, 0, stream>>>(xb, Wcomb, tb);

  // --- scores (triangular, 1088) + vvT (1024) in one 2112-block launch ---
  gemm_sv<<<dim3(2112), 256, 0, stream>>>(xb, Wcomb, tb, S, vT);

  softmax_causal<<<dim3(T, 8), 256, 0, stream>>>(S, T);

  // --- PV: per (b,h): P_h @ vvT_h^T -> bf16 head partials; m-interleaved ---
  gemm_bt<<<dim3(8, T / TM, K / TN), 256, 0, stream>>>(
      S, vT, T, T, 2048, K, 2,
      (long long)4 * TT, TT, (long long)4096 * 2048, (long long)1024 * 2048,
      (long long)2048 * 1024, MN, 1.0f,
      nullptr, nullptr, 0, nullptr, Pb, 2, 4);

  // --- head-sum + bu + x residual -> x1 ---
  reduce_epi<<<dim3(4096), 256, 0, stream>>>(Pb, 4, MN, bu, x, 0, x1f, x1b);

  // --- FFN1: split-K=4 (slices of 256) -> bf16 partials, relu in reduce ---
  gemm_bt<<<dim3(1024), 256, 0, stream>>>(
      x1b, W1T, 256, K, K, K, 0,
      256, 0, 256, 0, MN, 0, 1.0f,
      nullptr, nullptr, 0, nullptr, Pb2, 0, 6);
  reduce_epi<<<dim3(4096), 256, 0, stream>>>(Pb2, 4, MN, b1, nullptr, 1,
                                             nullptr, h1);

  // --- FFN2: split-K=4, + b2 + x1 residual -> out ---
  gemm_bt<<<dim3(1024), 256, 0, stream>>>(
      h1, W2T, 256, K, K, K, 0,
      256, 0, 256, 0, MN, 0, 1.0f,
      nullptr, nullptr, 0, nullptr, Pb2, 0, 6);
  reduce_epi<<<dim3(4096), 256, 0, stream>>>(Pb2, 4, MN, b2, x1f, 0, out,
                                             nullptr);
}

// Round 11
// 452.319 us; speedup vs baseline: 1.7071x; 1.0759x over previous
//
#include <hip/hip_runtime.h>
#include <math.h>

// ---------------------------------------------------------------------------
// TransformerBlock: B=2, T=2048, K=1024, H=4 (each head gets FULL dim K).
// R11 = R10 + FFN rework: split-K=4 (K=256/block, 2 reduce passes) replaced
// by a 128x64-tile full-K GEMM (core64): 512 blocks, 16 K-iters, fp32
// accumulation, bias/relu/residual fused in the epilogue. Kills 2 reduce
// launches + 64MB partial traffic. PV keeps partials+reduce (fusing head-sum
// would double S re-reads).
// Algebra (R5/R6): MT_h = s^2 Wk_h Wq_h^T ; VT_h = Wu_h^T Wv_h^T ;
// t = x MT^T ; S = t x^T (causal) ; P = softmax ; vvT = VT x^T ;
// x1 = x + sum_h P_h vv_h + bu ; out = x1 + relu(x1 W1 + b1) W2 + b2.
// Workspace (MB, 188): [0,8) xb | [8,16) Wqc | [16,24) Wvc | [24,32) Wkc'
// | [32,40) WuTb | [40,56) Wcomb | [56,88) tb | [88,120) vT | [120,184) S
// | [184,186) W1T | [186,188) W2T.  Aliases: Pb=[40,72) after sv;
// x1f=[8,24), x1b=[24,32), h1=[32,40) after combine.
// ---------------------------------------------------------------------------

#define TM 128
#define TN 128
#define BK 64

typedef __attribute__((ext_vector_type(8))) short short8;   // 8 bf16 (4 VGPRs)
typedef __attribute__((ext_vector_type(4))) float f32x4;

__device__ __forceinline__ unsigned short f2bf(float f) {
  union { float f; unsigned int u; } v; v.f = f;
  unsigned int r = (v.u + 0x7fffu + ((v.u >> 16) & 1u)) >> 16;
  return (unsigned short)r;
}
__device__ __forceinline__ float bf2f(unsigned short b) {
  union { unsigned int u; float f; } v; v.u = ((unsigned int)b) << 16;
  return v.f;
}

#define GL2LDS(g, l)                                                          \
  __builtin_amdgcn_global_load_lds(                                           \
      (__attribute__((address_space(1))) void*)(g),                           \
      (__attribute__((address_space(3))) void*)(l), 16, 0, 0)

// Shared GEMM core (128x128 tile): C_tile = scale*(A @ BT^T) [+epilogue].
__device__ __forceinline__ void gemm_core(
    const unsigned short* __restrict__ A, const unsigned short* __restrict__ BT,
    int m0, int n0, int kmax, int lda, int ldb, int ldc, long long coff,
    float scale, const float* __restrict__ bias,
    const float* __restrict__ resid, int do_relu, float* __restrict__ Cf,
    unsigned short* __restrict__ Cb, unsigned short* As, unsigned short* Bs) {
  const int tid = threadIdx.x;
  const int lane = tid & 63;
  const int wv = tid >> 6;
  const int wm = wv & 1;   // 2x2 wave grid over 128x128 tile
  const int wn = wv >> 1;

  const int srow = tid >> 2;            // 0..63
  const int scol = (tid & 3) * 8;       // 0,8,16,24 within a 32-col half
  const unsigned short* ap0 = A + (long long)(m0 + srow) * lda + scol;
  const unsigned short* ap1 = ap0 + (long long)64 * lda;
  const unsigned short* bp0 = BT + (long long)(n0 + srow) * ldb + scol;
  const unsigned short* bp1 = bp0 + (long long)64 * ldb;
  unsigned short* lA00 = As + wv * 512;
  unsigned short* lA10 = As + 2048 + wv * 512;
  unsigned short* lA01 = As + 4096 + wv * 512;
  unsigned short* lA11 = As + 6144 + wv * 512;
  unsigned short* lB00 = Bs + wv * 512;
  unsigned short* lB10 = Bs + 2048 + wv * 512;
  unsigned short* lB01 = Bs + 4096 + wv * 512;
  unsigned short* lB11 = Bs + 6144 + wv * 512;

  f32x4 acc[4][4];
#pragma unroll
  for (int i = 0; i < 4; ++i)
#pragma unroll
    for (int j2 = 0; j2 < 4; ++j2) acc[i][j2] = {0.f, 0.f, 0.f, 0.f};

  const int frow = lane & 15;          // m (or n) within 16x16
  const int fq = (lane >> 4) * 8;      // k chunk within 32-col half

  for (int k0 = 0; k0 < kmax; k0 += BK) {
    __syncthreads();                   // prev iter's ds_reads done
    GL2LDS(ap0, lA00); GL2LDS(ap0 + 32, lA01);
    GL2LDS(ap1, lA10); GL2LDS(ap1 + 32, lA11);
    GL2LDS(bp0, lB00); GL2LDS(bp0 + 32, lB01);
    GL2LDS(bp1, lB10); GL2LDS(bp1 + 32, lB11);
    ap0 += BK; ap1 += BK; bp0 += BK; bp1 += BK;
    __syncthreads();                   // vmcnt(0) drain -> LDS visible

#pragma unroll
    for (int s = 0; s < 2; ++s) {      // k-step of 32 per half
      short8 afr[4], bfr[4];
#pragma unroll
      for (int mi = 0; mi < 4; ++mi)
        afr[mi] = *(const short8*)(As + s * 4096 +
                                   (wm * 64 + mi * 16 + frow) * 32 + fq);
#pragma unroll
      for (int ni = 0; ni < 4; ++ni)
        bfr[ni] = *(const short8*)(Bs + s * 4096 +
                                   (wn * 64 + ni * 16 + frow) * 32 + fq);
#pragma unroll
      for (int mi = 0; mi < 4; ++mi)
#pragma unroll
        for (int ni = 0; ni < 4; ++ni)
          acc[mi][ni] = __builtin_amdgcn_mfma_f32_16x16x32_bf16(
              afr[mi], bfr[ni], acc[mi][ni], 0, 0, 0);
    }
  }

  // epilogue: C/D layout col=lane&15, row=(lane>>4)*4+r (m89-verified)
  const int ccol = lane & 15;
  const int crow = (lane >> 4) * 4;
#pragma unroll
  for (int mi = 0; mi < 4; ++mi) {
#pragma unroll
    for (int ni = 0; ni < 4; ++ni) {
      const int gc = n0 + wn * 64 + ni * 16 + ccol;
#pragma unroll
      for (int r = 0; r < 4; ++r) {
        const int gr = m0 + wm * 64 + mi * 16 + crow + r;
        float v = acc[mi][ni][r] * scale;
        if (bias) v += bias[gc];
        if (resid) v += resid[(long long)gr * ldc + gc];
        if (do_relu) v = fmaxf(v, 0.f);
        const long long ci = coff + (long long)gr * ldc + gc;
        if (Cf) Cf[ci] = v;
        if (Cb) Cb[ci] = f2bf(v);
      }
    }
  }
}

// 128x64-tile core: acc[4][2] += A[128,k] @ BT[64,k]^T.  A/BT pre-offset to
// tile origin. LDS: As 16KB ([2][128][32]), Bs 8KB ([2][64][32]).
__device__ __forceinline__ void core64(
    f32x4 acc[4][2], const unsigned short* __restrict__ A, int lda,
    const unsigned short* __restrict__ BT, int ldb, int kmax,
    unsigned short* As, unsigned short* Bs) {
  const int tid = threadIdx.x;
  const int lane = tid & 63;
  const int wv = tid >> 6;
  const int wm = wv & 1;               // 2 m-halves of 64
  const int wn = wv >> 1;              // 2 n-halves of 32
  const int srow = tid >> 2;           // 0..63
  const int scol = (tid & 3) * 8;
  const unsigned short* ap0 = A + (long long)srow * lda + scol;
  const unsigned short* ap1 = ap0 + (long long)64 * lda;
  const unsigned short* bp0 = BT + (long long)srow * ldb + scol;
  unsigned short* lA00 = As + wv * 512;
  unsigned short* lA10 = As + 2048 + wv * 512;
  unsigned short* lA01 = As + 4096 + wv * 512;
  unsigned short* lA11 = As + 6144 + wv * 512;
  unsigned short* lB00 = Bs + wv * 512;          // half0 rows 0..63
  unsigned short* lB01 = Bs + 2048 + wv * 512;   // half1 rows 0..63
  const int frow = lane & 15;
  const int fq = (lane >> 4) * 8;
  for (int k0 = 0; k0 < kmax; k0 += 64) {
    __syncthreads();
    GL2LDS(ap0, lA00); GL2LDS(ap0 + 32, lA01);
    GL2LDS(ap1, lA10); GL2LDS(ap1 + 32, lA11);
    GL2LDS(bp0, lB00); GL2LDS(bp0 + 32, lB01);
    ap0 += 64; ap1 += 64; bp0 += 64;
    __syncthreads();
#pragma unroll
    for (int s = 0; s < 2; ++s) {
      short8 afr[4], bfr[2];
#pragma unroll
      for (int mi = 0; mi < 4; ++mi)
        afr[mi] = *(const short8*)(As + s * 4096 +
                                   (wm * 64 + mi * 16 + frow) * 32 + fq);
#pragma unroll
      for (int ni = 0; ni < 2; ++ni)
        bfr[ni] = *(const short8*)(Bs + s * 2048 +
                                   (wn * 32 + ni * 16 + frow) * 32 + fq);
#pragma unroll
      for (int mi = 0; mi < 4; ++mi)
#pragma unroll
        for (int ni = 0; ni < 2; ++ni)
          acc[mi][ni] = __builtin_amdgcn_mfma_f32_16x16x32_bf16(
              afr[mi], bfr[ni], acc[mi][ni], 0, 0, 0);
    }
  }
}

// FFN GEMM, 128x64 tiles, full K=1024, fused epilogue.
// C = act(A @ BT^T + bias [+ resid]); A [4096,1024], BT [1024,1024].
// 512 blocks: xcd=bid&7 owns 4 m-tiles (1MB A-stripe L2-resident).
__global__ __launch_bounds__(256) void gemm_ffn(
    const unsigned short* __restrict__ A, const unsigned short* __restrict__ BT,
    const float* __restrict__ bias, const float* __restrict__ resid,
    int do_relu, float* __restrict__ Cf, unsigned short* __restrict__ Cb) {
  __shared__ unsigned short As[8192];
  __shared__ unsigned short Bs[4096];
  const int bid = blockIdx.x;
  const int xcd = bid & 7;
  const int j = bid >> 3;              // [0,64)
  const int m0 = (xcd * 4 + (j & 3)) * 128;   // 32 m-tiles
  const int n0 = (j >> 2) * 64;               // 16 n-tiles
  f32x4 acc[4][2];
#pragma unroll
  for (int i = 0; i < 4; ++i)
#pragma unroll
    for (int j2 = 0; j2 < 2; ++j2) acc[i][j2] = {0.f, 0.f, 0.f, 0.f};
  core64(acc, A + (long long)m0 * 1024, 1024, BT + (long long)n0 * 1024, 1024,
         1024, As, Bs);
  const int lane = threadIdx.x & 63;
  const int wv = threadIdx.x >> 6;
  const int wm = wv & 1, wn = wv >> 1;
  const int ccol = lane & 15, crow = (lane >> 4) * 4;
#pragma unroll
  for (int mi = 0; mi < 4; ++mi) {
#pragma unroll
    for (int ni = 0; ni < 2; ++ni) {
      const int gc = n0 + wn * 32 + ni * 16 + ccol;
#pragma unroll
      for (int r = 0; r < 4; ++r) {
        const int gr = m0 + wm * 64 + mi * 16 + crow + r;
        float v = acc[mi][ni][r] + bias[gc];
        if (resid) v += resid[(long long)gr * 1024 + gc];
        if (do_relu) v = fmaxf(v, 0.f);
        const long long ci = (long long)gr * 1024 + gc;
        if (Cf) Cf[ci] = v;
        if (Cb) Cb[ci] = f2bf(v);
      }
    }
  }
}

// Generic batched GEMM wrapper (128x128).
// grid_mode: 2 = (x=z, y=n, z=m); 4 = (x=z, y=m, z=n) [PV balanced tail].
// causal_mode: 2=truncate K at m0+TM.
__global__ __launch_bounds__(256) void gemm_bt(
    const unsigned short* __restrict__ A, const unsigned short* __restrict__ BT,
    int Kd, int lda, int ldb, int ldc, int bh_shift,
    long long aob, long long aoh, long long bob, long long boh,
    long long cob, long long coh, float scale,
    const float* __restrict__ bias, const float* __restrict__ resid,
    int do_relu, float* __restrict__ Cf, unsigned short* __restrict__ Cb,
    int causal_mode, int grid_mode) {
  __shared__ unsigned short As[8192];
  __shared__ unsigned short Bs[8192];
  int n0, m0, z;
  if (grid_mode == 2) {
    z = blockIdx.x; n0 = blockIdx.y * TN; m0 = blockIdx.z * TM;
  } else if (grid_mode == 4) {
    z = blockIdx.x; m0 = blockIdx.y * TM; n0 = blockIdx.z * TN;
  } else {
    n0 = blockIdx.x * TN; m0 = blockIdx.y * TM; z = blockIdx.z;
  }

  const int zb = z >> bh_shift;
  const int zh = z & ((1 << bh_shift) - 1);
  const long long aoff = (long long)zb * aob + (long long)zh * aoh;
  const long long boff = (long long)zb * bob + (long long)zh * boh;
  const long long coff = (long long)zb * cob + (long long)zh * coh;

  int kmax = Kd;
  if (causal_mode == 2) { int t = m0 + TM; if (t < kmax) kmax = t; }

  gemm_core(A + aoff, BT + boff, m0, n0, kmax, lda, ldb, ldc, coff, scale,
            bias, resid, do_relu, Cf, Cb, As, Bs);
}

// t-GEMM: tb[4096,4096] = xb @ MT^T (MT = Wcomb rows [0,4096)).
// 1024 blocks, XCD m-stripe.
__global__ __launch_bounds__(256) void gemm_t(
    const unsigned short* __restrict__ xb,
    const unsigned short* __restrict__ Wcomb,
    unsigned short* __restrict__ tb) {
  __shared__ unsigned short As[8192];
  __shared__ unsigned short Bs[8192];
  const int bid = blockIdx.x;
  const int xcd = bid & 7;
  const int j = bid >> 3;              // [0,128)
  const int m0 = (xcd * 4 + (j & 3)) * TM;   // 32 m-tiles
  const int n0 = (j >> 2) * TN;              // 32 n-tiles
  gemm_core(xb, Wcomb, m0, n0, 1024, 1024, 1024, 4096, 0, 1.0f,
            nullptr, nullptr, 0, nullptr, tb, As, Bs);
}

// Merged scores (bid<1088, compact triangular) + vvT (bid>=1088).
__global__ __launch_bounds__(256) void gemm_sv(
    const unsigned short* __restrict__ xb,
    const unsigned short* __restrict__ Wcomb,
    const unsigned short* __restrict__ tb,
    unsigned short* __restrict__ S, unsigned short* __restrict__ vT) {
  __shared__ unsigned short As[8192];
  __shared__ unsigned short Bs[8192];
  const long long TT = (long long)2048 * 2048;
  const int bid = blockIdx.x;
  if (bid < 1088) {                    // scores, triangular
    const int z = bid & 7, zb = z >> 2, zh = z & 3;
    const int idx = bid >> 3;          // [0,136)
    int m = (int)((sqrtf(8.0f * idx + 1.0f) - 1.0f) * 0.5f);
    while ((m + 1) * (m + 2) / 2 <= idx) ++m;
    while (m * (m + 1) / 2 > idx) --m;
    const int m0 = m * TM;
    const int n0 = (idx - m * (m + 1) / 2) * TN;
    gemm_core(tb + (long long)zb * 2048 * 4096 + zh * 1024,
              xb + (long long)zb * 2048 * 1024,
              m0, n0, 1024, 4096, 1024, 2048,
              (long long)zb * 4 * TT + (long long)zh * TT,
              1.0f, nullptr, nullptr, 0, nullptr, S, As, Bs);
  } else {                             // vvT, XCD m-stripe
    const int r = bid - 1088;          // [0,1024)
    const int xcd = r & 7;
    const int j = r >> 3;              // [0,128)
    const int bb = j >> 6;             // batch
    const int rr = j & 63;
    const int m0 = (xcd * 4 + (rr & 3)) * TM;  // 32 m-tiles
    const int n0 = (rr >> 2) * TN;             // 16 n-tiles
    gemm_core(Wcomb + (size_t)4096 * 1024, xb + (long long)bb * 2048 * 1024,
              m0, n0, 1024, 1024, 1024, 2048, (long long)bb * 4096 * 2048,
              1.0f, nullptr, nullptr, 0, nullptr, vT, As, Bs);
  }
}

// Partial-sum reduce + epilogue over bf16 partials (head-sum only now).
__global__ __launch_bounds__(256) void reduce_epi(
    const unsigned short* __restrict__ Pb, int S, long long MN,
    const float* __restrict__ bias, const float* __restrict__ resid,
    int do_relu, float* __restrict__ Cf, unsigned short* __restrict__ Cb) {
  const long long i4 = ((long long)blockIdx.x * 256 + threadIdx.x) * 4;
  if (i4 >= MN) return;
  float4 s = {0.f, 0.f, 0.f, 0.f};
  for (int t = 0; t < S; ++t) {
    const ushort4 p = *(const ushort4*)(Pb + (long long)t * MN + i4);
    s.x += bf2f(p.x); s.y += bf2f(p.y); s.z += bf2f(p.z); s.w += bf2f(p.w);
  }
  if (bias) {
    const int c0 = (int)(i4 & 1023);
    s.x += bias[c0]; s.y += bias[c0 + 1]; s.z += bias[c0 + 2]; s.w += bias[c0 + 3];
  }
  if (resid) {
    const float4 rr = *(const float4*)(resid + i4);
    s.x += rr.x; s.y += rr.y; s.z += rr.z; s.w += rr.w;
  }
  if (do_relu) {
    s.x = fmaxf(s.x, 0.f); s.y = fmaxf(s.y, 0.f);
    s.z = fmaxf(s.z, 0.f); s.w = fmaxf(s.w, 0.f);
  }
  if (Cf) *(float4*)(Cf + i4) = s;
  if (Cb) {
    ushort4 o;
    o.x = f2bf(s.x); o.y = f2bf(s.y); o.z = f2bf(s.z); o.w = f2bf(s.w);
    *(ushort4*)(Cb + i4) = o;
  }
}

// Row-wise causal softmax, in-place on bf16 scores. grid=(T, B*H), block=256.
__global__ __launch_bounds__(256) void softmax_causal(unsigned short* S, int T) {
  const int q = blockIdx.x;
  unsigned short* row = S + ((long long)blockIdx.y * T + q) * T;
  const int tid = threadIdx.x;
  const int lane = tid & 63;
  const int wv = tid >> 6;
  const int n = q + 1;
  const int nz = (n + 127) & ~127;     // load/store limit
  const int base = tid * 8;
  short8 raw = {};
  if (base < nz) raw = *(const short8*)(row + base);
  float vals[8];
  float m = -__builtin_inff();
#pragma unroll
  for (int i = 0; i < 8; ++i) {
    vals[i] = (base + i < n) ? bf2f((unsigned short)raw[i]) : -__builtin_inff();
    m = fmaxf(m, vals[i]);
  }
#pragma unroll
  for (int o = 32; o; o >>= 1) m = fmaxf(m, __shfl_xor(m, o, 64));
  __shared__ float red[4];
  if (lane == 0) red[wv] = m;
  __syncthreads();
  m = fmaxf(fmaxf(red[0], red[1]), fmaxf(red[2], red[3]));
  __syncthreads();
  float s = 0.f, e[8];
#pragma unroll
  for (int i = 0; i < 8; ++i) {
    e[i] = (base + i < n) ? __expf(vals[i] - m) : 0.f;
    s += e[i];
  }
#pragma unroll
  for (int o = 32; o; o >>= 1) s += __shfl_xor(s, o, 64);
  if (lane == 0) red[wv] = s;
  __syncthreads();
  s = red[0] + red[1] + red[2] + red[3];
  const float inv = 1.f / s;
  if (base < nz) {
    short8 o8;
#pragma unroll
    for (int i = 0; i < 8; ++i) o8[i] = (short)f2bf(e[i] * inv);
    *(short8*)(row + base) = o8;
  }
}

// All prep in one launch. grid=(4096, 7), block=256.
__global__ __launch_bounds__(256) void prep_all(
    const float* __restrict__ x, const float* __restrict__ Wq,
    const float* __restrict__ Wk, const float* __restrict__ Wv,
    const float* __restrict__ Wu, const float* __restrict__ W1,
    const float* __restrict__ W2, unsigned short* __restrict__ xb,
    unsigned short* __restrict__ Wqc, unsigned short* __restrict__ Wkc,
    unsigned short* __restrict__ Wvc, unsigned short* __restrict__ WuTb,
    unsigned short* __restrict__ W1T, unsigned short* __restrict__ W2T,
    float s2) {
  const int z = blockIdx.y;
  if (z <= 3) {
    const float* src = (z == 0) ? x : (z == 1) ? Wq : (z == 2) ? Wk : Wv;
    unsigned short* dst = (z == 0) ? xb : (z == 1) ? Wqc : (z == 2) ? Wkc : Wvc;
    const float sc = (z == 2) ? s2 : 1.0f;
    const long long i4 = ((long long)blockIdx.x * 256 + threadIdx.x) * 4;
    const float4 v = *(const float4*)(src + i4);
    ushort4 u;
    u.x = f2bf(v.x * sc); u.y = f2bf(v.y * sc);
    u.z = f2bf(v.z * sc); u.w = f2bf(v.w * sc);
    *(ushort4*)(dst + i4) = u;
    return;
  }
  const int R = (z == 4) ? 4096 : 1024;
  const int by = blockIdx.x >> 5;      // r-tile
  if (by * 32 >= R) return;
  const float* W = (z == 4) ? Wu : (z == 5) ? W1 : W2;
  unsigned short* WT = (z == 4) ? WuTb : (z == 5) ? W1T : W2T;
  __shared__ float tile[32][33];
  const int c0 = (blockIdx.x & 31) * 32;  // over C=1024
  const int r0 = by * 32;
  const int tx = threadIdx.x & 31;
  const int ty = threadIdx.x >> 5;
#pragma unroll
  for (int j = 0; j < 32; j += 8)
    tile[ty + j][tx] = W[(long long)(r0 + ty + j) * 1024 + c0 + tx];
  __syncthreads();
#pragma unroll
  for (int j = 0; j < 32; j += 8)
    WT[(long long)(c0 + ty + j) * R + r0 + tx] = f2bf(tile[tx][ty + j]);
}

extern "C" void kernel_launch(void* const* d_in, const int* in_sizes, int n_in,
                              void* d_out, int out_size, void* d_ws,
                              size_t ws_size, hipStream_t stream) {
  (void)in_sizes; (void)n_in; (void)out_size; (void)ws_size;
  const float* x  = (const float*)d_in[0];
  const float* Wq = (const float*)d_in[1];
  const float* Wk = (const float*)d_in[2];
  const float* Wv = (const float*)d_in[3];
  const float* Wu = (const float*)d_in[4];
  const float* bu = (const float*)d_in[5];
  const float* W1 = (const float*)d_in[6];
  const float* b1 = (const float*)d_in[7];
  const float* W2 = (const float*)d_in[8];
  const float* b2 = (const float*)d_in[9];
  float* out = (float*)d_out;

  const int T = 2048, K = 1024;
  const size_t MB = 1024 * 1024;
  const long long MN = (long long)4096 * 1024;  // 4 Mi elements
  const long long TT = (long long)T * T;        // 4 Mi
  const long long Mi = 1024 * 1024;

  char* w = (char*)d_ws;
  unsigned short* xb    = (unsigned short*)(w + 0 * MB);    //  8 MB
  unsigned short* Wqc   = (unsigned short*)(w + 8 * MB);    //  8 MB (dies)
  unsigned short* Wvc   = (unsigned short*)(w + 16 * MB);   //  8 MB (dies)
  unsigned short* Wkc   = (unsigned short*)(w + 24 * MB);   //  8 MB pre-scaled
  unsigned short* WuTb  = (unsigned short*)(w + 32 * MB);   //  8 MB (dies)
  unsigned short* Wcomb = (unsigned short*)(w + 40 * MB);   // 16 MB (dies)
  unsigned short* tb    = (unsigned short*)(w + 56 * MB);   // 32 MB (dies)
  unsigned short* vT    = (unsigned short*)(w + 88 * MB);   // 32 MB (dies)
  unsigned short* S     = (unsigned short*)(w + 120 * MB);  // 64 MB
  unsigned short* W1T   = (unsigned short*)(w + 184 * MB);  //  2 MB
  unsigned short* W2T   = (unsigned short*)(w + 186 * MB);  //  2 MB
  // liveness aliases:
  unsigned short* Pb    = (unsigned short*)(w + 40 * MB);   // 32 MB PV partials
  float*          x1f   = (float*)(w + 8 * MB);             // 16 MB
  unsigned short* x1b   = (unsigned short*)(w + 24 * MB);   //  8 MB
  unsigned short* h1    = (unsigned short*)(w + 32 * MB);   //  8 MB

  const float s2 = 0.03125f;  // (1024^-0.25)^2 = 2^-5

  // --- prep (all casts + transposes, one launch) ---
  prep_all<<<dim3(4096, 7), 256, 0, stream>>>(
      x, Wq, Wk, Wv, Wu, W1, W2, xb, Wqc, Wkc, Wvc, WuTb, W1T, W2T, s2);

  // --- merged combine (z=8): zb=0: MT_h; zb=1: VT_h -> Wcomb ---
  gemm_bt<<<dim3(8, 8, 8), 256, 0, stream>>>(
      Wkc, Wqc, K, 4096, 4096, 1024, 2,
      4 * Mi, 1024, 4 * Mi, 1024, 4 * Mi, Mi, 1.0f,
      nullptr, nullptr, 0, nullptr, Wcomb, 0, 2);

  // --- t = x @ MT^T (1024 blocks, 4/CU balanced) ---
  gemm_t<<<dim3(1024), 256, 0, stream>>>(xb, Wcomb, tb);

  // --- scores (triangular, 1088) + vvT (1024) in one 2112-block launch ---
  gemm_sv<<<dim3(2112), 256, 0, stream>>>(xb, Wcomb, tb, S, vT);

  softmax_causal<<<dim3(T, 8), 256, 0, stream>>>(S, T);

  // --- PV: per (b,h): P_h @ vvT_h^T -> bf16 head partials; m-interleaved ---
  gemm_bt<<<dim3(8, T / TM, K / TN), 256, 0, stream>>>(
      S, vT, T, T, 2048, K, 2,
      (long long)4 * TT, TT, (long long)4096 * 2048, (long long)1024 * 2048,
      (long long)2048 * 1024, MN, 1.0f,
      nullptr, nullptr, 0, nullptr, Pb, 2, 4);

  // --- head-sum + bu + x residual -> x1 ---
  reduce_epi<<<dim3(4096), 256, 0, stream>>>(Pb, 4, MN, bu, x, 0, x1f, x1b);

  // --- FFN1: full-K 128x64 tiles, bias+relu fused -> h1 ---
  gemm_ffn<<<dim3(512), 256, 0, stream>>>(x1b, W1T, b1, nullptr, 1,
                                          nullptr, h1);

  // --- FFN2: full-K 128x64 tiles, + b2 + x1 residual -> out ---
  gemm_ffn<<<dim3(512), 256, 0, stream>>>(h1, W2T, b2, x1f, 0, out, nullptr);
}